// Round 7
// baseline (1566.936 us; speedup 1.0000x reference)
//
#include <hip/hip_runtime.h>
#include <stdint.h>

typedef unsigned short u16;
typedef __attribute__((ext_vector_type(4))) float f32x4;
typedef __attribute__((ext_vector_type(8))) __bf16 bf16x8;
typedef __attribute__((ext_vector_type(4))) u16 u16x4;

#define B_  8192
#define D_  4096
#define C4_ 4096
#define C_  1024
#define K_  8192
#define CAP 256

__device__ __forceinline__ void load_lds16(const void* g, void* l) {
  __builtin_amdgcn_global_load_lds(
      (const __attribute__((address_space(1))) unsigned int*)g,
      (__attribute__((address_space(3))) unsigned int*)l, 16, 0, 0);
}

__device__ __forceinline__ u16 f2bf(float v) {
  unsigned int u = __float_as_uint(v);
  return (u16)((u + 0x7FFFu + ((u >> 16) & 1u)) >> 16);   // RNE
}
__device__ __forceinline__ float bf2f(u16 u) {
  return __uint_as_float(((unsigned int)u) << 16);
}
__device__ __forceinline__ unsigned int fkey(float x) {   // monotone float->uint
  unsigned int u = __float_as_uint(x);
  return u ^ (((unsigned int)(((int)u) >> 31)) | 0x80000000u);
}
__device__ __forceinline__ float key2f(unsigned int y) {  // inverse of fkey
  const unsigned int u = (y & 0x80000000u) ? (y ^ 0x80000000u) : ~y;
  return __uint_as_float(u);
}

#define VMW(N) asm volatile("s_waitcnt vmcnt(" #N ")" ::: "memory")
#define BARR() asm volatile("s_barrier" ::: "memory")

// ===================== GEMM1: 256x256 tile, 8-phase counted-vmcnt =========
// (R6-verified; unchanged.) 512 thr (8 waves 2Mx4N), BK=32, 2 K-tiles/iter,
// 3-product split-bf16. LDS 128 KB. Swizzle slot ^= (row>>1)&3 both sides.
// Waits steady [3,4,5,6]x2; final-iter drain [3,2,1,0]. 8 loads/K-tile.

#define STAGE_BX(P, GPTR, LOFF, k0)                                          \
  { load_lds16((GPTR) + sB_base + (size_t)(k0),                              \
               lds + (P) * 32768 + (LOFF) + w * 512);                        \
    load_lds16((GPTR) + sB_base + (size_t)128 * Ksz + (size_t)(k0),          \
               lds + (P) * 32768 + (LOFF) + 4096 + w * 512); }

#define STAGE_A1(P, j, k0)                                                   \
  { load_lds16(Asrc + sA_base + (size_t)((j) * 32) * Ksz + (size_t)(k0),     \
               lds + (P) * 32768 + aldsb + (j) * 1024); }

#define LOAD_B(P)                                                            \
  { const u16* bb = lds + (P) * 32768;                                       \
    _Pragma("unroll") for (int n = 0; n < 4; ++n) {                          \
      bhf[n] = *(const bf16x8*)(bb + ardB + n * 512);                        \
      blf[n] = *(const bf16x8*)(bb + 8192 + ardB + n * 512); } }

#define PH_A(P, Q, ...)                                                      \
  { const u16* bb = lds + (P) * 32768;                                       \
    const bf16x8 a0h = *(const bf16x8*)(bb + ardA + ((Q)*2 + 0) * 512);      \
    const bf16x8 a0l = *(const bf16x8*)(bb + 8192 + ardA + ((Q)*2+0) * 512); \
    const bf16x8 a1h = *(const bf16x8*)(bb + ardA + ((Q)*2 + 1) * 512);      \
    const bf16x8 a1l = *(const bf16x8*)(bb + 8192 + ardA + ((Q)*2+1) * 512); \
    __VA_ARGS__                                                              \
    __builtin_amdgcn_s_setprio(1);                                           \
    _Pragma("unroll") for (int n = 0; n < 4; ++n) {                          \
      acc[(Q)*2+0][n] = __builtin_amdgcn_mfma_f32_16x16x32_bf16(a0h, bhf[n], acc[(Q)*2+0][n], 0,0,0); \
      acc[(Q)*2+0][n] = __builtin_amdgcn_mfma_f32_16x16x32_bf16(a0l, bhf[n], acc[(Q)*2+0][n], 0,0,0); \
      acc[(Q)*2+0][n] = __builtin_amdgcn_mfma_f32_16x16x32_bf16(a0h, blf[n], acc[(Q)*2+0][n], 0,0,0); \
      acc[(Q)*2+1][n] = __builtin_amdgcn_mfma_f32_16x16x32_bf16(a1h, bhf[n], acc[(Q)*2+1][n], 0,0,0); \
      acc[(Q)*2+1][n] = __builtin_amdgcn_mfma_f32_16x16x32_bf16(a1l, bhf[n], acc[(Q)*2+1][n], 0,0,0); \
      acc[(Q)*2+1][n] = __builtin_amdgcn_mfma_f32_16x16x32_bf16(a1h, blf[n], acc[(Q)*2+1][n], 0,0,0); \
    }                                                                        \
    __builtin_amdgcn_s_setprio(0); }

__global__ __launch_bounds__(512, 2)
void k_gemm1(const u16* __restrict__ xh, const u16* __restrict__ xl,
             const u16* __restrict__ w1h, const u16* __restrict__ w1l,
             const float* __restrict__ b1,
             u16* __restrict__ hh, u16* __restrict__ hl) {
  extern __shared__ u16 lds[];
  const int tid = threadIdx.x;
  const int lane = tid & 63;
  const int w = tid >> 6;
  const int wr = w >> 2, wc = w & 3;
  const int rlow = lane & 15;
  const size_t Ksz = D_;
  const int nbn = C4_ / 256;
  const int bm = blockIdx.x / nbn, bn = blockIdx.x % nbn;
  const int rowA0 = bm * 256, rowB0 = bn * 256;
  const u16* __restrict__ Bhg = w1h;
  const u16* __restrict__ Blg = w1l;
  const u16* __restrict__ Asrc = (w < 4) ? xh : xl;

  const int gslot8 = (((lane & 3) ^ ((lane >> 3) & 3)) << 3);
  const size_t sB_base = (size_t)(rowB0 + w * 16 + (lane >> 2)) * Ksz + gslot8;
  const size_t sA_base =
      (size_t)(rowA0 + ((w >> 1) & 1) * 128 + (w & 1) * 16 + (lane >> 2)) * Ksz + gslot8;
  const int aldsb = ((w < 4) ? 0 : 8192) + ((w >> 1) & 1) * 4096 + (w & 1) * 512;

  const int aslot8 = (((lane >> 4) ^ ((lane >> 1) & 3)) << 3);
  const int ardA = wr * 4096 + rlow * 32 + aslot8;
  const int ardB = 16384 + wc * 2048 + rlow * 32 + aslot8;

  f32x4 acc[8][4];
#pragma unroll
  for (int m = 0; m < 8; ++m)
#pragma unroll
    for (int n = 0; n < 4; ++n) acc[m][n] = (f32x4){0.f, 0.f, 0.f, 0.f};
  bf16x8 bhf[4], blf[4];

  STAGE_BX(0, Bhg, 16384, 0); STAGE_BX(0, Blg, 24576, 0);
  STAGE_A1(0, 0, 0); STAGE_A1(0, 1, 0); STAGE_A1(0, 2, 0); STAGE_A1(0, 3, 0);

  const int NIT = (int)(Ksz / 64);
  for (int t = 0; t < NIT - 1; ++t) {
    const int k1 = t * 64 + 32;
    const int k2 = t * 64 + 64;
    VMW(3); BARR(); LOAD_B(0); PH_A(0, 0, STAGE_BX(1, Bhg, 16384, k1);)
    VMW(4); BARR();            PH_A(0, 1, STAGE_BX(1, Blg, 24576, k1);)
    VMW(5); BARR();            PH_A(0, 2, STAGE_A1(1, 0, k1); STAGE_A1(1, 1, k1);)
    VMW(6); BARR();            PH_A(0, 3, STAGE_A1(1, 2, k1); STAGE_A1(1, 3, k1);)
    VMW(3); BARR(); LOAD_B(1); PH_A(1, 0, STAGE_BX(0, Bhg, 16384, k2);)
    VMW(4); BARR();            PH_A(1, 1, STAGE_BX(0, Blg, 24576, k2);)
    VMW(5); BARR();            PH_A(1, 2, STAGE_A1(0, 0, k2); STAGE_A1(0, 1, k2);)
    VMW(6); BARR();            PH_A(1, 3, STAGE_A1(0, 2, k2); STAGE_A1(0, 3, k2);)
  }
  {
    const int k1 = (NIT - 1) * 64 + 32;
    VMW(3); BARR(); LOAD_B(0); PH_A(0, 0, STAGE_BX(1, Bhg, 16384, k1);)
    VMW(4); BARR();            PH_A(0, 1, STAGE_BX(1, Blg, 24576, k1);)
    VMW(5); BARR();            PH_A(0, 2, STAGE_A1(1, 0, k1); STAGE_A1(1, 1, k1);)
    VMW(6); BARR();            PH_A(0, 3, STAGE_A1(1, 2, k1); STAGE_A1(1, 3, k1);)
    VMW(3); BARR(); LOAD_B(1); PH_A(1, 0, )
    VMW(2); BARR();            PH_A(1, 1, )
    VMW(1); BARR();            PH_A(1, 2, )
    VMW(0); BARR();            PH_A(1, 3, )
  }

#pragma unroll
  for (int m = 0; m < 8; ++m)
#pragma unroll
    for (int n = 0; n < 4; ++n)
#pragma unroll
      for (int j = 0; j < 4; ++j) {
        const int rg = rowA0 + wr * 128 + m * 16 + (lane >> 4) * 4 + j;
        const int cg = rowB0 + wc * 64 + n * 16 + rlow;
        const float v = acc[m][n][j] + b1[cg];
        const float s = v / (1.f + __expf(-v));
        const size_t o = (size_t)rg * C4_ + cg;
        const u16 hi = f2bf(s);
        hh[o] = hi;
        hl[o] = f2bf(s - bf2f(hi));
      }
}

// ===================== GEMM2: 256x128 tile, 8-phase counted-vmcnt =========
// Same machinery, B-side halved (Bs [128][32], 1 load per array, 2 n-frags
// per wave). 6 loads/K-tile: order Bh,Bl,A0,A1,A2,A3. Waits steady
// [3,4,5,5]x2 (A3 is 6th-oldest with 5 new in flight); drain [3,2,1,0].
// LDS: 2 bufs x (As_h 8192 | As_l 8192 | Bs_h 4096 | Bs_l 4096) = 96 KB.

#define G2_SB(P, GPTR, LOFF, k0)                                             \
  load_lds16((GPTR) + sB_base + (size_t)(k0), lds + (P) * 24576 + (LOFF) + w * 512);
#define G2_SA(P, j, k0)                                                      \
  load_lds16(Asrc + sA_base + (size_t)((j) * 32) * 4096 + (size_t)(k0),      \
             lds + (P) * 24576 + aldsb + (j) * 1024);
#define G2_LOADB(P)                                                          \
  { const u16* bb = lds + (P) * 24576 + 16384 + wc * 1024 + rlow * 32 + aslot8; \
    bhf[0] = *(const bf16x8*)(bb);        bhf[1] = *(const bf16x8*)(bb + 512);  \
    blf[0] = *(const bf16x8*)(bb + 4096); blf[1] = *(const bf16x8*)(bb + 4608); }
#define G2_PH(P, Q, ...)                                                     \
  { const u16* ab = lds + (P) * 24576 + ardA;                                \
    const bf16x8 a0h = *(const bf16x8*)(ab + ((Q)*2 + 0) * 512);             \
    const bf16x8 a0l = *(const bf16x8*)(ab + 8192 + ((Q)*2 + 0) * 512);      \
    const bf16x8 a1h = *(const bf16x8*)(ab + ((Q)*2 + 1) * 512);             \
    const bf16x8 a1l = *(const bf16x8*)(ab + 8192 + ((Q)*2 + 1) * 512);      \
    __VA_ARGS__                                                              \
    __builtin_amdgcn_s_setprio(1);                                           \
    _Pragma("unroll") for (int n = 0; n < 2; ++n) {                          \
      acc[(Q)*2+0][n] = __builtin_amdgcn_mfma_f32_16x16x32_bf16(a0h, bhf[n], acc[(Q)*2+0][n], 0,0,0); \
      acc[(Q)*2+0][n] = __builtin_amdgcn_mfma_f32_16x16x32_bf16(a0l, bhf[n], acc[(Q)*2+0][n], 0,0,0); \
      acc[(Q)*2+0][n] = __builtin_amdgcn_mfma_f32_16x16x32_bf16(a0h, blf[n], acc[(Q)*2+0][n], 0,0,0); \
      acc[(Q)*2+1][n] = __builtin_amdgcn_mfma_f32_16x16x32_bf16(a1h, bhf[n], acc[(Q)*2+1][n], 0,0,0); \
      acc[(Q)*2+1][n] = __builtin_amdgcn_mfma_f32_16x16x32_bf16(a1l, bhf[n], acc[(Q)*2+1][n], 0,0,0); \
      acc[(Q)*2+1][n] = __builtin_amdgcn_mfma_f32_16x16x32_bf16(a1h, blf[n], acc[(Q)*2+1][n], 0,0,0); \
    }                                                                        \
    __builtin_amdgcn_s_setprio(0); }

__global__ __launch_bounds__(512, 2)
void k_gemm2(const u16* __restrict__ ah, const u16* __restrict__ al,
             const u16* __restrict__ w2h, const u16* __restrict__ w2l,
             const float* __restrict__ b2,
             float* __restrict__ zf, u16* __restrict__ zh) {
  extern __shared__ u16 lds[];
  const int tid = threadIdx.x;
  const int lane = tid & 63;
  const int w = tid >> 6;
  const int wr = w >> 2, wc = w & 3;
  const int rlow = lane & 15;
  const int nbn = C_ / 128;
  const int bm = blockIdx.x / nbn, bn = blockIdx.x % nbn;
  const int rowA0 = bm * 256, rowB0 = bn * 128;
  const u16* __restrict__ Bhg = w2h;
  const u16* __restrict__ Blg = w2l;
  const u16* __restrict__ Asrc = (w < 4) ? ah : al;

  const int gslot8 = (((lane & 3) ^ ((lane >> 3) & 3)) << 3);
  const size_t sB_base = (size_t)(rowB0 + w * 16 + (lane >> 2)) * 4096 + gslot8;
  const size_t sA_base =
      (size_t)(rowA0 + ((w >> 1) & 1) * 128 + (w & 1) * 16 + (lane >> 2)) * 4096 + gslot8;
  const int aldsb = ((w < 4) ? 0 : 8192) + ((w >> 1) & 1) * 4096 + (w & 1) * 512;

  const int aslot8 = (((lane >> 4) ^ ((lane >> 1) & 3)) << 3);
  const int ardA = wr * 4096 + rlow * 32 + aslot8;

  f32x4 acc[8][2];
#pragma unroll
  for (int m = 0; m < 8; ++m)
#pragma unroll
    for (int n = 0; n < 2; ++n) acc[m][n] = (f32x4){0.f, 0.f, 0.f, 0.f};
  bf16x8 bhf[2], blf[2];

  // prologue: tile 0 -> buf0 (Bh, Bl, A0..A3 = 6 loads)
  G2_SB(0, Bhg, 16384, 0); G2_SB(0, Blg, 20480, 0);
  G2_SA(0, 0, 0); G2_SA(0, 1, 0); G2_SA(0, 2, 0); G2_SA(0, 3, 0);

  for (int t = 0; t < 63; ++t) {
    const int k1 = t * 64 + 32;
    const int k2 = t * 64 + 64;
    VMW(3); BARR(); G2_LOADB(0); G2_PH(0, 0, G2_SB(1, Bhg, 16384, k1); G2_SB(1, Blg, 20480, k1);)
    VMW(4); BARR();              G2_PH(0, 1, G2_SA(1, 0, k1); G2_SA(1, 1, k1);)
    VMW(5); BARR();              G2_PH(0, 2, G2_SA(1, 2, k1);)
    VMW(5); BARR();              G2_PH(0, 3, G2_SA(1, 3, k1);)
    VMW(3); BARR(); G2_LOADB(1); G2_PH(1, 0, G2_SB(0, Bhg, 16384, k2); G2_SB(0, Blg, 20480, k2);)
    VMW(4); BARR();              G2_PH(1, 1, G2_SA(0, 0, k2); G2_SA(0, 1, k2);)
    VMW(5); BARR();              G2_PH(1, 2, G2_SA(0, 2, k2);)
    VMW(5); BARR();              G2_PH(1, 3, G2_SA(0, 3, k2);)
  }
  {
    const int k1 = 63 * 64 + 32;
    VMW(3); BARR(); G2_LOADB(0); G2_PH(0, 0, G2_SB(1, Bhg, 16384, k1); G2_SB(1, Blg, 20480, k1);)
    VMW(4); BARR();              G2_PH(0, 1, G2_SA(1, 0, k1); G2_SA(1, 1, k1);)
    VMW(5); BARR();              G2_PH(0, 2, G2_SA(1, 2, k1);)
    VMW(5); BARR();              G2_PH(0, 3, G2_SA(1, 3, k1);)
    VMW(3); BARR(); G2_LOADB(1); G2_PH(1, 0, )
    VMW(2); BARR();              G2_PH(1, 1, )
    VMW(1); BARR();              G2_PH(1, 2, )
    VMW(0); BARR();              G2_PH(1, 3, )
  }

#pragma unroll
  for (int m = 0; m < 8; ++m)
#pragma unroll
    for (int n = 0; n < 2; ++n)
#pragma unroll
      for (int j = 0; j < 4; ++j) {
        const int rg = rowA0 + wr * 128 + m * 16 + (lane >> 4) * 4 + j;
        const int cg = rowB0 + wc * 32 + n * 16 + rlow;
        const float v = acc[m][n][j] + b2[cg];
        const size_t o = (size_t)rg * C_ + cg;
        zf[o] = v;
        zh[o] = f2bf(v);
      }
}

// ========== GEMM3: 256x256, 1-product bf16, fused candidate collection ====
// sc_k = ||e_k||^2 - 2 z.e_k computed per block tile; per-row 16-lane-group
// local min; collect cols with sc <= groupmin + 2B (B = rigorous error
// bound). Soundness: groupmin >= globalmin >= truemin - B and sc(true
// argmin) <= truemin + B, so the local 2B window provably contains the true
// argmin -> superset collection; k_rescore re-filters by global candidate
// min (itself always collected) then exact f64. ~148 cands/row expected;
// CAP=256 with full-scan fallback.
// 4 loads/K-tile (b0,b1,a0,a1); waits [1,-,2,-]x2, drain [1,-,0,-].
// LDS: 2 bufs x (As [256][32] 8192 | Bs [256][32] 8192) = 64 KB static.

#define G3_SB0(P, k0)                                                        \
  load_lds16(Bsrc + sB_base + (size_t)(k0), lds3 + (P) * 16384 + 8192 + w * 512);
#define G3_SB1(P, k0)                                                        \
  load_lds16(Bsrc + sB_base + (size_t)(128 * 1024) + (size_t)(k0),           \
             lds3 + (P) * 16384 + 12288 + w * 512);
#define G3_SA0(P, k0)                                                        \
  load_lds16(Asrc + sA_base + (size_t)(k0), lds3 + (P) * 16384 + adst);
#define G3_SA1(P, k0)                                                        \
  load_lds16(Asrc + sA_base + (size_t)(64 * 1024) + (size_t)(k0),            \
             lds3 + (P) * 16384 + adst + 2048);
#define G3_LOADB(P)                                                          \
  { const u16* bb = lds3 + (P) * 16384 + 8192 + wc * 2048 + rlow * 32 + aslot8; \
    bhf[0] = *(const bf16x8*)(bb);        bhf[1] = *(const bf16x8*)(bb + 512);  \
    bhf[2] = *(const bf16x8*)(bb + 1024); bhf[3] = *(const bf16x8*)(bb + 1536); }
#define G3_PH(P, Q, ...)                                                     \
  { const u16* ab = lds3 + (P) * 16384 + ardA;                               \
    const bf16x8 a0 = *(const bf16x8*)(ab + ((Q)*2 + 0) * 512);              \
    const bf16x8 a1 = *(const bf16x8*)(ab + ((Q)*2 + 1) * 512);              \
    __VA_ARGS__                                                              \
    __builtin_amdgcn_s_setprio(1);                                           \
    _Pragma("unroll") for (int n = 0; n < 4; ++n) {                          \
      acc[(Q)*2+0][n] = __builtin_amdgcn_mfma_f32_16x16x32_bf16(a0, bhf[n], acc[(Q)*2+0][n], 0,0,0); \
      acc[(Q)*2+1][n] = __builtin_amdgcn_mfma_f32_16x16x32_bf16(a1, bhf[n], acc[(Q)*2+1][n], 0,0,0); \
    }                                                                        \
    __builtin_amdgcn_s_setprio(0); }

__global__ __launch_bounds__(512, 2)
void k_gemm3(const u16* __restrict__ zh, const u16* __restrict__ eh,
             const float* __restrict__ norms, const float* __restrict__ zn2,
             const unsigned int* __restrict__ emaxb,
             unsigned long long* __restrict__ cand, int* __restrict__ candcnt) {
  __shared__ u16 lds3[32768];
  const int tid = threadIdx.x;
  const int lane = tid & 63;
  const int w = tid >> 6;
  const int wr = w >> 2, wc = w & 3;
  const int rlow = lane & 15;
  const int nbn = K_ / 256;
  const int bm = blockIdx.x / nbn, bn = blockIdx.x % nbn;
  const int rowA0 = bm * 256, rowB0 = bn * 256;
  const u16* __restrict__ Asrc = zh;
  const u16* __restrict__ Bsrc = eh;

  const int gslot8 = (((lane & 3) ^ ((lane >> 3) & 3)) << 3);
  const size_t sB_base = (size_t)(rowB0 + w * 16 + (lane >> 2)) * 1024 + gslot8;
  const size_t sA_base =
      (size_t)(rowA0 + (w >> 2) * 128 + (w & 3) * 16 + (lane >> 2)) * 1024 + gslot8;
  const int adst = (w >> 2) * 4096 + (w & 3) * 512;

  const int aslot8 = (((lane >> 4) ^ ((lane >> 1) & 3)) << 3);
  const int ardA = wr * 4096 + rlow * 32 + aslot8;

  f32x4 acc[8][4];
#pragma unroll
  for (int m = 0; m < 8; ++m)
#pragma unroll
    for (int n = 0; n < 4; ++n) acc[m][n] = (f32x4){0.f, 0.f, 0.f, 0.f};
  bf16x8 bhf[4];

  // prologue: tile 0 -> buf0 (b0, b1, a0, a1)
  G3_SB0(0, 0); G3_SB1(0, 0); G3_SA0(0, 0); G3_SA1(0, 0);

  for (int t = 0; t < 15; ++t) {
    const int k1 = t * 64 + 32;
    const int k2 = t * 64 + 64;
    VMW(1); BARR(); G3_LOADB(0);
    G3_PH(0, 0, G3_SB0(1, k1);)
    G3_PH(0, 1, G3_SB1(1, k1);)
    VMW(2); BARR();
    G3_PH(0, 2, G3_SA0(1, k1);)
    G3_PH(0, 3, G3_SA1(1, k1);)
    VMW(1); BARR(); G3_LOADB(1);
    G3_PH(1, 0, G3_SB0(0, k2);)
    G3_PH(1, 1, G3_SB1(0, k2);)
    VMW(2); BARR();
    G3_PH(1, 2, G3_SA0(0, k2);)
    G3_PH(1, 3, G3_SA1(0, k2);)
  }
  {
    const int k1 = 15 * 64 + 32;
    VMW(1); BARR(); G3_LOADB(0);
    G3_PH(0, 0, G3_SB0(1, k1);)
    G3_PH(0, 1, G3_SB1(1, k1);)
    VMW(2); BARR();
    G3_PH(0, 2, G3_SA0(1, k1);)
    G3_PH(0, 3, G3_SA1(1, k1);)
    VMW(1); BARR(); G3_LOADB(1);
    G3_PH(1, 0, )
    G3_PH(1, 1, )
    VMW(0); BARR();
    G3_PH(1, 2, )
    G3_PH(1, 3, )
  }

  // ---- fused candidate collection (replaces dotm write + scan kernel) ----
  float nrm[4];
#pragma unroll
  for (int n = 0; n < 4; ++n) nrm[n] = norms[rowB0 + wc * 64 + n * 16 + rlow];
  const float emax2 = __uint_as_float(*emaxb);
#pragma unroll
  for (int m = 0; m < 8; ++m)
#pragma unroll
    for (int j = 0; j < 4; ++j) {
      const int rg = rowA0 + wr * 128 + m * 16 + (lane >> 4) * 4 + j;
      float sc[4];
      float mn = 3.4e38f;
#pragma unroll
      for (int n = 0; n < 4; ++n) {
        sc[n] = nrm[n] - 2.f * acc[m][n][j];
        mn = fminf(mn, sc[n]);
      }
#pragma unroll
      for (int off = 1; off <= 8; off <<= 1)     // 16-lane-group row min
        mn = fminf(mn, __shfl_xor(mn, off, 64));
      const float bnd = 0.010f * sqrtf(zn2[rg]) * sqrtf(emax2) + 0.01f;
      const float win = mn + 2.f * bnd;
#pragma unroll
      for (int n = 0; n < 4; ++n) {
        if (sc[n] <= win) {
          const int p = atomicAdd(&candcnt[rg], 1);
          if (p < CAP)
            cand[(size_t)rg * CAP + p] =
                ((unsigned long long)fkey(sc[n]) << 32) |
                (unsigned int)(rowB0 + wc * 64 + n * 16 + rlow);
        }
      }
    }
}

// -------- rescore: sc-prefilter (global min is collected) + exact f64 -----
__global__ __launch_bounds__(64)
void k_rescore(const unsigned long long* __restrict__ cand,
               const int* __restrict__ candcnt,
               const float* __restrict__ zf, const float* __restrict__ embT,
               const float* __restrict__ zn2, const unsigned int* __restrict__ emaxb,
               int* __restrict__ idx) {
  const int r = blockIdx.x, lane = threadIdx.x;
  const int cnt = candcnt[r];
  double bestd = 1e300; int bestk = 0x7fffffff;
  if (cnt <= CAP) {
    unsigned int kmin = 0xFFFFFFFFu;
    for (int c = lane; c < cnt; c += 64) {
      const unsigned int ky = (unsigned int)(cand[(size_t)r * CAP + c] >> 32);
      kmin = (ky < kmin) ? ky : kmin;
    }
#pragma unroll
    for (int off = 32; off >= 1; off >>= 1) {
      const unsigned int o = (unsigned int)__shfl_xor((int)kmin, off, 64);
      kmin = (o < kmin) ? o : kmin;
    }
    const float cmin = key2f(kmin);
    const float bnd = 0.010f * sqrtf(zn2[r]) * sqrtf(__uint_as_float(*emaxb)) + 0.01f;
    const unsigned int wkey = fkey(cmin + 2.f * bnd);
    for (int c = 0; c < cnt; ++c) {
      const unsigned long long e = cand[(size_t)r * CAP + c];
      if ((unsigned int)(e >> 32) > wkey) continue;
      const int k = (int)(e & 0xFFFFFFFFu);
      double s = 0.0;
      for (int i = lane; i < C_; i += 64) {
        const double d = (double)zf[(size_t)r * C_ + i] - (double)embT[(size_t)k * C_ + i];
        s += d * d;
      }
#pragma unroll
      for (int off = 32; off >= 1; off >>= 1) s += __shfl_xor(s, off, 64);
      if (s < bestd || (s == bestd && k < bestk)) { bestd = s; bestk = k; }
    }
  } else {  // rigorous fallback (never expected)
    for (int k = 0; k < K_; ++k) {
      double s = 0.0;
      for (int i = lane; i < C_; i += 64) {
        const double d = (double)zf[(size_t)r * C_ + i] - (double)embT[(size_t)k * C_ + i];
        s += d * d;
      }
#pragma unroll
      for (int off = 32; off >= 1; off >>= 1) s += __shfl_xor(s, off, 64);
      if (s < bestd || (s == bestd && k < bestk)) { bestd = s; bestk = k; }
    }
  }
  if (lane == 0) idx[r] = bestk;
}

// -------- prep kernels ----------------------------------------------------
__global__ void k_split(const float4* __restrict__ in, size_t n4,
                        u16* __restrict__ hi, u16* __restrict__ lo) {
  size_t i = (size_t)blockIdx.x * blockDim.x + threadIdx.x;
  const size_t stride = (size_t)gridDim.x * blockDim.x;
  for (; i < n4; i += stride) {
    const float4 v = in[i];
    const float vv[4] = {v.x, v.y, v.z, v.w};
    u16x4 h, l;
#pragma unroll
    for (int j = 0; j < 4; ++j) {
      const u16 a = f2bf(vv[j]);
      h[j] = a;
      l[j] = f2bf(vv[j] - bf2f(a));
    }
    *(u16x4*)(hi + i * 4) = h;
    *(u16x4*)(lo + i * 4) = l;
  }
}

template <bool WF32, bool WLO>
__global__ void k_tsplit(const float* __restrict__ in, int R, int Cc,
                         u16* __restrict__ hiT, u16* __restrict__ loT,
                         float* __restrict__ f32T) {
  __shared__ float t[32][33];
  const int c0 = blockIdx.x * 32, r0 = blockIdx.y * 32;
  const int tx = threadIdx.x, ty = threadIdx.y;
#pragma unroll
  for (int i = 0; i < 4; ++i)
    t[ty + i * 8][tx] = in[(size_t)(r0 + ty + i * 8) * Cc + (c0 + tx)];
  __syncthreads();
#pragma unroll
  for (int i = 0; i < 4; ++i) {
    const int orow = c0 + ty + i * 8;
    const int ocol = r0 + tx;
    const float v = t[tx][ty + i * 8];
    const size_t o = (size_t)orow * R + ocol;
    const u16 hi = f2bf(v);
    hiT[o] = hi;
    if (WLO) loT[o] = f2bf(v - bf2f(hi));
    if (WF32) f32T[o] = v;
  }
}

__global__ __launch_bounds__(256)
void k_rownorm(const float* __restrict__ in, float* __restrict__ out,
               unsigned int* __restrict__ maxb, int domax) {
  const int r = blockIdx.x, tid = threadIdx.x;
  const float4 v = *(const float4*)(in + (size_t)r * 1024 + tid * 4);
  double s = (double)v.x * v.x + (double)v.y * v.y +
             (double)v.z * v.z + (double)v.w * v.w;
#pragma unroll
  for (int off = 32; off >= 1; off >>= 1) s += __shfl_xor(s, off, 64);
  __shared__ double sw[4];
  if ((tid & 63) == 0) sw[tid >> 6] = s;
  __syncthreads();
  if (tid == 0) {
    const float t = (float)(sw[0] + sw[1] + sw[2] + sw[3]);
    out[r] = t;
    if (domax) atomicMax(maxb, __float_as_uint(t));
  }
}

__global__ void k_init(double* __restrict__ dacc, unsigned int* __restrict__ emaxb,
                       int* __restrict__ candcnt) {
  const int i = blockIdx.x * blockDim.x + threadIdx.x;
  if (i == 0) { *dacc = 0.0; *emaxb = 0u; }
  if (i < B_) candcnt[i] = 0;
}

// -------- finalize: gather + LayerNorm + commitment partial ---------------
__global__ __launch_bounds__(256)
void k_finalize(const int* __restrict__ idx,
                const float* __restrict__ embT, const float* __restrict__ zf,
                const float* __restrict__ gamma, const float* __restrict__ beta,
                float* __restrict__ out, double* __restrict__ dacc) {
  const int row = blockIdx.x;
  const int tid = threadIdx.x;
  const int lane = tid & 63, w = tid >> 6;
  const int id = idx[row];

  const float4 e4 = *(const float4*)(embT + (size_t)id * C_ + tid * 4);
  float s1 = e4.x + e4.y + e4.z + e4.w;
  float s2 = e4.x * e4.x + e4.y * e4.y + e4.z * e4.z + e4.w * e4.w;
#pragma unroll
  for (int off = 32; off >= 1; off >>= 1) {
    s1 += __shfl_xor(s1, off, 64);
    s2 += __shfl_xor(s2, off, 64);
  }
  __shared__ float r1[4], r2[4], rd[4];
  if (lane == 0) { r1[w] = s1; r2[w] = s2; }
  __syncthreads();
  const float S1 = r1[0] + r1[1] + r1[2] + r1[3];
  const float S2 = r2[0] + r2[1] + r2[2] + r2[3];
  const float mu = S1 * (1.f / C_);
  const float var = S2 * (1.f / C_) - mu * mu;
  const float inv = 1.f / sqrtf(var + 1e-5f);

  const float4 z4 = *(const float4*)(zf + (size_t)row * C_ + tid * 4);
  const float4 g4 = *(const float4*)(gamma + tid * 4);
  const float4 b4 = *(const float4*)(beta + tid * 4);
  float4 o4;
  o4.x = (e4.x - mu) * inv * g4.x + b4.x;
  o4.y = (e4.y - mu) * inv * g4.y + b4.y;
  o4.z = (e4.z - mu) * inv * g4.z + b4.z;
  o4.w = (e4.w - mu) * inv * g4.w + b4.w;
  *(float4*)(out + (size_t)row * C_ + tid * 4) = o4;

  const float dx = e4.x - z4.x, dy = e4.y - z4.y, dz = e4.z - z4.z, dw = e4.w - z4.w;
  float d = dx * dx + dy * dy + dz * dz + dw * dw;
#pragma unroll
  for (int off = 32; off >= 1; off >>= 1) d += __shfl_xor(d, off, 64);
  __syncthreads();
  if (lane == 0) rd[w] = d;
  __syncthreads();
  if (tid == 0) atomicAdd(dacc, (double)(rd[0] + rd[1] + rd[2] + rd[3]));
}

__global__ void k_wdiff(const double* __restrict__ dacc, float* __restrict__ out) {
  out[(size_t)B_ * C_] = (float)(0.01 * (*dacc) / ((double)B_ * (double)C_));
}

// ---------------------------------------------------------------------------
extern "C" void kernel_launch(void* const* d_in, const int* in_sizes, int n_in,
                              void* d_out, int out_size, void* d_ws, size_t ws_size,
                              hipStream_t stream) {
  const float* x     = (const float*)d_in[0];
  const float* W1    = (const float*)d_in[1];
  const float* b1    = (const float*)d_in[2];
  const float* W2    = (const float*)d_in[3];
  const float* b2    = (const float*)d_in[4];
  const float* gamma = (const float*)d_in[5];
  const float* beta  = (const float*)d_in[6];
  const float* embed = (const float*)d_in[7];
  float* out = (float*)d_out;

  char* ws = (char*)d_ws;
  const size_t M = 1048576ull;
  // phase 1: xh 0..64M, xl 64..128M, w1h 128..160M, w1l 160..192M,
  //          hh 192..256M, hl 256..320M
  // phase 2 (over dead regions): w2h 0..8M, w2l 8..16M, zf 16..48M,
  //          zh 48..64M, embT 64..96M, eh 96..112M, small @112M, cand 113..129M
  u16* xh  = (u16*)(ws);
  u16* xl  = (u16*)(ws + 64 * M);
  u16* w1h = (u16*)(ws + 128 * M);
  u16* w1l = (u16*)(ws + 160 * M);
  u16* hh  = (u16*)(ws + 192 * M);
  u16* hl  = (u16*)(ws + 256 * M);
  u16* w2h = (u16*)(ws);
  u16* w2l = (u16*)(ws + 8 * M);
  float* zf = (float*)(ws + 16 * M);
  u16* zh  = (u16*)(ws + 48 * M);
  float* embT = (float*)(ws + 64 * M);
  u16* eh  = (u16*)(ws + 96 * M);
  float* norms = (float*)(ws + 112 * M);
  float* zn2   = (float*)(ws + 112 * M + 65536ull);
  int* candcnt = (int*)(ws + 112 * M + 131072ull);
  int* idx     = (int*)(ws + 112 * M + 196608ull);
  unsigned int* emaxb = (unsigned int*)(ws + 112 * M + 262144ull);
  double* dacc = (double*)(ws + 112 * M + 262144ull + 64ull);
  unsigned long long* cand = (unsigned long long*)(ws + 113 * M);  // 16 MB

  (void)hipFuncSetAttribute((const void*)k_gemm1,
                            hipFuncAttributeMaxDynamicSharedMemorySize, 131072);
  (void)hipFuncSetAttribute((const void*)k_gemm2,
                            hipFuncAttributeMaxDynamicSharedMemorySize, 98304);

  // 1. split x -> xh/xl
  k_split<<<2048, 256, 0, stream>>>((const float4*)x, (size_t)B_ * D_ / 4, xh, xl);
  // 2. W1 [D][4C] -> W1T hi/lo [4C][D]
  k_tsplit<false, true><<<dim3(C4_ / 32, D_ / 32), dim3(32, 8), 0, stream>>>(W1, D_, C4_, w1h, w1l, nullptr);
  // 3. GEMM1 (256^2 8-phase; +bias+SiLU+split)
  k_gemm1<<<(B_ / 256) * (C4_ / 256), 512, 131072, stream>>>(xh, xl, w1h, w1l, b1, hh, hl);
  // 4. W2 [4C][C] -> W2T hi/lo [C][4C]
  k_tsplit<false, true><<<dim3(C_ / 32, C4_ / 32), dim3(32, 8), 0, stream>>>(W2, C4_, C_, w2h, w2l, nullptr);
  // 5. GEMM2 (256x128 8-phase; +bias, write z f32 + bf16 hi)
  k_gemm2<<<(B_ / 256) * (C_ / 128), 512, 98304, stream>>>(hh, hl, w2h, w2l, b2, zf, zh);
  // 6. embed [C][K] -> embT f32 + bf16 hi [K][C]
  k_tsplit<true, false><<<dim3(K_ / 32, C_ / 32), dim3(32, 8), 0, stream>>>(embed, C_, K_, eh, nullptr, embT);
  // 7. init accumulators + candidate counters
  k_init<<<B_ / 256, 256, 0, stream>>>(dacc, emaxb, candcnt);
  // 8. norms (coalesced, f64) + max; z row norms
  k_rownorm<<<K_, 256, 0, stream>>>(embT, norms, emaxb, 1);
  k_rownorm<<<B_, 256, 0, stream>>>(zf, zn2, emaxb, 0);
  // 9. GEMM3 (256^2 8-phase 1-product) + fused candidate collection
  k_gemm3<<<(B_ / 256) * (K_ / 256), 512, 0, stream>>>(zh, eh, norms, zn2, emaxb, cand, candcnt);
  // 10. sc-prefilter + exact f64 rescore -> final indices
  k_rescore<<<B_, 64, 0, stream>>>(cand, candcnt, zf, embT, zn2, emaxb, idx);
  // 11. gather + LayerNorm + commitment
  k_finalize<<<B_, 256, 0, stream>>>(idx, embT, zf, gamma, beta, out, dacc);
  // 12. scalar diff output
  k_wdiff<<<1, 1, 0, stream>>>(dacc, out);
}

// Round 8
// 1477.423 us; speedup vs baseline: 1.0606x; 1.0606x over previous
//
#include <hip/hip_runtime.h>
#include <stdint.h>

typedef unsigned short u16;
typedef __attribute__((ext_vector_type(4))) float f32x4;
typedef __attribute__((ext_vector_type(8))) __bf16 bf16x8;
typedef __attribute__((ext_vector_type(4))) u16 u16x4;

#define B_  8192
#define D_  4096
#define C4_ 4096
#define C_  1024
#define K_  8192
#define BM  128
#define BN  128
#define CAP 256

__device__ __forceinline__ void load_lds16(const void* g, void* l) {
  __builtin_amdgcn_global_load_lds(
      (const __attribute__((address_space(1))) unsigned int*)g,
      (__attribute__((address_space(3))) unsigned int*)l, 16, 0, 0);
}

__device__ __forceinline__ u16 f2bf(float v) {
  unsigned int u = __float_as_uint(v);
  return (u16)((u + 0x7FFFu + ((u >> 16) & 1u)) >> 16);   // RNE
}
__device__ __forceinline__ float bf2f(u16 u) {
  return __uint_as_float(((unsigned int)u) << 16);
}
__device__ __forceinline__ unsigned int fkey(float x) {   // monotone float->uint
  unsigned int u = __float_as_uint(x);
  return u ^ (((unsigned int)(((int)u) >> 31)) | 0x80000000u);
}
__device__ __forceinline__ float key2f(unsigned int y) {  // inverse of fkey
  const unsigned int u = (y & 0x80000000u) ? (y ^ 0x80000000u) : ~y;
  return __uint_as_float(u);
}

#define VMW(N) asm volatile("s_waitcnt vmcnt(" #N ")" ::: "memory")
#define BARR() asm volatile("s_barrier" ::: "memory")

// ===================== GEMM1: 256x256 tile, 8-phase counted-vmcnt =========
// (R6-verified; unchanged.) 512 thr (8 waves 2Mx4N), BK=32, 2 K-tiles/iter,
// 3-product split-bf16. LDS 128 KB. Swizzle slot ^= (row>>1)&3 both sides.
// Waits steady [3,4,5,6]x2; final-iter drain [3,2,1,0]. 24 MFMA/phase.

#define STAGE_BX(P, GPTR, LOFF, k0)                                          \
  { load_lds16((GPTR) + sB_base + (size_t)(k0),                              \
               lds + (P) * 32768 + (LOFF) + w * 512);                        \
    load_lds16((GPTR) + sB_base + (size_t)128 * Ksz + (size_t)(k0),          \
               lds + (P) * 32768 + (LOFF) + 4096 + w * 512); }

#define STAGE_A1(P, j, k0)                                                   \
  { load_lds16(Asrc + sA_base + (size_t)((j) * 32) * Ksz + (size_t)(k0),     \
               lds + (P) * 32768 + aldsb + (j) * 1024); }

#define LOAD_B(P)                                                            \
  { const u16* bb = lds + (P) * 32768;                                       \
    _Pragma("unroll") for (int n = 0; n < 4; ++n) {                          \
      bhf[n] = *(const bf16x8*)(bb + ardB + n * 512);                        \
      blf[n] = *(const bf16x8*)(bb + 8192 + ardB + n * 512); } }

#define PH_A(P, Q, ...)                                                      \
  { const u16* bb = lds + (P) * 32768;                                       \
    const bf16x8 a0h = *(const bf16x8*)(bb + ardA + ((Q)*2 + 0) * 512);      \
    const bf16x8 a0l = *(const bf16x8*)(bb + 8192 + ardA + ((Q)*2+0) * 512); \
    const bf16x8 a1h = *(const bf16x8*)(bb + ardA + ((Q)*2 + 1) * 512);      \
    const bf16x8 a1l = *(const bf16x8*)(bb + 8192 + ardA + ((Q)*2+1) * 512); \
    __VA_ARGS__                                                              \
    __builtin_amdgcn_s_setprio(1);                                           \
    _Pragma("unroll") for (int n = 0; n < 4; ++n) {                          \
      acc[(Q)*2+0][n] = __builtin_amdgcn_mfma_f32_16x16x32_bf16(a0h, bhf[n], acc[(Q)*2+0][n], 0,0,0); \
      acc[(Q)*2+0][n] = __builtin_amdgcn_mfma_f32_16x16x32_bf16(a0l, bhf[n], acc[(Q)*2+0][n], 0,0,0); \
      acc[(Q)*2+0][n] = __builtin_amdgcn_mfma_f32_16x16x32_bf16(a0h, blf[n], acc[(Q)*2+0][n], 0,0,0); \
      acc[(Q)*2+1][n] = __builtin_amdgcn_mfma_f32_16x16x32_bf16(a1h, bhf[n], acc[(Q)*2+1][n], 0,0,0); \
      acc[(Q)*2+1][n] = __builtin_amdgcn_mfma_f32_16x16x32_bf16(a1l, bhf[n], acc[(Q)*2+1][n], 0,0,0); \
      acc[(Q)*2+1][n] = __builtin_amdgcn_mfma_f32_16x16x32_bf16(a1h, blf[n], acc[(Q)*2+1][n], 0,0,0); \
    }                                                                        \
    __builtin_amdgcn_s_setprio(0); }

__global__ __launch_bounds__(512, 2)
void k_gemm1(const u16* __restrict__ xh, const u16* __restrict__ xl,
             const u16* __restrict__ w1h, const u16* __restrict__ w1l,
             const float* __restrict__ b1,
             u16* __restrict__ hh, u16* __restrict__ hl) {
  extern __shared__ u16 lds[];
  const int tid = threadIdx.x;
  const int lane = tid & 63;
  const int w = tid >> 6;
  const int wr = w >> 2, wc = w & 3;
  const int rlow = lane & 15;
  const size_t Ksz = D_;
  const int nbn = C4_ / 256;
  const int bm = blockIdx.x / nbn, bn = blockIdx.x % nbn;
  const int rowA0 = bm * 256, rowB0 = bn * 256;
  const u16* __restrict__ Bhg = w1h;
  const u16* __restrict__ Blg = w1l;
  const u16* __restrict__ Asrc = (w < 4) ? xh : xl;

  const int gslot8 = (((lane & 3) ^ ((lane >> 3) & 3)) << 3);
  const size_t sB_base = (size_t)(rowB0 + w * 16 + (lane >> 2)) * Ksz + gslot8;
  const size_t sA_base =
      (size_t)(rowA0 + ((w >> 1) & 1) * 128 + (w & 1) * 16 + (lane >> 2)) * Ksz + gslot8;
  const int aldsb = ((w < 4) ? 0 : 8192) + ((w >> 1) & 1) * 4096 + (w & 1) * 512;

  const int aslot8 = (((lane >> 4) ^ ((lane >> 1) & 3)) << 3);
  const int ardA = wr * 4096 + rlow * 32 + aslot8;
  const int ardB = 16384 + wc * 2048 + rlow * 32 + aslot8;

  f32x4 acc[8][4];
#pragma unroll
  for (int m = 0; m < 8; ++m)
#pragma unroll
    for (int n = 0; n < 4; ++n) acc[m][n] = (f32x4){0.f, 0.f, 0.f, 0.f};
  bf16x8 bhf[4], blf[4];

  STAGE_BX(0, Bhg, 16384, 0); STAGE_BX(0, Blg, 24576, 0);
  STAGE_A1(0, 0, 0); STAGE_A1(0, 1, 0); STAGE_A1(0, 2, 0); STAGE_A1(0, 3, 0);

  const int NIT = (int)(Ksz / 64);
  for (int t = 0; t < NIT - 1; ++t) {
    const int k1 = t * 64 + 32;
    const int k2 = t * 64 + 64;
    VMW(3); BARR(); LOAD_B(0); PH_A(0, 0, STAGE_BX(1, Bhg, 16384, k1);)
    VMW(4); BARR();            PH_A(0, 1, STAGE_BX(1, Blg, 24576, k1);)
    VMW(5); BARR();            PH_A(0, 2, STAGE_A1(1, 0, k1); STAGE_A1(1, 1, k1);)
    VMW(6); BARR();            PH_A(0, 3, STAGE_A1(1, 2, k1); STAGE_A1(1, 3, k1);)
    VMW(3); BARR(); LOAD_B(1); PH_A(1, 0, STAGE_BX(0, Bhg, 16384, k2);)
    VMW(4); BARR();            PH_A(1, 1, STAGE_BX(0, Blg, 24576, k2);)
    VMW(5); BARR();            PH_A(1, 2, STAGE_A1(0, 0, k2); STAGE_A1(0, 1, k2);)
    VMW(6); BARR();            PH_A(1, 3, STAGE_A1(0, 2, k2); STAGE_A1(0, 3, k2);)
  }
  {
    const int k1 = (NIT - 1) * 64 + 32;
    VMW(3); BARR(); LOAD_B(0); PH_A(0, 0, STAGE_BX(1, Bhg, 16384, k1);)
    VMW(4); BARR();            PH_A(0, 1, STAGE_BX(1, Blg, 24576, k1);)
    VMW(5); BARR();            PH_A(0, 2, STAGE_A1(1, 0, k1); STAGE_A1(1, 1, k1);)
    VMW(6); BARR();            PH_A(0, 3, STAGE_A1(1, 2, k1); STAGE_A1(1, 3, k1);)
    VMW(3); BARR(); LOAD_B(1); PH_A(1, 0, )
    VMW(2); BARR();            PH_A(1, 1, )
    VMW(1); BARR();            PH_A(1, 2, )
    VMW(0); BARR();            PH_A(1, 3, )
  }

#pragma unroll
  for (int m = 0; m < 8; ++m)
#pragma unroll
    for (int n = 0; n < 4; ++n)
#pragma unroll
      for (int j = 0; j < 4; ++j) {
        const int rg = rowA0 + wr * 128 + m * 16 + (lane >> 4) * 4 + j;
        const int cg = rowB0 + wc * 64 + n * 16 + rlow;
        const float v = acc[m][n][j] + b1[cg];
        const float s = v / (1.f + __expf(-v));
        const size_t o = (size_t)rg * C4_ + cg;
        const u16 hi = f2bf(s);
        hh[o] = hi;
        hl[o] = f2bf(s - bf2f(hi));
      }
}

// ============ 128x128 split-bf16 mainloop (R2-verified) for GEMM2 =========
__device__ __forceinline__ void mfma_mainloop(
    const u16* __restrict__ Ah, const u16* __restrict__ Al,
    const u16* __restrict__ Bh, const u16* __restrict__ Bl,
    int K, int rowA0, int rowB0, u16* lds, f32x4 acc[4][4]) {
  const int tid = threadIdx.x;
  const int lane = tid & 63;
  const int w = tid >> 6;
  const int wr = w >> 1, wc = w & 1;

  u16* As_h = lds;            // [128][64]
  u16* As_l = lds + 8192;
  u16* Bs_h = lds + 16384;
  u16* Bs_l = lds + 24576;

#pragma unroll
  for (int m = 0; m < 4; ++m)
#pragma unroll
    for (int n = 0; n < 4; ++n) acc[m][n] = (f32x4){0.f, 0.f, 0.f, 0.f};

  const int rstage = w * 8 + (lane >> 3);
  const int estage = (((lane & 7) ^ (lane >> 3)) << 3);

  for (int k0 = 0; k0 < K; k0 += 64) {
#pragma unroll
    for (int c = 0; c < 4; ++c) {
      const int r = c * 32 + rstage;
      const size_t ga = (size_t)(rowA0 + r) * K + (k0 + estage);
      const size_t gb = (size_t)(rowB0 + r) * K + (k0 + estage);
      const int lo = (c * 32 + w * 8) * 64;
      load_lds16(Ah + ga, As_h + lo);
      load_lds16(Al + ga, As_l + lo);
      load_lds16(Bh + gb, Bs_h + lo);
      load_lds16(Bl + gb, Bs_l + lo);
    }
    __syncthreads();
#pragma unroll
    for (int ks = 0; ks < 2; ++ks) {
      bf16x8 ah[4], al[4], bh[4], bl[4];
      const int kof = (((ks * 4 + (lane >> 4)) ^ (lane & 7)) << 3);
#pragma unroll
      for (int m = 0; m < 4; ++m) {
        const int ra = (wr * 64 + m * 16 + (lane & 15)) * 64 + kof;
        ah[m] = *(const bf16x8*)(As_h + ra);
        al[m] = *(const bf16x8*)(As_l + ra);
      }
#pragma unroll
      for (int n = 0; n < 4; ++n) {
        const int rb = (wc * 64 + n * 16 + (lane & 15)) * 64 + kof;
        bh[n] = *(const bf16x8*)(Bs_h + rb);
        bl[n] = *(const bf16x8*)(Bs_l + rb);
      }
#pragma unroll
      for (int m = 0; m < 4; ++m)
#pragma unroll
        for (int n = 0; n < 4; ++n) {
          acc[m][n] = __builtin_amdgcn_mfma_f32_16x16x32_bf16(ah[m], bh[n], acc[m][n], 0, 0, 0);
          acc[m][n] = __builtin_amdgcn_mfma_f32_16x16x32_bf16(al[m], bh[n], acc[m][n], 0, 0, 0);
          acc[m][n] = __builtin_amdgcn_mfma_f32_16x16x32_bf16(ah[m], bl[n], acc[m][n], 0, 0, 0);
        }
    }
    __syncthreads();
  }
}

// -------- GEMM2: z = h@W2 + b2, write z f32 + bf16 hi (R6-verified) -------
__global__ __launch_bounds__(256, 2)
void k_gemm2(const u16* __restrict__ ah, const u16* __restrict__ al,
             const u16* __restrict__ bh, const u16* __restrict__ bl,
             const float* __restrict__ b2,
             float* __restrict__ zf, u16* __restrict__ zh) {
  __shared__ u16 lds[32768];
  const int nbn = C_ / BN;
  const int bm = blockIdx.x / nbn, bn = blockIdx.x % nbn;
  f32x4 acc[4][4];
  mfma_mainloop(ah, al, bh, bl, C4_, bm * BM, bn * BN, lds, acc);
  const int lane = threadIdx.x & 63, w = threadIdx.x >> 6;
  const int wr = w >> 1, wc = w & 1;
#pragma unroll
  for (int m = 0; m < 4; ++m)
#pragma unroll
    for (int n = 0; n < 4; ++n)
#pragma unroll
      for (int j = 0; j < 4; ++j) {
        const int rg = bm * BM + wr * 64 + m * 16 + (lane >> 4) * 4 + j;
        const int cg = bn * BN + wc * 64 + n * 16 + (lane & 15);
        const float v = acc[m][n][j] + b2[cg];
        const size_t o = (size_t)rg * C_ + cg;
        zf[o] = v;
        zh[o] = f2bf(v);
      }
}

// ========== GEMM3 v2: 256x256, 1-product, 1 LONG phase per BK=32 tile =====
// R7's 8-MFMA phases were too short (fixed per-phase cost dominated). v2:
// per tile ONE phase = 12 ds_read_b128 + 32 MFMA (~gemm1 phase length),
// 2-deep prefetch (tiles t,t+1 resident; stage t+2 after the post-compute
// barrier), VMW(4) steady / VMW(0) final. LDS 2 x (As[256][32] | Bs[256][32])
// = 64 KB -> 2 blocks/CU co-residency. Swizzle identical to gemm1
// (verified 0-conflict). Fused candidate collection epilogue is R7-verified.

#define G3_SB0(P, k0)                                                        \
  load_lds16(Bsrc + sB_base + (size_t)(k0), lds3 + (P) * 16384 + 8192 + w * 512);
#define G3_SB1(P, k0)                                                        \
  load_lds16(Bsrc + sB_base + (size_t)(128 * 1024) + (size_t)(k0),           \
             lds3 + (P) * 16384 + 12288 + w * 512);
#define G3_SA0(P, k0)                                                        \
  load_lds16(Asrc + sA_base + (size_t)(k0), lds3 + (P) * 16384 + adst);
#define G3_SA1(P, k0)                                                        \
  load_lds16(Asrc + sA_base + (size_t)(64 * 1024) + (size_t)(k0),            \
             lds3 + (P) * 16384 + adst + 2048);

#define G3_STEP(P, STG)                                                      \
  { const u16* ab = lds3 + (P) * 16384 + ardA;                               \
    const u16* bb = lds3 + (P) * 16384 + 8192 + bRD;                         \
    bf16x8 af[8], bfv[4];                                                    \
    _Pragma("unroll") for (int f = 0; f < 8; ++f)                            \
      af[f] = *(const bf16x8*)(ab + f * 512);                                \
    _Pragma("unroll") for (int n = 0; n < 4; ++n)                            \
      bfv[n] = *(const bf16x8*)(bb + n * 512);                               \
    __builtin_amdgcn_s_setprio(1);                                           \
    _Pragma("unroll") for (int f = 0; f < 8; ++f)                            \
      _Pragma("unroll") for (int n = 0; n < 4; ++n)                          \
        acc[f][n] = __builtin_amdgcn_mfma_f32_16x16x32_bf16(af[f], bfv[n], acc[f][n], 0, 0, 0); \
    __builtin_amdgcn_s_setprio(0);                                           \
    BARR();                                                                  \
    STG }

__global__ __launch_bounds__(512, 2)
void k_gemm3(const u16* __restrict__ zh, const u16* __restrict__ eh,
             const float* __restrict__ norms, const float* __restrict__ zn2,
             const unsigned int* __restrict__ emaxb,
             unsigned long long* __restrict__ cand, int* __restrict__ candcnt) {
  __shared__ u16 lds3[32768];
  const int tid = threadIdx.x;
  const int lane = tid & 63;
  const int w = tid >> 6;
  const int wr = w >> 2, wc = w & 3;
  const int rlow = lane & 15;
  const int nbn = K_ / 256;
  const int bm = blockIdx.x / nbn, bn = blockIdx.x % nbn;
  const int rowA0 = bm * 256, rowB0 = bn * 256;
  const u16* __restrict__ Asrc = zh;
  const u16* __restrict__ Bsrc = eh;

  const int gslot8 = (((lane & 3) ^ ((lane >> 3) & 3)) << 3);
  const size_t sB_base = (size_t)(rowB0 + w * 16 + (lane >> 2)) * 1024 + gslot8;
  const size_t sA_base =
      (size_t)(rowA0 + (w >> 2) * 128 + (w & 3) * 16 + (lane >> 2)) * 1024 + gslot8;
  const int adst = (w >> 2) * 4096 + (w & 3) * 512;

  const int aslot8 = (((lane >> 4) ^ ((lane >> 1) & 3)) << 3);
  const int ardA = wr * 4096 + rlow * 32 + aslot8;
  const int bRD = wc * 2048 + rlow * 32 + aslot8;

  f32x4 acc[8][4];
#pragma unroll
  for (int m = 0; m < 8; ++m)
#pragma unroll
    for (int n = 0; n < 4; ++n) acc[m][n] = (f32x4){0.f, 0.f, 0.f, 0.f};

  // prologue: tiles 0 (buf0) and 1 (buf1), 4 loads each
  G3_SB0(0, 0); G3_SB1(0, 0); G3_SA0(0, 0); G3_SA1(0, 0);
  G3_SB0(1, 32); G3_SB1(1, 32); G3_SA0(1, 32); G3_SA1(1, 32);

  for (int tt = 0; tt < 15; ++tt) {          // tiles 0..29 (pairs)
    const int ka = tt * 64 + 64;             // tile 2tt+2 -> buf0
    const int kb = tt * 64 + 96;             // tile 2tt+3 -> buf1
    VMW(4); BARR();
    G3_STEP(0, G3_SB0(0, ka); G3_SB1(0, ka); G3_SA0(0, ka); G3_SA1(0, ka);)
    VMW(4); BARR();
    G3_STEP(1, G3_SB0(1, kb); G3_SB1(1, kb); G3_SA0(1, kb); G3_SA1(1, kb);)
  }
  VMW(4); BARR(); G3_STEP(0, )               // tile 30
  VMW(0); BARR(); G3_STEP(1, )               // tile 31

  // ---- fused candidate collection (R7-verified) ----
  float nrm[4];
#pragma unroll
  for (int n = 0; n < 4; ++n) nrm[n] = norms[rowB0 + wc * 64 + n * 16 + rlow];
  const float emax2 = __uint_as_float(*emaxb);
#pragma unroll
  for (int m = 0; m < 8; ++m)
#pragma unroll
    for (int j = 0; j < 4; ++j) {
      const int rg = rowA0 + wr * 128 + m * 16 + (lane >> 4) * 4 + j;
      float sc[4];
      float mn = 3.4e38f;
#pragma unroll
      for (int n = 0; n < 4; ++n) {
        sc[n] = nrm[n] - 2.f * acc[m][n][j];
        mn = fminf(mn, sc[n]);
      }
#pragma unroll
      for (int off = 1; off <= 8; off <<= 1)     // 16-lane-group row min
        mn = fminf(mn, __shfl_xor(mn, off, 64));
      const float bnd = 0.010f * sqrtf(zn2[rg]) * sqrtf(emax2) + 0.01f;
      const float win = mn + 2.f * bnd;
#pragma unroll
      for (int n = 0; n < 4; ++n) {
        if (sc[n] <= win) {
          const int p = atomicAdd(&candcnt[rg], 1);
          if (p < CAP)
            cand[(size_t)rg * CAP + p] =
                ((unsigned long long)fkey(sc[n]) << 32) |
                (unsigned int)(rowB0 + wc * 64 + n * 16 + rlow);
        }
      }
    }
}

// -------- rescore: sc-prefilter (global min is collected) + exact f64 -----
__global__ __launch_bounds__(64)
void k_rescore(const unsigned long long* __restrict__ cand,
               const int* __restrict__ candcnt,
               const float* __restrict__ zf, const float* __restrict__ embT,
               const float* __restrict__ zn2, const unsigned int* __restrict__ emaxb,
               int* __restrict__ idx) {
  const int r = blockIdx.x, lane = threadIdx.x;
  const int cnt = candcnt[r];
  double bestd = 1e300; int bestk = 0x7fffffff;
  if (cnt <= CAP) {
    unsigned int kmin = 0xFFFFFFFFu;
    for (int c = lane; c < cnt; c += 64) {
      const unsigned int ky = (unsigned int)(cand[(size_t)r * CAP + c] >> 32);
      kmin = (ky < kmin) ? ky : kmin;
    }
#pragma unroll
    for (int off = 32; off >= 1; off >>= 1) {
      const unsigned int o = (unsigned int)__shfl_xor((int)kmin, off, 64);
      kmin = (o < kmin) ? o : kmin;
    }
    const float cmin = key2f(kmin);
    const float bnd = 0.010f * sqrtf(zn2[r]) * sqrtf(__uint_as_float(*emaxb)) + 0.01f;
    const unsigned int wkey = fkey(cmin + 2.f * bnd);
    for (int c = 0; c < cnt; ++c) {
      const unsigned long long e = cand[(size_t)r * CAP + c];
      if ((unsigned int)(e >> 32) > wkey) continue;
      const int k = (int)(e & 0xFFFFFFFFu);
      double s = 0.0;
      for (int i = lane; i < C_; i += 64) {
        const double d = (double)zf[(size_t)r * C_ + i] - (double)embT[(size_t)k * C_ + i];
        s += d * d;
      }
#pragma unroll
      for (int off = 32; off >= 1; off >>= 1) s += __shfl_xor(s, off, 64);
      if (s < bestd || (s == bestd && k < bestk)) { bestd = s; bestk = k; }
    }
  } else {  // rigorous fallback (never expected)
    for (int k = 0; k < K_; ++k) {
      double s = 0.0;
      for (int i = lane; i < C_; i += 64) {
        const double d = (double)zf[(size_t)r * C_ + i] - (double)embT[(size_t)k * C_ + i];
        s += d * d;
      }
#pragma unroll
      for (int off = 32; off >= 1; off >>= 1) s += __shfl_xor(s, off, 64);
      if (s < bestd || (s == bestd && k < bestk)) { bestd = s; bestk = k; }
    }
  }
  if (lane == 0) idx[r] = bestk;
}

// -------- prep kernels ----------------------------------------------------
__global__ void k_split(const float4* __restrict__ in, size_t n4,
                        u16* __restrict__ hi, u16* __restrict__ lo) {
  size_t i = (size_t)blockIdx.x * blockDim.x + threadIdx.x;
  const size_t stride = (size_t)gridDim.x * blockDim.x;
  for (; i < n4; i += stride) {
    const float4 v = in[i];
    const float vv[4] = {v.x, v.y, v.z, v.w};
    u16x4 h, l;
#pragma unroll
    for (int j = 0; j < 4; ++j) {
      const u16 a = f2bf(vv[j]);
      h[j] = a;
      l[j] = f2bf(vv[j] - bf2f(a));
    }
    *(u16x4*)(hi + i * 4) = h;
    *(u16x4*)(lo + i * 4) = l;
  }
}

template <bool WF32, bool WLO>
__global__ void k_tsplit(const float* __restrict__ in, int R, int Cc,
                         u16* __restrict__ hiT, u16* __restrict__ loT,
                         float* __restrict__ f32T) {
  __shared__ float t[32][33];
  const int c0 = blockIdx.x * 32, r0 = blockIdx.y * 32;
  const int tx = threadIdx.x, ty = threadIdx.y;
#pragma unroll
  for (int i = 0; i < 4; ++i)
    t[ty + i * 8][tx] = in[(size_t)(r0 + ty + i * 8) * Cc + (c0 + tx)];
  __syncthreads();
#pragma unroll
  for (int i = 0; i < 4; ++i) {
    const int orow = c0 + ty + i * 8;
    const int ocol = r0 + tx;
    const float v = t[tx][ty + i * 8];
    const size_t o = (size_t)orow * R + ocol;
    const u16 hi = f2bf(v);
    hiT[o] = hi;
    if (WLO) loT[o] = f2bf(v - bf2f(hi));
    if (WF32) f32T[o] = v;
  }
}

__global__ __launch_bounds__(256)
void k_rownorm(const float* __restrict__ in, float* __restrict__ out,
               unsigned int* __restrict__ maxb, int domax) {
  const int r = blockIdx.x, tid = threadIdx.x;
  const float4 v = *(const float4*)(in + (size_t)r * 1024 + tid * 4);
  double s = (double)v.x * v.x + (double)v.y * v.y +
             (double)v.z * v.z + (double)v.w * v.w;
#pragma unroll
  for (int off = 32; off >= 1; off >>= 1) s += __shfl_xor(s, off, 64);
  __shared__ double sw[4];
  if ((tid & 63) == 0) sw[tid >> 6] = s;
  __syncthreads();
  if (tid == 0) {
    const float t = (float)(sw[0] + sw[1] + sw[2] + sw[3]);
    out[r] = t;
    if (domax) atomicMax(maxb, __float_as_uint(t));
  }
}

__global__ void k_init(double* __restrict__ dacc, unsigned int* __restrict__ emaxb,
                       int* __restrict__ candcnt) {
  const int i = blockIdx.x * blockDim.x + threadIdx.x;
  if (i == 0) { *dacc = 0.0; *emaxb = 0u; }
  if (i < B_) candcnt[i] = 0;
}

// -------- finalize: gather + LayerNorm + commitment partial ---------------
__global__ __launch_bounds__(256)
void k_finalize(const int* __restrict__ idx,
                const float* __restrict__ embT, const float* __restrict__ zf,
                const float* __restrict__ gamma, const float* __restrict__ beta,
                float* __restrict__ out, double* __restrict__ dacc) {
  const int row = blockIdx.x;
  const int tid = threadIdx.x;
  const int lane = tid & 63, w = tid >> 6;
  const int id = idx[row];

  const float4 e4 = *(const float4*)(embT + (size_t)id * C_ + tid * 4);
  float s1 = e4.x + e4.y + e4.z + e4.w;
  float s2 = e4.x * e4.x + e4.y * e4.y + e4.z * e4.z + e4.w * e4.w;
#pragma unroll
  for (int off = 32; off >= 1; off >>= 1) {
    s1 += __shfl_xor(s1, off, 64);
    s2 += __shfl_xor(s2, off, 64);
  }
  __shared__ float r1[4], r2[4], rd[4];
  if (lane == 0) { r1[w] = s1; r2[w] = s2; }
  __syncthreads();
  const float S1 = r1[0] + r1[1] + r1[2] + r1[3];
  const float S2 = r2[0] + r2[1] + r2[2] + r2[3];
  const float mu = S1 * (1.f / C_);
  const float var = S2 * (1.f / C_) - mu * mu;
  const float inv = 1.f / sqrtf(var + 1e-5f);

  const float4 z4 = *(const float4*)(zf + (size_t)row * C_ + tid * 4);
  const float4 g4 = *(const float4*)(gamma + tid * 4);
  const float4 b4 = *(const float4*)(beta + tid * 4);
  float4 o4;
  o4.x = (e4.x - mu) * inv * g4.x + b4.x;
  o4.y = (e4.y - mu) * inv * g4.y + b4.y;
  o4.z = (e4.z - mu) * inv * g4.z + b4.z;
  o4.w = (e4.w - mu) * inv * g4.w + b4.w;
  *(float4*)(out + (size_t)row * C_ + tid * 4) = o4;

  const float dx = e4.x - z4.x, dy = e4.y - z4.y, dz = e4.z - z4.z, dw = e4.w - z4.w;
  float d = dx * dx + dy * dy + dz * dz + dw * dw;
#pragma unroll
  for (int off = 32; off >= 1; off >>= 1) d += __shfl_xor(d, off, 64);
  __syncthreads();
  if (lane == 0) rd[w] = d;
  __syncthreads();
  if (tid == 0) atomicAdd(dacc, (double)(rd[0] + rd[1] + rd[2] + rd[3]));
}

__global__ void k_wdiff(const double* __restrict__ dacc, float* __restrict__ out) {
  out[(size_t)B_ * C_] = (float)(0.01 * (*dacc) / ((double)B_ * (double)C_));
}

// ---------------------------------------------------------------------------
extern "C" void kernel_launch(void* const* d_in, const int* in_sizes, int n_in,
                              void* d_out, int out_size, void* d_ws, size_t ws_size,
                              hipStream_t stream) {
  const float* x     = (const float*)d_in[0];
  const float* W1    = (const float*)d_in[1];
  const float* b1    = (const float*)d_in[2];
  const float* W2    = (const float*)d_in[3];
  const float* b2    = (const float*)d_in[4];
  const float* gamma = (const float*)d_in[5];
  const float* beta  = (const float*)d_in[6];
  const float* embed = (const float*)d_in[7];
  float* out = (float*)d_out;

  char* ws = (char*)d_ws;
  const size_t M = 1048576ull;
  u16* xh  = (u16*)(ws);
  u16* xl  = (u16*)(ws + 64 * M);
  u16* w1h = (u16*)(ws + 128 * M);
  u16* w1l = (u16*)(ws + 160 * M);
  u16* hh  = (u16*)(ws + 192 * M);
  u16* hl  = (u16*)(ws + 256 * M);
  u16* w2h = (u16*)(ws);
  u16* w2l = (u16*)(ws + 8 * M);
  float* zf = (float*)(ws + 16 * M);
  u16* zh  = (u16*)(ws + 48 * M);
  float* embT = (float*)(ws + 64 * M);
  u16* eh  = (u16*)(ws + 96 * M);
  float* norms = (float*)(ws + 112 * M);
  float* zn2   = (float*)(ws + 112 * M + 65536ull);
  int* candcnt = (int*)(ws + 112 * M + 131072ull);
  int* idx     = (int*)(ws + 112 * M + 196608ull);
  unsigned int* emaxb = (unsigned int*)(ws + 112 * M + 262144ull);
  double* dacc = (double*)(ws + 112 * M + 262144ull + 64ull);
  unsigned long long* cand = (unsigned long long*)(ws + 113 * M);  // 16 MB

  (void)hipFuncSetAttribute((const void*)k_gemm1,
                            hipFuncAttributeMaxDynamicSharedMemorySize, 131072);

  // 1. split x -> xh/xl
  k_split<<<2048, 256, 0, stream>>>((const float4*)x, (size_t)B_ * D_ / 4, xh, xl);
  // 2. W1 [D][4C] -> W1T hi/lo [4C][D]
  k_tsplit<false, true><<<dim3(C4_ / 32, D_ / 32), dim3(32, 8), 0, stream>>>(W1, D_, C4_, w1h, w1l, nullptr);
  // 3. GEMM1 (256^2 8-phase; +bias+SiLU+split)
  k_gemm1<<<(B_ / 256) * (C4_ / 256), 512, 131072, stream>>>(xh, xl, w1h, w1l, b1, hh, hl);
  // 4. W2 [4C][C] -> W2T hi/lo [C][4C]
  k_tsplit<false, true><<<dim3(C_ / 32, C4_ / 32), dim3(32, 8), 0, stream>>>(W2, C4_, C_, w2h, w2l, nullptr);
  // 5. GEMM2 (R6-verified 128^2; +bias, write z f32 + bf16 hi)
  k_gemm2<<<(B_ / BM) * (C_ / BN), 256, 0, stream>>>(hh, hl, w2h, w2l, b2, zf, zh);
  // 6. embed [C][K] -> embT f32 + bf16 hi [K][C]
  k_tsplit<true, false><<<dim3(K_ / 32, C_ / 32), dim3(32, 8), 0, stream>>>(embed, C_, K_, eh, nullptr, embT);
  // 7. init accumulators + candidate counters
  k_init<<<B_ / 256, 256, 0, stream>>>(dacc, emaxb, candcnt);
  // 8. norms (coalesced, f64) + max; z row norms
  k_rownorm<<<K_, 256, 0, stream>>>(embT, norms, emaxb, 1);
  k_rownorm<<<B_, 256, 0, stream>>>(zf, zn2, emaxb, 0);
  // 9. GEMM3 v2 (256^2, 1-phase/tile, 2-deep prefetch) + fused candidates
  k_gemm3<<<(B_ / 256) * (K_ / 256), 512, 0, stream>>>(zh, eh, norms, zn2, emaxb, cand, candcnt);
  // 10. sc-prefilter + exact f64 rescore -> final indices
  k_rescore<<<B_, 64, 0, stream>>>(cand, candcnt, zf, embT, zn2, emaxb, idx);
  // 11. gather + LayerNorm + commitment
  k_finalize<<<B_, 256, 0, stream>>>(idx, embT, zf, gamma, beta, out, dacc);
  // 12. scalar diff output
  k_wdiff<<<1, 1, 0, stream>>>(dacc, out);
}

// Round 9
// 1285.406 us; speedup vs baseline: 1.2190x; 1.1494x over previous
//
#include <hip/hip_runtime.h>
#include <stdint.h>

typedef unsigned short u16;
typedef __attribute__((ext_vector_type(4))) float f32x4;
typedef __attribute__((ext_vector_type(8))) __bf16 bf16x8;
typedef __attribute__((ext_vector_type(4))) u16 u16x4;

#define B_  8192
#define D_  4096
#define C4_ 4096
#define C_  1024
#define K_  8192
#define BM  128
#define BN  128
#define CAP 64

__device__ __forceinline__ void load_lds16(const void* g, void* l) {
  __builtin_amdgcn_global_load_lds(
      (const __attribute__((address_space(1))) unsigned int*)g,
      (__attribute__((address_space(3))) unsigned int*)l, 16, 0, 0);
}

__device__ __forceinline__ u16 f2bf(float v) {
  unsigned int u = __float_as_uint(v);
  return (u16)((u + 0x7FFFu + ((u >> 16) & 1u)) >> 16);   // RNE
}
__device__ __forceinline__ float bf2f(u16 u) {
  return __uint_as_float(((unsigned int)u) << 16);
}
__device__ __forceinline__ u16 f2h(float v) {
  _Float16 h = (_Float16)v; u16 b; __builtin_memcpy(&b, &h, 2); return b;
}
__device__ __forceinline__ float h2f(u16 b) {
  _Float16 h; __builtin_memcpy(&h, &b, 2); return (float)h;
}

#define VMW(N) asm volatile("s_waitcnt vmcnt(" #N ")" ::: "memory")
#define BARR() asm volatile("s_barrier" ::: "memory")

// ===================== GEMM1: 256x256 tile, 8-phase counted-vmcnt =========
// (R6-verified; unchanged.) 512 thr (8 waves 2Mx4N), BK=32, 2 K-tiles/iter,
// 3-product split-bf16. LDS 128 KB. Swizzle slot ^= (row>>1)&3 both sides.
// Waits steady [3,4,5,6]x2; final-iter drain [3,2,1,0]. 24 MFMA/phase.

#define STAGE_BX(P, GPTR, LOFF, k0)                                          \
  { load_lds16((GPTR) + sB_base + (size_t)(k0),                              \
               lds + (P) * 32768 + (LOFF) + w * 512);                        \
    load_lds16((GPTR) + sB_base + (size_t)128 * Ksz + (size_t)(k0),          \
               lds + (P) * 32768 + (LOFF) + 4096 + w * 512); }

#define STAGE_A1(P, j, k0)                                                   \
  { load_lds16(Asrc + sA_base + (size_t)((j) * 32) * Ksz + (size_t)(k0),     \
               lds + (P) * 32768 + aldsb + (j) * 1024); }

#define LOAD_B(P)                                                            \
  { const u16* bb = lds + (P) * 32768;                                       \
    _Pragma("unroll") for (int n = 0; n < 4; ++n) {                          \
      bhf[n] = *(const bf16x8*)(bb + ardB + n * 512);                        \
      blf[n] = *(const bf16x8*)(bb + 8192 + ardB + n * 512); } }

#define PH_A(P, Q, ...)                                                      \
  { const u16* bb = lds + (P) * 32768;                                       \
    const bf16x8 a0h = *(const bf16x8*)(bb + ardA + ((Q)*2 + 0) * 512);      \
    const bf16x8 a0l = *(const bf16x8*)(bb + 8192 + ardA + ((Q)*2+0) * 512); \
    const bf16x8 a1h = *(const bf16x8*)(bb + ardA + ((Q)*2 + 1) * 512);      \
    const bf16x8 a1l = *(const bf16x8*)(bb + 8192 + ardA + ((Q)*2+1) * 512); \
    __VA_ARGS__                                                              \
    __builtin_amdgcn_s_setprio(1);                                           \
    _Pragma("unroll") for (int n = 0; n < 4; ++n) {                          \
      acc[(Q)*2+0][n] = __builtin_amdgcn_mfma_f32_16x16x32_bf16(a0h, bhf[n], acc[(Q)*2+0][n], 0,0,0); \
      acc[(Q)*2+0][n] = __builtin_amdgcn_mfma_f32_16x16x32_bf16(a0l, bhf[n], acc[(Q)*2+0][n], 0,0,0); \
      acc[(Q)*2+0][n] = __builtin_amdgcn_mfma_f32_16x16x32_bf16(a0h, blf[n], acc[(Q)*2+0][n], 0,0,0); \
      acc[(Q)*2+1][n] = __builtin_amdgcn_mfma_f32_16x16x32_bf16(a1h, bhf[n], acc[(Q)*2+1][n], 0,0,0); \
      acc[(Q)*2+1][n] = __builtin_amdgcn_mfma_f32_16x16x32_bf16(a1l, bhf[n], acc[(Q)*2+1][n], 0,0,0); \
      acc[(Q)*2+1][n] = __builtin_amdgcn_mfma_f32_16x16x32_bf16(a1h, blf[n], acc[(Q)*2+1][n], 0,0,0); \
    }                                                                        \
    __builtin_amdgcn_s_setprio(0); }

__global__ __launch_bounds__(512, 2)
void k_gemm1(const u16* __restrict__ xh, const u16* __restrict__ xl,
             const u16* __restrict__ w1h, const u16* __restrict__ w1l,
             const float* __restrict__ b1,
             u16* __restrict__ hh, u16* __restrict__ hl) {
  extern __shared__ u16 lds[];
  const int tid = threadIdx.x;
  const int lane = tid & 63;
  const int w = tid >> 6;
  const int wr = w >> 2, wc = w & 3;
  const int rlow = lane & 15;
  const size_t Ksz = D_;
  const int nbn = C4_ / 256;
  const int bm = blockIdx.x / nbn, bn = blockIdx.x % nbn;
  const int rowA0 = bm * 256, rowB0 = bn * 256;
  const u16* __restrict__ Bhg = w1h;
  const u16* __restrict__ Blg = w1l;
  const u16* __restrict__ Asrc = (w < 4) ? xh : xl;

  const int gslot8 = (((lane & 3) ^ ((lane >> 3) & 3)) << 3);
  const size_t sB_base = (size_t)(rowB0 + w * 16 + (lane >> 2)) * Ksz + gslot8;
  const size_t sA_base =
      (size_t)(rowA0 + ((w >> 1) & 1) * 128 + (w & 1) * 16 + (lane >> 2)) * Ksz + gslot8;
  const int aldsb = ((w < 4) ? 0 : 8192) + ((w >> 1) & 1) * 4096 + (w & 1) * 512;

  const int aslot8 = (((lane >> 4) ^ ((lane >> 1) & 3)) << 3);
  const int ardA = wr * 4096 + rlow * 32 + aslot8;
  const int ardB = 16384 + wc * 2048 + rlow * 32 + aslot8;

  f32x4 acc[8][4];
#pragma unroll
  for (int m = 0; m < 8; ++m)
#pragma unroll
    for (int n = 0; n < 4; ++n) acc[m][n] = (f32x4){0.f, 0.f, 0.f, 0.f};
  bf16x8 bhf[4], blf[4];

  STAGE_BX(0, Bhg, 16384, 0); STAGE_BX(0, Blg, 24576, 0);
  STAGE_A1(0, 0, 0); STAGE_A1(0, 1, 0); STAGE_A1(0, 2, 0); STAGE_A1(0, 3, 0);

  const int NIT = (int)(Ksz / 64);
  for (int t = 0; t < NIT - 1; ++t) {
    const int k1 = t * 64 + 32;
    const int k2 = t * 64 + 64;
    VMW(3); BARR(); LOAD_B(0); PH_A(0, 0, STAGE_BX(1, Bhg, 16384, k1);)
    VMW(4); BARR();            PH_A(0, 1, STAGE_BX(1, Blg, 24576, k1);)
    VMW(5); BARR();            PH_A(0, 2, STAGE_A1(1, 0, k1); STAGE_A1(1, 1, k1);)
    VMW(6); BARR();            PH_A(0, 3, STAGE_A1(1, 2, k1); STAGE_A1(1, 3, k1);)
    VMW(3); BARR(); LOAD_B(1); PH_A(1, 0, STAGE_BX(0, Bhg, 16384, k2);)
    VMW(4); BARR();            PH_A(1, 1, STAGE_BX(0, Blg, 24576, k2);)
    VMW(5); BARR();            PH_A(1, 2, STAGE_A1(0, 0, k2); STAGE_A1(0, 1, k2);)
    VMW(6); BARR();            PH_A(1, 3, STAGE_A1(0, 2, k2); STAGE_A1(0, 3, k2);)
  }
  {
    const int k1 = (NIT - 1) * 64 + 32;
    VMW(3); BARR(); LOAD_B(0); PH_A(0, 0, STAGE_BX(1, Bhg, 16384, k1);)
    VMW(4); BARR();            PH_A(0, 1, STAGE_BX(1, Blg, 24576, k1);)
    VMW(5); BARR();            PH_A(0, 2, STAGE_A1(1, 0, k1); STAGE_A1(1, 1, k1);)
    VMW(6); BARR();            PH_A(0, 3, STAGE_A1(1, 2, k1); STAGE_A1(1, 3, k1);)
    VMW(3); BARR(); LOAD_B(1); PH_A(1, 0, )
    VMW(2); BARR();            PH_A(1, 1, )
    VMW(1); BARR();            PH_A(1, 2, )
    VMW(0); BARR();            PH_A(1, 3, )
  }

#pragma unroll
  for (int m = 0; m < 8; ++m)
#pragma unroll
    for (int n = 0; n < 4; ++n)
#pragma unroll
      for (int j = 0; j < 4; ++j) {
        const int rg = rowA0 + wr * 128 + m * 16 + (lane >> 4) * 4 + j;
        const int cg = rowB0 + wc * 64 + n * 16 + rlow;
        const float v = acc[m][n][j] + b1[cg];
        const float s = v / (1.f + __expf(-v));
        const size_t o = (size_t)rg * C4_ + cg;
        const u16 hi = f2bf(s);
        hh[o] = hi;
        hl[o] = f2bf(s - bf2f(hi));
      }
}

// ============ 128x128 split-bf16 mainloop (R2-verified) for GEMM2 =========
__device__ __forceinline__ void mfma_mainloop(
    const u16* __restrict__ Ah, const u16* __restrict__ Al,
    const u16* __restrict__ Bh, const u16* __restrict__ Bl,
    int K, int rowA0, int rowB0, u16* lds, f32x4 acc[4][4]) {
  const int tid = threadIdx.x;
  const int lane = tid & 63;
  const int w = tid >> 6;
  const int wr = w >> 1, wc = w & 1;

  u16* As_h = lds;            // [128][64]
  u16* As_l = lds + 8192;
  u16* Bs_h = lds + 16384;
  u16* Bs_l = lds + 24576;

#pragma unroll
  for (int m = 0; m < 4; ++m)
#pragma unroll
    for (int n = 0; n < 4; ++n) acc[m][n] = (f32x4){0.f, 0.f, 0.f, 0.f};

  const int rstage = w * 8 + (lane >> 3);
  const int estage = (((lane & 7) ^ (lane >> 3)) << 3);

  for (int k0 = 0; k0 < K; k0 += 64) {
#pragma unroll
    for (int c = 0; c < 4; ++c) {
      const int r = c * 32 + rstage;
      const size_t ga = (size_t)(rowA0 + r) * K + (k0 + estage);
      const size_t gb = (size_t)(rowB0 + r) * K + (k0 + estage);
      const int lo = (c * 32 + w * 8) * 64;
      load_lds16(Ah + ga, As_h + lo);
      load_lds16(Al + ga, As_l + lo);
      load_lds16(Bh + gb, Bs_h + lo);
      load_lds16(Bl + gb, Bs_l + lo);
    }
    __syncthreads();
#pragma unroll
    for (int ks = 0; ks < 2; ++ks) {
      bf16x8 ah[4], al[4], bh[4], bl[4];
      const int kof = (((ks * 4 + (lane >> 4)) ^ (lane & 7)) << 3);
#pragma unroll
      for (int m = 0; m < 4; ++m) {
        const int ra = (wr * 64 + m * 16 + (lane & 15)) * 64 + kof;
        ah[m] = *(const bf16x8*)(As_h + ra);
        al[m] = *(const bf16x8*)(As_l + ra);
      }
#pragma unroll
      for (int n = 0; n < 4; ++n) {
        const int rb = (wc * 64 + n * 16 + (lane & 15)) * 64 + kof;
        bh[n] = *(const bf16x8*)(Bs_h + rb);
        bl[n] = *(const bf16x8*)(Bs_l + rb);
      }
#pragma unroll
      for (int m = 0; m < 4; ++m)
#pragma unroll
        for (int n = 0; n < 4; ++n) {
          acc[m][n] = __builtin_amdgcn_mfma_f32_16x16x32_bf16(ah[m], bh[n], acc[m][n], 0, 0, 0);
          acc[m][n] = __builtin_amdgcn_mfma_f32_16x16x32_bf16(al[m], bh[n], acc[m][n], 0, 0, 0);
          acc[m][n] = __builtin_amdgcn_mfma_f32_16x16x32_bf16(ah[m], bl[n], acc[m][n], 0, 0, 0);
        }
    }
    __syncthreads();
  }
}

// -------- GEMM2: z = h@W2 + b2, write z f32 + bf16 hi (R6-verified) -------
__global__ __launch_bounds__(256, 2)
void k_gemm2(const u16* __restrict__ ah, const u16* __restrict__ al,
             const u16* __restrict__ bh, const u16* __restrict__ bl,
             const float* __restrict__ b2,
             float* __restrict__ zf, u16* __restrict__ zh) {
  __shared__ u16 lds[32768];
  const int nbn = C_ / BN;
  const int bm = blockIdx.x / nbn, bn = blockIdx.x % nbn;
  f32x4 acc[4][4];
  mfma_mainloop(ah, al, bh, bl, C4_, bm * BM, bn * BN, lds, acc);
  const int lane = threadIdx.x & 63, w = threadIdx.x >> 6;
  const int wr = w >> 1, wc = w & 1;
#pragma unroll
  for (int m = 0; m < 4; ++m)
#pragma unroll
    for (int n = 0; n < 4; ++n)
#pragma unroll
      for (int j = 0; j < 4; ++j) {
        const int rg = bm * BM + wr * 64 + m * 16 + (lane >> 4) * 4 + j;
        const int cg = bn * BN + wc * 64 + n * 16 + (lane & 15);
        const float v = acc[m][n][j] + b2[cg];
        const size_t o = (size_t)rg * C_ + cg;
        zf[o] = v;
        zh[o] = f2bf(v);
      }
}

// ===== GEMM3 v3: 256x256, BK=64, ONE long step/tile, writes dotm f16 ======
// Mirrors gemm1's per-wave ledger: 8 loads/wave/step (4 A + 4 B chunks of
// 8 rows), steady VMW(8) (flight = one full step: 64 MFMA + 24 ds_read),
// drain VMW(0) at final tile only. LDS 2 bufs x (As[256][64] 32KB |
// Bs[256][64] 32KB) = 128 KB dynamic (1 block/CU — gemm1's proven regime).
// Swizzle = R2-verified 8-slot form on both sides. Selection reverted to
// the R6-proven dotm + global-window scan (R7/R8's local-window collection
// overflowed CAP -> full-scan fallbacks were the +200us regression).

#define G3_STG(P, k0)                                                        \
  _Pragma("unroll") for (int jj = 0; jj < 4; ++jj) {                         \
    load_lds16(zh + aA_base + (size_t)(jj * 8) * 1024 + (size_t)(k0),        \
               lds + (P) * 32768 + (w * 4 + jj) * 512);                      \
    load_lds16(eh + aB_base + (size_t)(jj * 8) * 1024 + (size_t)(k0),        \
               lds + (P) * 32768 + 16384 + (w * 4 + jj) * 512);              \
  }

#define G3_COMP(P)                                                           \
  { const u16* ab = lds + (P) * 32768;                                       \
    const u16* bb = lds + (P) * 32768 + 16384;                               \
    _Pragma("unroll") for (int ks = 0; ks < 2; ++ks) {                       \
      const int kof = (((ks * 4 + (lane >> 4)) ^ (lane & 7)) << 3);          \
      bf16x8 af[8], bfv[4];                                                  \
      _Pragma("unroll") for (int m = 0; m < 8; ++m)                          \
        af[m] = *(const bf16x8*)(ab + (wr * 128 + m * 16 + rlow) * 64 + kof);\
      _Pragma("unroll") for (int n = 0; n < 4; ++n)                          \
        bfv[n] = *(const bf16x8*)(bb + (wc * 64 + n * 16 + rlow) * 64 + kof);\
      __builtin_amdgcn_s_setprio(1);                                         \
      _Pragma("unroll") for (int m = 0; m < 8; ++m)                          \
        _Pragma("unroll") for (int n = 0; n < 4; ++n)                        \
          acc[m][n] = __builtin_amdgcn_mfma_f32_16x16x32_bf16(af[m], bfv[n], acc[m][n], 0, 0, 0); \
      __builtin_amdgcn_s_setprio(0);                                         \
    } }

__global__ __launch_bounds__(512, 2)
void k_gemm3(const u16* __restrict__ zh, const u16* __restrict__ eh,
             u16* __restrict__ dotm) {
  extern __shared__ u16 lds[];
  const int tid = threadIdx.x;
  const int lane = tid & 63;
  const int w = tid >> 6;
  const int wr = w >> 2, wc = w & 3;
  const int rlow = lane & 15;
  const int nbn = K_ / 256;
  const int bm = blockIdx.x / nbn, bn = blockIdx.x % nbn;
  const int rowA0 = bm * 256, rowB0 = bn * 256;

  const int gsl = (((lane & 7) ^ (lane >> 3)) << 3);   // pre-swizzled slot
  const size_t aA_base = (size_t)(rowA0 + w * 32 + (lane >> 3)) * 1024 + gsl;
  const size_t aB_base = (size_t)(rowB0 + w * 32 + (lane >> 3)) * 1024 + gsl;

  f32x4 acc[8][4];
#pragma unroll
  for (int m = 0; m < 8; ++m)
#pragma unroll
    for (int n = 0; n < 4; ++n) acc[m][n] = (f32x4){0.f, 0.f, 0.f, 0.f};

  // prologue: tiles 0 -> buf0, 1 -> buf1 (8 loads/wave each)
  G3_STG(0, 0); G3_STG(1, 64);

  for (int t = 0; t < 14; ++t) {
    VMW(8); BARR();
    G3_COMP(t & 1);
    BARR();
    G3_STG(t & 1, (t + 2) * 64);
  }
  VMW(8); BARR(); G3_COMP(0); BARR();
  VMW(0); BARR(); G3_COMP(1);

  // epilogue: repack acc -> f16 dotm via LDS in 4 passes of 64 rows
  __syncthreads();
  u16* ldsw = lds;   // 32 KB repack region
#pragma unroll
  for (int p = 0; p < 4; ++p) {
    if (wr == (p >> 1)) {
      const int mb = (p & 1) * 4;
#pragma unroll
      for (int mm = 0; mm < 4; ++mm)
#pragma unroll
        for (int n = 0; n < 4; ++n)
#pragma unroll
          for (int j = 0; j < 4; ++j) {
            const int rl = mm * 16 + (lane >> 4) * 4 + j;     // 0..63
            const int cl = wc * 64 + n * 16 + rlow;
            ldsw[rl * 256 + cl] = f2h(acc[mb + mm][n][j]);
          }
    }
    __syncthreads();
    for (int i = tid; i < 2048; i += 512) {
      const int r = i >> 5, c = (i & 31) * 8;
      *(uint4*)(dotm + (size_t)(rowA0 + p * 64 + r) * K_ + rowB0 + c) =
          *(const uint4*)(ldsw + r * 256 + c);
    }
    __syncthreads();
  }
}

// -------- scan: per-row min + candidates within rigorous bound (R6) -------
// sc_k = norms_k - 2*h2f(dotm[r][k]).  |sc_k - true_k| <= Bnd where
// Bnd = 0.010*||z||*||e||max + 0.01. Candidate set {k: sc_k <= min + 2Bnd}
// provably contains the true argmin.
__global__ __launch_bounds__(256)
void k_scan(const u16* __restrict__ dotm, const float* __restrict__ norms,
            const float* __restrict__ zn2, const unsigned int* __restrict__ emaxb,
            int* __restrict__ cand, int* __restrict__ candcnt) {
  __shared__ __align__(16) u16 srow[K_];
  __shared__ float rmin[4];
  __shared__ int lcnt;
  const int r = blockIdx.x, tid = threadIdx.x;
  const size_t base = (size_t)r * K_;
  for (int i = tid; i < K_ / 8; i += 256)
    ((uint4*)srow)[i] = ((const uint4*)(dotm + base))[i];
  if (tid == 0) lcnt = 0;
  __syncthreads();
  float mymin = 3.4e38f;
  for (int k = tid; k < K_; k += 256)
    mymin = fminf(mymin, norms[k] - 2.f * h2f(srow[k]));
#pragma unroll
  for (int off = 32; off >= 1; off >>= 1)
    mymin = fminf(mymin, __shfl_xor(mymin, off, 64));
  if ((tid & 63) == 0) rmin[tid >> 6] = mymin;
  __syncthreads();
  const float gmin = fminf(fminf(rmin[0], rmin[1]), fminf(rmin[2], rmin[3]));
  const float bnd = 0.010f * sqrtf(zn2[r]) * sqrtf(__uint_as_float(*emaxb)) + 0.01f;
  const float win = gmin + 2.f * bnd;
  for (int k = tid; k < K_; k += 256) {
    const float sc = norms[k] - 2.f * h2f(srow[k]);
    if (sc <= win) {
      const int p = atomicAdd(&lcnt, 1);
      if (p < CAP) cand[r * CAP + p] = k;
    }
  }
  __syncthreads();
  if (tid == 0) candcnt[r] = lcnt;
}

// -------- rescore: exact f64 distance over candidates (R6) ----------------
__global__ __launch_bounds__(64)
void k_rescore(const int* __restrict__ cand, const int* __restrict__ candcnt,
               const float* __restrict__ zf, const float* __restrict__ embT,
               int* __restrict__ idx) {
  const int r = blockIdx.x, lane = threadIdx.x;
  const int cnt = candcnt[r];
  if (cnt <= 1) { if (lane == 0) idx[r] = cand[r * CAP]; return; }
  const bool full = cnt > CAP;           // never expected; rigorous fallback
  const int n = full ? K_ : cnt;
  double bestd = 1e300; int bestk = 0x7fffffff;
  for (int c = 0; c < n; ++c) {
    const int k = full ? c : cand[r * CAP + c];
    double s = 0.0;
    for (int i = lane; i < C_; i += 64) {
      const double d = (double)zf[(size_t)r * C_ + i] - (double)embT[(size_t)k * C_ + i];
      s += d * d;
    }
#pragma unroll
    for (int off = 32; off >= 1; off >>= 1) s += __shfl_xor(s, off, 64);
    if (s < bestd || (s == bestd && k < bestk)) { bestd = s; bestk = k; }
  }
  if (lane == 0) idx[r] = bestk;
}

// -------- prep kernels ----------------------------------------------------
__global__ void k_split(const float4* __restrict__ in, size_t n4,
                        u16* __restrict__ hi, u16* __restrict__ lo) {
  size_t i = (size_t)blockIdx.x * blockDim.x + threadIdx.x;
  const size_t stride = (size_t)gridDim.x * blockDim.x;
  for (; i < n4; i += stride) {
    const float4 v = in[i];
    const float vv[4] = {v.x, v.y, v.z, v.w};
    u16x4 h, l;
#pragma unroll
    for (int j = 0; j < 4; ++j) {
      const u16 a = f2bf(vv[j]);
      h[j] = a;
      l[j] = f2bf(vv[j] - bf2f(a));
    }
    *(u16x4*)(hi + i * 4) = h;
    *(u16x4*)(lo + i * 4) = l;
  }
}

template <bool WF32, bool WLO>
__global__ void k_tsplit(const float* __restrict__ in, int R, int Cc,
                         u16* __restrict__ hiT, u16* __restrict__ loT,
                         float* __restrict__ f32T) {
  __shared__ float t[32][33];
  const int c0 = blockIdx.x * 32, r0 = blockIdx.y * 32;
  const int tx = threadIdx.x, ty = threadIdx.y;
#pragma unroll
  for (int i = 0; i < 4; ++i)
    t[ty + i * 8][tx] = in[(size_t)(r0 + ty + i * 8) * Cc + (c0 + tx)];
  __syncthreads();
#pragma unroll
  for (int i = 0; i < 4; ++i) {
    const int orow = c0 + ty + i * 8;
    const int ocol = r0 + tx;
    const float v = t[tx][ty + i * 8];
    const size_t o = (size_t)orow * R + ocol;
    const u16 hi = f2bf(v);
    hiT[o] = hi;
    if (WLO) loT[o] = f2bf(v - bf2f(hi));
    if (WF32) f32T[o] = v;
  }
}

__global__ __launch_bounds__(256)
void k_rownorm(const float* __restrict__ in, float* __restrict__ out,
               unsigned int* __restrict__ maxb, int domax) {
  const int r = blockIdx.x, tid = threadIdx.x;
  const float4 v = *(const float4*)(in + (size_t)r * 1024 + tid * 4);
  double s = (double)v.x * v.x + (double)v.y * v.y +
             (double)v.z * v.z + (double)v.w * v.w;
#pragma unroll
  for (int off = 32; off >= 1; off >>= 1) s += __shfl_xor(s, off, 64);
  __shared__ double sw[4];
  if ((tid & 63) == 0) sw[tid >> 6] = s;
  __syncthreads();
  if (tid == 0) {
    const float t = (float)(sw[0] + sw[1] + sw[2] + sw[3]);
    out[r] = t;
    if (domax) atomicMax(maxb, __float_as_uint(t));
  }
}

__global__ void k_init(double* __restrict__ dacc, unsigned int* __restrict__ emaxb) {
  *dacc = 0.0;
  *emaxb = 0u;
}

// -------- finalize: gather + LayerNorm + commitment partial ---------------
__global__ __launch_bounds__(256)
void k_finalize(const int* __restrict__ idx,
                const float* __restrict__ embT, const float* __restrict__ zf,
                const float* __restrict__ gamma, const float* __restrict__ beta,
                float* __restrict__ out, double* __restrict__ dacc) {
  const int row = blockIdx.x;
  const int tid = threadIdx.x;
  const int lane = tid & 63, w = tid >> 6;
  const int id = idx[row];

  const float4 e4 = *(const float4*)(embT + (size_t)id * C_ + tid * 4);
  float s1 = e4.x + e4.y + e4.z + e4.w;
  float s2 = e4.x * e4.x + e4.y * e4.y + e4.z * e4.z + e4.w * e4.w;
#pragma unroll
  for (int off = 32; off >= 1; off >>= 1) {
    s1 += __shfl_xor(s1, off, 64);
    s2 += __shfl_xor(s2, off, 64);
  }
  __shared__ float r1[4], r2[4], rd[4];
  if (lane == 0) { r1[w] = s1; r2[w] = s2; }
  __syncthreads();
  const float S1 = r1[0] + r1[1] + r1[2] + r1[3];
  const float S2 = r2[0] + r2[1] + r2[2] + r2[3];
  const float mu = S1 * (1.f / C_);
  const float var = S2 * (1.f / C_) - mu * mu;
  const float inv = 1.f / sqrtf(var + 1e-5f);

  const float4 z4 = *(const float4*)(zf + (size_t)row * C_ + tid * 4);
  const float4 g4 = *(const float4*)(gamma + tid * 4);
  const float4 b4 = *(const float4*)(beta + tid * 4);
  float4 o4;
  o4.x = (e4.x - mu) * inv * g4.x + b4.x;
  o4.y = (e4.y - mu) * inv * g4.y + b4.y;
  o4.z = (e4.z - mu) * inv * g4.z + b4.z;
  o4.w = (e4.w - mu) * inv * g4.w + b4.w;
  *(float4*)(out + (size_t)row * C_ + tid * 4) = o4;

  const float dx = e4.x - z4.x, dy = e4.y - z4.y, dz = e4.z - z4.z, dw = e4.w - z4.w;
  float d = dx * dx + dy * dy + dz * dz + dw * dw;
#pragma unroll
  for (int off = 32; off >= 1; off >>= 1) d += __shfl_xor(d, off, 64);
  __syncthreads();
  if (lane == 0) rd[w] = d;
  __syncthreads();
  if (tid == 0) atomicAdd(dacc, (double)(rd[0] + rd[1] + rd[2] + rd[3]));
}

__global__ void k_wdiff(const double* __restrict__ dacc, float* __restrict__ out) {
  out[(size_t)B_ * C_] = (float)(0.01 * (*dacc) / ((double)B_ * (double)C_));
}

// ---------------------------------------------------------------------------
extern "C" void kernel_launch(void* const* d_in, const int* in_sizes, int n_in,
                              void* d_out, int out_size, void* d_ws, size_t ws_size,
                              hipStream_t stream) {
  const float* x     = (const float*)d_in[0];
  const float* W1    = (const float*)d_in[1];
  const float* b1    = (const float*)d_in[2];
  const float* W2    = (const float*)d_in[3];
  const float* b2    = (const float*)d_in[4];
  const float* gamma = (const float*)d_in[5];
  const float* beta  = (const float*)d_in[6];
  const float* embed = (const float*)d_in[7];
  float* out = (float*)d_out;

  char* ws = (char*)d_ws;
  const size_t M = 1048576ull;
  // phase 1: xh 0..64M, xl 64..128M, w1h 128..160M, w1l 160..192M,
  //          hh 192..256M, hl 256..320M
  // phase 2 (over dead regions): w2h 0..8M, w2l 8..16M, zf 16..48M,
  //          zh 48..64M, embT 64..96M, eh 96..112M, small @112M,
  //          cand 113..115M, dotm 192..320M (over hh/hl)
  u16* xh  = (u16*)(ws);
  u16* xl  = (u16*)(ws + 64 * M);
  u16* w1h = (u16*)(ws + 128 * M);
  u16* w1l = (u16*)(ws + 160 * M);
  u16* hh  = (u16*)(ws + 192 * M);
  u16* hl  = (u16*)(ws + 256 * M);
  u16* w2h = (u16*)(ws);
  u16* w2l = (u16*)(ws + 8 * M);
  float* zf = (float*)(ws + 16 * M);
  u16* zh  = (u16*)(ws + 48 * M);
  float* embT = (float*)(ws + 64 * M);
  u16* eh  = (u16*)(ws + 96 * M);
  float* norms = (float*)(ws + 112 * M);
  float* zn2   = (float*)(ws + 112 * M + 65536ull);
  int* candcnt = (int*)(ws + 112 * M + 131072ull);
  int* idx     = (int*)(ws + 112 * M + 196608ull);
  unsigned int* emaxb = (unsigned int*)(ws + 112 * M + 262144ull);
  double* dacc = (double*)(ws + 112 * M + 262144ull + 64ull);
  int* cand    = (int*)(ws + 113 * M);
  u16* dotm    = (u16*)(ws + 192 * M);

  (void)hipFuncSetAttribute((const void*)k_gemm1,
                            hipFuncAttributeMaxDynamicSharedMemorySize, 131072);
  (void)hipFuncSetAttribute((const void*)k_gemm3,
                            hipFuncAttributeMaxDynamicSharedMemorySize, 131072);

  // 1. split x -> xh/xl
  k_split<<<2048, 256, 0, stream>>>((const float4*)x, (size_t)B_ * D_ / 4, xh, xl);
  // 2. W1 [D][4C] -> W1T hi/lo [4C][D]
  k_tsplit<false, true><<<dim3(C4_ / 32, D_ / 32), dim3(32, 8), 0, stream>>>(W1, D_, C4_, w1h, w1l, nullptr);
  // 3. GEMM1 (256^2 8-phase; +bias+SiLU+split)
  k_gemm1<<<(B_ / 256) * (C4_ / 256), 512, 131072, stream>>>(xh, xl, w1h, w1l, b1, hh, hl);
  // 4. W2 [4C][C] -> W2T hi/lo [C][4C]
  k_tsplit<false, true><<<dim3(C_ / 32, C4_ / 32), dim3(32, 8), 0, stream>>>(W2, C4_, C_, w2h, w2l, nullptr);
  // 5. GEMM2 (R6-verified 128^2; +bias, write z f32 + bf16 hi)
  k_gemm2<<<(B_ / BM) * (C_ / BN), 256, 0, stream>>>(hh, hl, w2h, w2l, b2, zf, zh);
  // 6. embed [C][K] -> embT f32 + bf16 hi [K][C]
  k_tsplit<true, false><<<dim3(K_ / 32, C_ / 32), dim3(32, 8), 0, stream>>>(embed, C_, K_, eh, nullptr, embT);
  // 7. init accumulators
  k_init<<<1, 1, 0, stream>>>(dacc, emaxb);
  // 8. norms (coalesced, f64) + max; z row norms
  k_rownorm<<<K_, 256, 0, stream>>>(embT, norms, emaxb, 1);
  k_rownorm<<<B_, 256, 0, stream>>>(zf, zn2, emaxb, 0);
  // 9. GEMM3 v3 (256^2 BK=64 long-step, counted vmcnt) -> dotm f16
  k_gemm3<<<(B_ / 256) * (K_ / 256), 512, 131072, stream>>>(zh, eh, dotm);
  // 10. per-row min + global-window candidates (R6-proven)
  k_scan<<<B_, 256, 0, stream>>>(dotm, norms, zn2, emaxb, cand, candcnt);
  // 11. exact f64 rescore -> final indices
  k_rescore<<<B_, 64, 0, stream>>>(cand, candcnt, zf, embT, idx);
  // 12. gather + LayerNorm + commitment
  k_finalize<<<B_, 256, 0, stream>>>(idx, embT, zf, gamma, beta, out, dacc);
  // 13. scalar diff output
  k_wdiff<<<1, 1, 0, stream>>>(dacc, out);
}

// Round 10
// 1270.089 us; speedup vs baseline: 1.2337x; 1.0121x over previous
//
#include <hip/hip_runtime.h>
#include <stdint.h>

typedef unsigned short u16;
typedef __attribute__((ext_vector_type(4))) float f32x4;
typedef __attribute__((ext_vector_type(8))) __bf16 bf16x8;
typedef __attribute__((ext_vector_type(4))) u16 u16x4;

#define B_  8192
#define D_  4096
#define C4_ 4096
#define C_  1024
#define K_  8192
#define BM  128
#define BN  128
#define CAP 64

__device__ __forceinline__ void load_lds16(const void* g, void* l) {
  __builtin_amdgcn_global_load_lds(
      (const __attribute__((address_space(1))) unsigned int*)g,
      (__attribute__((address_space(3))) unsigned int*)l, 16, 0, 0);
}

__device__ __forceinline__ u16 f2bf(float v) {
  unsigned int u = __float_as_uint(v);
  return (u16)((u + 0x7FFFu + ((u >> 16) & 1u)) >> 16);   // RNE
}
__device__ __forceinline__ float bf2f(u16 u) {
  return __uint_as_float(((unsigned int)u) << 16);
}
__device__ __forceinline__ u16 f2h(float v) {
  _Float16 h = (_Float16)v; u16 b; __builtin_memcpy(&b, &h, 2); return b;
}
__device__ __forceinline__ float h2f(u16 b) {
  _Float16 h; __builtin_memcpy(&h, &b, 2); return (float)h;
}

#define VMW(N) asm volatile("s_waitcnt vmcnt(" #N ")" ::: "memory")
#define BARR() asm volatile("s_barrier" ::: "memory")

// ===================== GEMM1: 256x256 tile, 8-phase counted-vmcnt =========
// (R6-verified; unchanged.) 512 thr (8 waves 2Mx4N), BK=32, 2 K-tiles/iter,
// 3-product split-bf16. LDS 128 KB. Swizzle slot ^= (row>>1)&3 both sides.
// Waits steady [3,4,5,6]x2; final-iter drain [3,2,1,0]. 24 MFMA/phase.

#define STAGE_BX(P, GPTR, LOFF, k0)                                          \
  { load_lds16((GPTR) + sB_base + (size_t)(k0),                              \
               lds + (P) * 32768 + (LOFF) + w * 512);                        \
    load_lds16((GPTR) + sB_base + (size_t)128 * Ksz + (size_t)(k0),          \
               lds + (P) * 32768 + (LOFF) + 4096 + w * 512); }

#define STAGE_A1(P, j, k0)                                                   \
  { load_lds16(Asrc + sA_base + (size_t)((j) * 32) * Ksz + (size_t)(k0),     \
               lds + (P) * 32768 + aldsb + (j) * 1024); }

#define LOAD_B(P)                                                            \
  { const u16* bb = lds + (P) * 32768;                                       \
    _Pragma("unroll") for (int n = 0; n < 4; ++n) {                          \
      bhf[n] = *(const bf16x8*)(bb + ardB + n * 512);                        \
      blf[n] = *(const bf16x8*)(bb + 8192 + ardB + n * 512); } }

#define PH_A(P, Q, ...)                                                      \
  { const u16* bb = lds + (P) * 32768;                                       \
    const bf16x8 a0h = *(const bf16x8*)(bb + ardA + ((Q)*2 + 0) * 512);      \
    const bf16x8 a0l = *(const bf16x8*)(bb + 8192 + ardA + ((Q)*2+0) * 512); \
    const bf16x8 a1h = *(const bf16x8*)(bb + ardA + ((Q)*2 + 1) * 512);      \
    const bf16x8 a1l = *(const bf16x8*)(bb + 8192 + ardA + ((Q)*2+1) * 512); \
    __VA_ARGS__                                                              \
    __builtin_amdgcn_s_setprio(1);                                           \
    _Pragma("unroll") for (int n = 0; n < 4; ++n) {                          \
      acc[(Q)*2+0][n] = __builtin_amdgcn_mfma_f32_16x16x32_bf16(a0h, bhf[n], acc[(Q)*2+0][n], 0,0,0); \
      acc[(Q)*2+0][n] = __builtin_amdgcn_mfma_f32_16x16x32_bf16(a0l, bhf[n], acc[(Q)*2+0][n], 0,0,0); \
      acc[(Q)*2+0][n] = __builtin_amdgcn_mfma_f32_16x16x32_bf16(a0h, blf[n], acc[(Q)*2+0][n], 0,0,0); \
      acc[(Q)*2+1][n] = __builtin_amdgcn_mfma_f32_16x16x32_bf16(a1h, bhf[n], acc[(Q)*2+1][n], 0,0,0); \
      acc[(Q)*2+1][n] = __builtin_amdgcn_mfma_f32_16x16x32_bf16(a1l, bhf[n], acc[(Q)*2+1][n], 0,0,0); \
      acc[(Q)*2+1][n] = __builtin_amdgcn_mfma_f32_16x16x32_bf16(a1h, blf[n], acc[(Q)*2+1][n], 0,0,0); \
    }                                                                        \
    __builtin_amdgcn_s_setprio(0); }

__global__ __launch_bounds__(512, 2)
void k_gemm1(const u16* __restrict__ xh, const u16* __restrict__ xl,
             const u16* __restrict__ w1h, const u16* __restrict__ w1l,
             const float* __restrict__ b1,
             u16* __restrict__ hh, u16* __restrict__ hl) {
  extern __shared__ u16 lds[];
  const int tid = threadIdx.x;
  const int lane = tid & 63;
  const int w = tid >> 6;
  const int wr = w >> 2, wc = w & 3;
  const int rlow = lane & 15;
  const size_t Ksz = D_;
  const int nbn = C4_ / 256;
  const int bm = blockIdx.x / nbn, bn = blockIdx.x % nbn;
  const int rowA0 = bm * 256, rowB0 = bn * 256;
  const u16* __restrict__ Bhg = w1h;
  const u16* __restrict__ Blg = w1l;
  const u16* __restrict__ Asrc = (w < 4) ? xh : xl;

  const int gslot8 = (((lane & 3) ^ ((lane >> 3) & 3)) << 3);
  const size_t sB_base = (size_t)(rowB0 + w * 16 + (lane >> 2)) * Ksz + gslot8;
  const size_t sA_base =
      (size_t)(rowA0 + ((w >> 1) & 1) * 128 + (w & 1) * 16 + (lane >> 2)) * Ksz + gslot8;
  const int aldsb = ((w < 4) ? 0 : 8192) + ((w >> 1) & 1) * 4096 + (w & 1) * 512;

  const int aslot8 = (((lane >> 4) ^ ((lane >> 1) & 3)) << 3);
  const int ardA = wr * 4096 + rlow * 32 + aslot8;
  const int ardB = 16384 + wc * 2048 + rlow * 32 + aslot8;

  f32x4 acc[8][4];
#pragma unroll
  for (int m = 0; m < 8; ++m)
#pragma unroll
    for (int n = 0; n < 4; ++n) acc[m][n] = (f32x4){0.f, 0.f, 0.f, 0.f};
  bf16x8 bhf[4], blf[4];

  STAGE_BX(0, Bhg, 16384, 0); STAGE_BX(0, Blg, 24576, 0);
  STAGE_A1(0, 0, 0); STAGE_A1(0, 1, 0); STAGE_A1(0, 2, 0); STAGE_A1(0, 3, 0);

  const int NIT = (int)(Ksz / 64);
  for (int t = 0; t < NIT - 1; ++t) {
    const int k1 = t * 64 + 32;
    const int k2 = t * 64 + 64;
    VMW(3); BARR(); LOAD_B(0); PH_A(0, 0, STAGE_BX(1, Bhg, 16384, k1);)
    VMW(4); BARR();            PH_A(0, 1, STAGE_BX(1, Blg, 24576, k1);)
    VMW(5); BARR();            PH_A(0, 2, STAGE_A1(1, 0, k1); STAGE_A1(1, 1, k1);)
    VMW(6); BARR();            PH_A(0, 3, STAGE_A1(1, 2, k1); STAGE_A1(1, 3, k1);)
    VMW(3); BARR(); LOAD_B(1); PH_A(1, 0, STAGE_BX(0, Bhg, 16384, k2);)
    VMW(4); BARR();            PH_A(1, 1, STAGE_BX(0, Blg, 24576, k2);)
    VMW(5); BARR();            PH_A(1, 2, STAGE_A1(0, 0, k2); STAGE_A1(0, 1, k2);)
    VMW(6); BARR();            PH_A(1, 3, STAGE_A1(0, 2, k2); STAGE_A1(0, 3, k2);)
  }
  {
    const int k1 = (NIT - 1) * 64 + 32;
    VMW(3); BARR(); LOAD_B(0); PH_A(0, 0, STAGE_BX(1, Bhg, 16384, k1);)
    VMW(4); BARR();            PH_A(0, 1, STAGE_BX(1, Blg, 24576, k1);)
    VMW(5); BARR();            PH_A(0, 2, STAGE_A1(1, 0, k1); STAGE_A1(1, 1, k1);)
    VMW(6); BARR();            PH_A(0, 3, STAGE_A1(1, 2, k1); STAGE_A1(1, 3, k1);)
    VMW(3); BARR(); LOAD_B(1); PH_A(1, 0, )
    VMW(2); BARR();            PH_A(1, 1, )
    VMW(1); BARR();            PH_A(1, 2, )
    VMW(0); BARR();            PH_A(1, 3, )
  }

#pragma unroll
  for (int m = 0; m < 8; ++m)
#pragma unroll
    for (int n = 0; n < 4; ++n)
#pragma unroll
      for (int j = 0; j < 4; ++j) {
        const int rg = rowA0 + wr * 128 + m * 16 + (lane >> 4) * 4 + j;
        const int cg = rowB0 + wc * 64 + n * 16 + rlow;
        const float v = acc[m][n][j] + b1[cg];
        const float s = v / (1.f + __expf(-v));
        const size_t o = (size_t)rg * C4_ + cg;
        const u16 hi = f2bf(s);
        hh[o] = hi;
        hl[o] = f2bf(s - bf2f(hi));
      }
}

// ============ 128x128 split-bf16 mainloop (R2-verified) for GEMM2 =========
__device__ __forceinline__ void mfma_mainloop(
    const u16* __restrict__ Ah, const u16* __restrict__ Al,
    const u16* __restrict__ Bh, const u16* __restrict__ Bl,
    int K, int rowA0, int rowB0, u16* lds, f32x4 acc[4][4]) {
  const int tid = threadIdx.x;
  const int lane = tid & 63;
  const int w = tid >> 6;
  const int wr = w >> 1, wc = w & 1;

  u16* As_h = lds;            // [128][64]
  u16* As_l = lds + 8192;
  u16* Bs_h = lds + 16384;
  u16* Bs_l = lds + 24576;

#pragma unroll
  for (int m = 0; m < 4; ++m)
#pragma unroll
    for (int n = 0; n < 4; ++n) acc[m][n] = (f32x4){0.f, 0.f, 0.f, 0.f};

  const int rstage = w * 8 + (lane >> 3);
  const int estage = (((lane & 7) ^ (lane >> 3)) << 3);

  for (int k0 = 0; k0 < K; k0 += 64) {
#pragma unroll
    for (int c = 0; c < 4; ++c) {
      const int r = c * 32 + rstage;
      const size_t ga = (size_t)(rowA0 + r) * K + (k0 + estage);
      const size_t gb = (size_t)(rowB0 + r) * K + (k0 + estage);
      const int lo = (c * 32 + w * 8) * 64;
      load_lds16(Ah + ga, As_h + lo);
      load_lds16(Al + ga, As_l + lo);
      load_lds16(Bh + gb, Bs_h + lo);
      load_lds16(Bl + gb, Bs_l + lo);
    }
    __syncthreads();
#pragma unroll
    for (int ks = 0; ks < 2; ++ks) {
      bf16x8 ah[4], al[4], bh[4], bl[4];
      const int kof = (((ks * 4 + (lane >> 4)) ^ (lane & 7)) << 3);
#pragma unroll
      for (int m = 0; m < 4; ++m) {
        const int ra = (wr * 64 + m * 16 + (lane & 15)) * 64 + kof;
        ah[m] = *(const bf16x8*)(As_h + ra);
        al[m] = *(const bf16x8*)(As_l + ra);
      }
#pragma unroll
      for (int n = 0; n < 4; ++n) {
        const int rb = (wc * 64 + n * 16 + (lane & 15)) * 64 + kof;
        bh[n] = *(const bf16x8*)(Bs_h + rb);
        bl[n] = *(const bf16x8*)(Bs_l + rb);
      }
#pragma unroll
      for (int m = 0; m < 4; ++m)
#pragma unroll
        for (int n = 0; n < 4; ++n) {
          acc[m][n] = __builtin_amdgcn_mfma_f32_16x16x32_bf16(ah[m], bh[n], acc[m][n], 0, 0, 0);
          acc[m][n] = __builtin_amdgcn_mfma_f32_16x16x32_bf16(al[m], bh[n], acc[m][n], 0, 0, 0);
          acc[m][n] = __builtin_amdgcn_mfma_f32_16x16x32_bf16(ah[m], bl[n], acc[m][n], 0, 0, 0);
        }
    }
    __syncthreads();
  }
}

// -------- GEMM2: z = h@W2 + b2, write z f32 + bf16 hi (R6-verified) -------
__global__ __launch_bounds__(256, 2)
void k_gemm2(const u16* __restrict__ ah, const u16* __restrict__ al,
             const u16* __restrict__ bh, const u16* __restrict__ bl,
             const float* __restrict__ b2,
             float* __restrict__ zf, u16* __restrict__ zh) {
  __shared__ u16 lds[32768];
  const int nbn = C_ / BN;
  const int bm = blockIdx.x / nbn, bn = blockIdx.x % nbn;
  f32x4 acc[4][4];
  mfma_mainloop(ah, al, bh, bl, C4_, bm * BM, bn * BN, lds, acc);
  const int lane = threadIdx.x & 63, w = threadIdx.x >> 6;
  const int wr = w >> 1, wc = w & 1;
#pragma unroll
  for (int m = 0; m < 4; ++m)
#pragma unroll
    for (int n = 0; n < 4; ++n)
#pragma unroll
      for (int j = 0; j < 4; ++j) {
        const int rg = bm * BM + wr * 64 + m * 16 + (lane >> 4) * 4 + j;
        const int cg = bn * BN + wc * 64 + n * 16 + (lane & 15);
        const float v = acc[m][n][j] + b2[cg];
        const size_t o = (size_t)rg * C_ + cg;
        zf[o] = v;
        zh[o] = f2bf(v);
      }
}

// ===== GEMM3 v4: 256x256, quadrant-phase 8-phase template (gemm1 skeleton)
// 1-product bf16, 512 thr (8 waves 2Mx4N, wave-tile 128x64), BK=64 tiles,
// 2 tiles/iter, 8 phases/iter. Phase (h,ks) = A-half h x kslot ks:
// {4-8 ds_read -> 2 stage-loads -> 16 MFMA}. Per-wave stage order per tile:
// B0,B1,B2,B3, Ah0a,Ah0b, Ah1a,Ah1b (8 loads; every wave contributes to
// each chunk, so ordinal per-wave vmcnt == chunk completeness).
// Waits steady [2,2,-,-]x2; tail [2,0,-,-]. LDS 2 bufs x (As[256][64] |
// Bs[256][64]) = 128 KB dynamic. Swizzle = R2-verified 8-slot form.
// Writes dotm f16 (R9-verified epilogue); R6-proven scan+rescore follow.

#define G3_SB(P, jj, k0)                                                     \
  load_lds16(eh + sB_base + (size_t)((jj) * 8) * 1024 + (size_t)(k0),        \
             lds + (P) * 32768 + 16384 + (w * 32 + (jj) * 8) * 64);
#define G3_SA(P, h, l, k0)                                                   \
  load_lds16(zh + sA_base + (size_t)((h) * 64 + (l) * 8) * 1024 + (size_t)(k0), \
             lds + (P) * 32768 + (aw0 + (h) * 64 + (l) * 8) * 64);
#define G3_RB(P, ks)                                                         \
  { const u16* bb = lds + (P) * 32768 + 16384;                               \
    const int kof = ((((ks) * 4 + (lane >> 4)) ^ (lane & 7)) << 3);          \
    _Pragma("unroll") for (int n = 0; n < 4; ++n)                            \
      bfv[n] = *(const bf16x8*)(bb + (wc * 64 + n * 16 + rlow) * 64 + kof); }
#define G3_PH(P, h, ks, ...)                                                 \
  { const u16* ab = lds + (P) * 32768;                                       \
    const int kof = ((((ks) * 4 + (lane >> 4)) ^ (lane & 7)) << 3);          \
    bf16x8 af[4];                                                            \
    _Pragma("unroll") for (int m = 0; m < 4; ++m)                            \
      af[m] = *(const bf16x8*)(ab + (wr * 128 + (h) * 64 + m * 16 + rlow) * 64 + kof); \
    __VA_ARGS__                                                              \
    __builtin_amdgcn_s_setprio(1);                                           \
    _Pragma("unroll") for (int m = 0; m < 4; ++m)                            \
      _Pragma("unroll") for (int n = 0; n < 4; ++n)                          \
        acc[(h) * 4 + m][n] = __builtin_amdgcn_mfma_f32_16x16x32_bf16(af[m], bfv[n], acc[(h) * 4 + m][n], 0, 0, 0); \
    __builtin_amdgcn_s_setprio(0); }

__global__ __launch_bounds__(512, 2)
void k_gemm3(const u16* __restrict__ zh, const u16* __restrict__ eh,
             u16* __restrict__ dotm) {
  extern __shared__ u16 lds[];
  const int tid = threadIdx.x;
  const int lane = tid & 63;
  const int w = tid >> 6;
  const int wr = w >> 2, wc = w & 3;
  const int rlow = lane & 15;
  const int nbn = K_ / 256;
  const int bm = blockIdx.x / nbn, bn = blockIdx.x % nbn;
  const int rowA0 = bm * 256, rowB0 = bn * 256;

  const int gsl = (((lane & 7) ^ (lane >> 3)) << 3);   // pre-swizzled slot
  const int aw0 = (w >> 2) * 128 + (w & 3) * 16;
  const size_t sB_base = (size_t)(rowB0 + w * 32 + (lane >> 3)) * 1024 + gsl;
  const size_t sA_base = (size_t)(rowA0 + aw0 + (lane >> 3)) * 1024 + gsl;

  f32x4 acc[8][4];
#pragma unroll
  for (int m = 0; m < 8; ++m)
#pragma unroll
    for (int n = 0; n < 4; ++n) acc[m][n] = (f32x4){0.f, 0.f, 0.f, 0.f};
  bf16x8 bfv[4];

  // prologue: tile 0 -> buf0 (B0..B3, Ah0 x2, Ah1 x2 = 8 loads/wave)
  G3_SB(0, 0, 0); G3_SB(0, 1, 0); G3_SB(0, 2, 0); G3_SB(0, 3, 0);
  G3_SA(0, 0, 0, 0); G3_SA(0, 0, 1, 0); G3_SA(0, 1, 0, 0); G3_SA(0, 1, 1, 0);

  for (int t = 0; t < 7; ++t) {
    const int k1 = t * 128 + 64;    // tile 2t+1 -> buf1
    const int k2 = t * 128 + 128;   // tile 2t+2 -> buf0
    VMW(2); BARR(); G3_RB(0, 0); G3_PH(0, 0, 0, G3_SB(1, 0, k1); G3_SB(1, 1, k1);)
    VMW(2); BARR();              G3_PH(0, 1, 0, G3_SB(1, 2, k1); G3_SB(1, 3, k1);)
            BARR(); G3_RB(0, 1); G3_PH(0, 0, 1, G3_SA(1, 0, 0, k1); G3_SA(1, 0, 1, k1);)
            BARR();              G3_PH(0, 1, 1, G3_SA(1, 1, 0, k1); G3_SA(1, 1, 1, k1);)
    VMW(2); BARR(); G3_RB(1, 0); G3_PH(1, 0, 0, G3_SB(0, 0, k2); G3_SB(0, 1, k2);)
    VMW(2); BARR();              G3_PH(1, 1, 0, G3_SB(0, 2, k2); G3_SB(0, 3, k2);)
            BARR(); G3_RB(1, 1); G3_PH(1, 0, 1, G3_SA(0, 0, 0, k2); G3_SA(0, 0, 1, k2);)
            BARR();              G3_PH(1, 1, 1, G3_SA(0, 1, 0, k2); G3_SA(0, 1, 1, k2);)
  }
  { // last iter: stage tile 15 -> buf1; no buf0 stages; drain
    const int k1 = 7 * 128 + 64;
    VMW(2); BARR(); G3_RB(0, 0); G3_PH(0, 0, 0, G3_SB(1, 0, k1); G3_SB(1, 1, k1);)
    VMW(2); BARR();              G3_PH(0, 1, 0, G3_SB(1, 2, k1); G3_SB(1, 3, k1);)
            BARR(); G3_RB(0, 1); G3_PH(0, 0, 1, G3_SA(1, 0, 0, k1); G3_SA(1, 0, 1, k1);)
            BARR();              G3_PH(0, 1, 1, G3_SA(1, 1, 0, k1); G3_SA(1, 1, 1, k1);)
    VMW(2); BARR(); G3_RB(1, 0); G3_PH(1, 0, 0, )
    VMW(0); BARR();              G3_PH(1, 1, 0, )
            BARR(); G3_RB(1, 1); G3_PH(1, 0, 1, )
            BARR();              G3_PH(1, 1, 1, )
  }

  // epilogue: repack acc -> f16 dotm via LDS in 4 passes of 64 rows (R9-ok)
  __syncthreads();
  u16* ldsw = lds;   // 32 KB repack region
#pragma unroll
  for (int p = 0; p < 4; ++p) {
    if (wr == (p >> 1)) {
      const int mb = (p & 1) * 4;
#pragma unroll
      for (int mm = 0; mm < 4; ++mm)
#pragma unroll
        for (int n = 0; n < 4; ++n)
#pragma unroll
          for (int j = 0; j < 4; ++j) {
            const int rl = mm * 16 + (lane >> 4) * 4 + j;     // 0..63
            const int cl = wc * 64 + n * 16 + rlow;
            ldsw[rl * 256 + cl] = f2h(acc[mb + mm][n][j]);
          }
    }
    __syncthreads();
    for (int i = tid; i < 2048; i += 512) {
      const int r = i >> 5, c = (i & 31) * 8;
      *(uint4*)(dotm + (size_t)(rowA0 + p * 64 + r) * K_ + rowB0 + c) =
          *(const uint4*)(ldsw + r * 256 + c);
    }
    __syncthreads();
  }
}

// -------- scan: per-row min + candidates within rigorous bound (R6) -------
// sc_k = norms_k - 2*h2f(dotm[r][k]).  |sc_k - true_k| <= Bnd where
// Bnd = 0.010*||z||*||e||max + 0.01. Candidate set {k: sc_k <= min + 2Bnd}
// provably contains the true argmin.
__global__ __launch_bounds__(256)
void k_scan(const u16* __restrict__ dotm, const float* __restrict__ norms,
            const float* __restrict__ zn2, const unsigned int* __restrict__ emaxb,
            int* __restrict__ cand, int* __restrict__ candcnt) {
  __shared__ __align__(16) u16 srow[K_];
  __shared__ float rmin[4];
  __shared__ int lcnt;
  const int r = blockIdx.x, tid = threadIdx.x;
  const size_t base = (size_t)r * K_;
  for (int i = tid; i < K_ / 8; i += 256)
    ((uint4*)srow)[i] = ((const uint4*)(dotm + base))[i];
  if (tid == 0) lcnt = 0;
  __syncthreads();
  float mymin = 3.4e38f;
  for (int k = tid; k < K_; k += 256)
    mymin = fminf(mymin, norms[k] - 2.f * h2f(srow[k]));
#pragma unroll
  for (int off = 32; off >= 1; off >>= 1)
    mymin = fminf(mymin, __shfl_xor(mymin, off, 64));
  if ((tid & 63) == 0) rmin[tid >> 6] = mymin;
  __syncthreads();
  const float gmin = fminf(fminf(rmin[0], rmin[1]), fminf(rmin[2], rmin[3]));
  const float bnd = 0.010f * sqrtf(zn2[r]) * sqrtf(__uint_as_float(*emaxb)) + 0.01f;
  const float win = gmin + 2.f * bnd;
  for (int k = tid; k < K_; k += 256) {
    const float sc = norms[k] - 2.f * h2f(srow[k]);
    if (sc <= win) {
      const int p = atomicAdd(&lcnt, 1);
      if (p < CAP) cand[r * CAP + p] = k;
    }
  }
  __syncthreads();
  if (tid == 0) candcnt[r] = lcnt;
}

// -------- rescore: exact f64 distance over candidates (R6) ----------------
__global__ __launch_bounds__(64)
void k_rescore(const int* __restrict__ cand, const int* __restrict__ candcnt,
               const float* __restrict__ zf, const float* __restrict__ embT,
               int* __restrict__ idx) {
  const int r = blockIdx.x, lane = threadIdx.x;
  const int cnt = candcnt[r];
  if (cnt <= 1) { if (lane == 0) idx[r] = cand[r * CAP]; return; }
  const bool full = cnt > CAP;           // never expected; rigorous fallback
  const int n = full ? K_ : cnt;
  double bestd = 1e300; int bestk = 0x7fffffff;
  for (int c = 0; c < n; ++c) {
    const int k = full ? c : cand[r * CAP + c];
    double s = 0.0;
    for (int i = lane; i < C_; i += 64) {
      const double d = (double)zf[(size_t)r * C_ + i] - (double)embT[(size_t)k * C_ + i];
      s += d * d;
    }
#pragma unroll
    for (int off = 32; off >= 1; off >>= 1) s += __shfl_xor(s, off, 64);
    if (s < bestd || (s == bestd && k < bestk)) { bestd = s; bestk = k; }
  }
  if (lane == 0) idx[r] = bestk;
}

// -------- prep kernels ----------------------------------------------------
__global__ void k_split(const float4* __restrict__ in, size_t n4,
                        u16* __restrict__ hi, u16* __restrict__ lo) {
  size_t i = (size_t)blockIdx.x * blockDim.x + threadIdx.x;
  const size_t stride = (size_t)gridDim.x * blockDim.x;
  for (; i < n4; i += stride) {
    const float4 v = in[i];
    const float vv[4] = {v.x, v.y, v.z, v.w};
    u16x4 h, l;
#pragma unroll
    for (int j = 0; j < 4; ++j) {
      const u16 a = f2bf(vv[j]);
      h[j] = a;
      l[j] = f2bf(vv[j] - bf2f(a));
    }
    *(u16x4*)(hi + i * 4) = h;
    *(u16x4*)(lo + i * 4) = l;
  }
}

template <bool WF32, bool WLO>
__global__ void k_tsplit(const float* __restrict__ in, int R, int Cc,
                         u16* __restrict__ hiT, u16* __restrict__ loT,
                         float* __restrict__ f32T) {
  __shared__ float t[32][33];
  const int c0 = blockIdx.x * 32, r0 = blockIdx.y * 32;
  const int tx = threadIdx.x, ty = threadIdx.y;
#pragma unroll
  for (int i = 0; i < 4; ++i)
    t[ty + i * 8][tx] = in[(size_t)(r0 + ty + i * 8) * Cc + (c0 + tx)];
  __syncthreads();
#pragma unroll
  for (int i = 0; i < 4; ++i) {
    const int orow = c0 + ty + i * 8;
    const int ocol = r0 + tx;
    const float v = t[tx][ty + i * 8];
    const size_t o = (size_t)orow * R + ocol;
    const u16 hi = f2bf(v);
    hiT[o] = hi;
    if (WLO) loT[o] = f2bf(v - bf2f(hi));
    if (WF32) f32T[o] = v;
  }
}

__global__ __launch_bounds__(256)
void k_rownorm(const float* __restrict__ in, float* __restrict__ out,
               unsigned int* __restrict__ maxb, int domax) {
  const int r = blockIdx.x, tid = threadIdx.x;
  const float4 v = *(const float4*)(in + (size_t)r * 1024 + tid * 4);
  double s = (double)v.x * v.x + (double)v.y * v.y +
             (double)v.z * v.z + (double)v.w * v.w;
#pragma unroll
  for (int off = 32; off >= 1; off >>= 1) s += __shfl_xor(s, off, 64);
  __shared__ double sw[4];
  if ((tid & 63) == 0) sw[tid >> 6] = s;
  __syncthreads();
  if (tid == 0) {
    const float t = (float)(sw[0] + sw[1] + sw[2] + sw[3]);
    out[r] = t;
    if (domax) atomicMax(maxb, __float_as_uint(t));
  }
}

__global__ void k_init(double* __restrict__ dacc, unsigned int* __restrict__ emaxb) {
  *dacc = 0.0;
  *emaxb = 0u;
}

// -------- finalize: gather + LayerNorm + commitment partial ---------------
__global__ __launch_bounds__(256)
void k_finalize(const int* __restrict__ idx,
                const float* __restrict__ embT, const float* __restrict__ zf,
                const float* __restrict__ gamma, const float* __restrict__ beta,
                float* __restrict__ out, double* __restrict__ dacc) {
  const int row = blockIdx.x;
  const int tid = threadIdx.x;
  const int lane = tid & 63, w = tid >> 6;
  const int id = idx[row];

  const float4 e4 = *(const float4*)(embT + (size_t)id * C_ + tid * 4);
  float s1 = e4.x + e4.y + e4.z + e4.w;
  float s2 = e4.x * e4.x + e4.y * e4.y + e4.z * e4.z + e4.w * e4.w;
#pragma unroll
  for (int off = 32; off >= 1; off >>= 1) {
    s1 += __shfl_xor(s1, off, 64);
    s2 += __shfl_xor(s2, off, 64);
  }
  __shared__ float r1[4], r2[4], rd[4];
  if (lane == 0) { r1[w] = s1; r2[w] = s2; }
  __syncthreads();
  const float S1 = r1[0] + r1[1] + r1[2] + r1[3];
  const float S2 = r2[0] + r2[1] + r2[2] + r2[3];
  const float mu = S1 * (1.f / C_);
  const float var = S2 * (1.f / C_) - mu * mu;
  const float inv = 1.f / sqrtf(var + 1e-5f);

  const float4 z4 = *(const float4*)(zf + (size_t)row * C_ + tid * 4);
  const float4 g4 = *(const float4*)(gamma + tid * 4);
  const float4 b4 = *(const float4*)(beta + tid * 4);
  float4 o4;
  o4.x = (e4.x - mu) * inv * g4.x + b4.x;
  o4.y = (e4.y - mu) * inv * g4.y + b4.y;
  o4.z = (e4.z - mu) * inv * g4.z + b4.z;
  o4.w = (e4.w - mu) * inv * g4.w + b4.w;
  *(float4*)(out + (size_t)row * C_ + tid * 4) = o4;

  const float dx = e4.x - z4.x, dy = e4.y - z4.y, dz = e4.z - z4.z, dw = e4.w - z4.w;
  float d = dx * dx + dy * dy + dz * dz + dw * dw;
#pragma unroll
  for (int off = 32; off >= 1; off >>= 1) d += __shfl_xor(d, off, 64);
  __syncthreads();
  if (lane == 0) rd[w] = d;
  __syncthreads();
  if (tid == 0) atomicAdd(dacc, (double)(rd[0] + rd[1] + rd[2] + rd[3]));
}

__global__ void k_wdiff(const double* __restrict__ dacc, float* __restrict__ out) {
  out[(size_t)B_ * C_] = (float)(0.01 * (*dacc) / ((double)B_ * (double)C_));
}

// ---------------------------------------------------------------------------
extern "C" void kernel_launch(void* const* d_in, const int* in_sizes, int n_in,
                              void* d_out, int out_size, void* d_ws, size_t ws_size,
                              hipStream_t stream) {
  const float* x     = (const float*)d_in[0];
  const float* W1    = (const float*)d_in[1];
  const float* b1    = (const float*)d_in[2];
  const float* W2    = (const float*)d_in[3];
  const float* b2    = (const float*)d_in[4];
  const float* gamma = (const float*)d_in[5];
  const float* beta  = (const float*)d_in[6];
  const float* embed = (const float*)d_in[7];
  float* out = (float*)d_out;

  char* ws = (char*)d_ws;
  const size_t M = 1048576ull;
  // phase 1: xh 0..64M, xl 64..128M, w1h 128..160M, w1l 160..192M,
  //          hh 192..256M, hl 256..320M
  // phase 2 (over dead regions): w2h 0..8M, w2l 8..16M, zf 16..48M,
  //          zh 48..64M, embT 64..96M, eh 96..112M, small @112M,
  //          cand 113..115M, dotm 192..320M (over hh/hl)
  u16* xh  = (u16*)(ws);
  u16* xl  = (u16*)(ws + 64 * M);
  u16* w1h = (u16*)(ws + 128 * M);
  u16* w1l = (u16*)(ws + 160 * M);
  u16* hh  = (u16*)(ws + 192 * M);
  u16* hl  = (u16*)(ws + 256 * M);
  u16* w2h = (u16*)(ws);
  u16* w2l = (u16*)(ws + 8 * M);
  float* zf = (float*)(ws + 16 * M);
  u16* zh  = (u16*)(ws + 48 * M);
  float* embT = (float*)(ws + 64 * M);
  u16* eh  = (u16*)(ws + 96 * M);
  float* norms = (float*)(ws + 112 * M);
  float* zn2   = (float*)(ws + 112 * M + 65536ull);
  int* candcnt = (int*)(ws + 112 * M + 131072ull);
  int* idx     = (int*)(ws + 112 * M + 196608ull);
  unsigned int* emaxb = (unsigned int*)(ws + 112 * M + 262144ull);
  double* dacc = (double*)(ws + 112 * M + 262144ull + 64ull);
  int* cand    = (int*)(ws + 113 * M);
  u16* dotm    = (u16*)(ws + 192 * M);

  (void)hipFuncSetAttribute((const void*)k_gemm1,
                            hipFuncAttributeMaxDynamicSharedMemorySize, 131072);
  (void)hipFuncSetAttribute((const void*)k_gemm3,
                            hipFuncAttributeMaxDynamicSharedMemorySize, 131072);

  // 1. split x -> xh/xl
  k_split<<<2048, 256, 0, stream>>>((const float4*)x, (size_t)B_ * D_ / 4, xh, xl);
  // 2. W1 [D][4C] -> W1T hi/lo [4C][D]
  k_tsplit<false, true><<<dim3(C4_ / 32, D_ / 32), dim3(32, 8), 0, stream>>>(W1, D_, C4_, w1h, w1l, nullptr);
  // 3. GEMM1 (256^2 8-phase; +bias+SiLU+split)
  k_gemm1<<<(B_ / 256) * (C4_ / 256), 512, 131072, stream>>>(xh, xl, w1h, w1l, b1, hh, hl);
  // 4. W2 [4C][C] -> W2T hi/lo [C][4C]
  k_tsplit<false, true><<<dim3(C_ / 32, C4_ / 32), dim3(32, 8), 0, stream>>>(W2, C4_, C_, w2h, w2l, nullptr);
  // 5. GEMM2 (R6-verified 128^2; +bias, write z f32 + bf16 hi)
  k_gemm2<<<(B_ / BM) * (C_ / BN), 256, 0, stream>>>(hh, hl, w2h, w2l, b2, zf, zh);
  // 6. embed [C][K] -> embT f32 + bf16 hi [K][C]
  k_tsplit<true, false><<<dim3(K_ / 32, C_ / 32), dim3(32, 8), 0, stream>>>(embed, C_, K_, eh, nullptr, embT);
  // 7. init accumulators
  k_init<<<1, 1, 0, stream>>>(dacc, emaxb);
  // 8. norms (coalesced, f64) + max; z row norms
  k_rownorm<<<K_, 256, 0, stream>>>(embT, norms, emaxb, 1);
  k_rownorm<<<B_, 256, 0, stream>>>(zf, zn2, emaxb, 0);
  // 9. GEMM3 v4 (256^2 quadrant-phase 8-phase) -> dotm f16
  k_gemm3<<<(B_ / 256) * (K_ / 256), 512, 131072, stream>>>(zh, eh, dotm);
  // 10. per-row min + global-window candidates (R6-proven)
  k_scan<<<B_, 256, 0, stream>>>(dotm, norms, zn2, emaxb, cand, candcnt);
  // 11. exact f64 rescore -> final indices
  k_rescore<<<B_, 64, 0, stream>>>(cand, candcnt, zf, embT, idx);
  // 12. gather + LayerNorm + commitment
  k_finalize<<<B_, 256, 0, stream>>>(idx, embT, zf, gamma, beta, out, dacc);
  // 13. scalar diff output
  k_wdiff<<<1, 1, 0, stream>>>(dacc, out);
}

// Round 11
// 1241.460 us; speedup vs baseline: 1.2622x; 1.0231x over previous
//
#include <hip/hip_runtime.h>
#include <stdint.h>

typedef unsigned short u16;
typedef __attribute__((ext_vector_type(4))) float f32x4;
typedef __attribute__((ext_vector_type(8))) __bf16 bf16x8;
typedef __attribute__((ext_vector_type(4))) u16 u16x4;

#define B_  8192
#define D_  4096
#define C4_ 4096
#define C_  1024
#define K_  8192
#define CAP 64

__device__ __forceinline__ void load_lds16(const void* g, void* l) {
  __builtin_amdgcn_global_load_lds(
      (const __attribute__((address_space(1))) unsigned int*)g,
      (__attribute__((address_space(3))) unsigned int*)l, 16, 0, 0);
}

__device__ __forceinline__ u16 f2bf(float v) {
  unsigned int u = __float_as_uint(v);
  return (u16)((u + 0x7FFFu + ((u >> 16) & 1u)) >> 16);   // RNE
}
__device__ __forceinline__ float bf2f(u16 u) {
  return __uint_as_float(((unsigned int)u) << 16);
}
__device__ __forceinline__ u16 f2h(float v) {
  _Float16 h = (_Float16)v; u16 b; __builtin_memcpy(&b, &h, 2); return b;
}
__device__ __forceinline__ float h2f(u16 b) {
  _Float16 h; __builtin_memcpy(&h, &b, 2); return (float)h;
}

#define VMW(N) asm volatile("s_waitcnt vmcnt(" #N ")" ::: "memory")
#define BARR() asm volatile("s_barrier" ::: "memory")

// ===================== GEMM1: 256x256 tile, 8-phase counted-vmcnt =========
// (R6-verified; unchanged.) 512 thr (8 waves 2Mx4N), BK=32, 2 K-tiles/iter,
// 3-product split-bf16. LDS 128 KB. Swizzle slot ^= (row>>1)&3 both sides.
// Waits steady [3,4,5,6]x2; final-iter drain [3,2,1,0]. 24 MFMA/phase.

#define STAGE_BX(P, GPTR, LOFF, k0)                                          \
  { load_lds16((GPTR) + sB_base + (size_t)(k0),                              \
               lds + (P) * 32768 + (LOFF) + w * 512);                        \
    load_lds16((GPTR) + sB_base + (size_t)128 * Ksz + (size_t)(k0),          \
               lds + (P) * 32768 + (LOFF) + 4096 + w * 512); }

#define STAGE_A1(P, j, k0)                                                   \
  { load_lds16(Asrc + sA_base + (size_t)((j) * 32) * Ksz + (size_t)(k0),     \
               lds + (P) * 32768 + aldsb + (j) * 1024); }

#define LOAD_B(P)                                                            \
  { const u16* bb = lds + (P) * 32768;                                       \
    _Pragma("unroll") for (int n = 0; n < 4; ++n) {                          \
      bhf[n] = *(const bf16x8*)(bb + ardB + n * 512);                        \
      blf[n] = *(const bf16x8*)(bb + 8192 + ardB + n * 512); } }

#define PH_A(P, Q, ...)                                                      \
  { const u16* bb = lds + (P) * 32768;                                       \
    const bf16x8 a0h = *(const bf16x8*)(bb + ardA + ((Q)*2 + 0) * 512);      \
    const bf16x8 a0l = *(const bf16x8*)(bb + 8192 + ardA + ((Q)*2+0) * 512); \
    const bf16x8 a1h = *(const bf16x8*)(bb + ardA + ((Q)*2 + 1) * 512);      \
    const bf16x8 a1l = *(const bf16x8*)(bb + 8192 + ardA + ((Q)*2+1) * 512); \
    __VA_ARGS__                                                              \
    __builtin_amdgcn_s_setprio(1);                                           \
    _Pragma("unroll") for (int n = 0; n < 4; ++n) {                          \
      acc[(Q)*2+0][n] = __builtin_amdgcn_mfma_f32_16x16x32_bf16(a0h, bhf[n], acc[(Q)*2+0][n], 0,0,0); \
      acc[(Q)*2+0][n] = __builtin_amdgcn_mfma_f32_16x16x32_bf16(a0l, bhf[n], acc[(Q)*2+0][n], 0,0,0); \
      acc[(Q)*2+0][n] = __builtin_amdgcn_mfma_f32_16x16x32_bf16(a0h, blf[n], acc[(Q)*2+0][n], 0,0,0); \
      acc[(Q)*2+1][n] = __builtin_amdgcn_mfma_f32_16x16x32_bf16(a1h, bhf[n], acc[(Q)*2+1][n], 0,0,0); \
      acc[(Q)*2+1][n] = __builtin_amdgcn_mfma_f32_16x16x32_bf16(a1l, bhf[n], acc[(Q)*2+1][n], 0,0,0); \
      acc[(Q)*2+1][n] = __builtin_amdgcn_mfma_f32_16x16x32_bf16(a1h, blf[n], acc[(Q)*2+1][n], 0,0,0); \
    }                                                                        \
    __builtin_amdgcn_s_setprio(0); }

// shared mainloop body for gemm1 / gemm2s (identical schedule; K-extent and
// k-offset differ). Emits into local `acc`; all locals must be in scope.
#define G1_MAINLOOP(KBASE, NIT)                                              \
  STAGE_BX(0, Bhg, 16384, (KBASE)); STAGE_BX(0, Blg, 24576, (KBASE));        \
  STAGE_A1(0, 0, (KBASE)); STAGE_A1(0, 1, (KBASE));                          \
  STAGE_A1(0, 2, (KBASE)); STAGE_A1(0, 3, (KBASE));                          \
  for (int t = 0; t < (NIT) - 1; ++t) {                                      \
    const int k1 = (KBASE) + t * 64 + 32;                                    \
    const int k2 = (KBASE) + t * 64 + 64;                                    \
    VMW(3); BARR(); LOAD_B(0); PH_A(0, 0, STAGE_BX(1, Bhg, 16384, k1);)      \
    VMW(4); BARR();            PH_A(0, 1, STAGE_BX(1, Blg, 24576, k1);)      \
    VMW(5); BARR();            PH_A(0, 2, STAGE_A1(1, 0, k1); STAGE_A1(1, 1, k1);) \
    VMW(6); BARR();            PH_A(0, 3, STAGE_A1(1, 2, k1); STAGE_A1(1, 3, k1);) \
    VMW(3); BARR(); LOAD_B(1); PH_A(1, 0, STAGE_BX(0, Bhg, 16384, k2);)      \
    VMW(4); BARR();            PH_A(1, 1, STAGE_BX(0, Blg, 24576, k2);)      \
    VMW(5); BARR();            PH_A(1, 2, STAGE_A1(0, 0, k2); STAGE_A1(0, 1, k2);) \
    VMW(6); BARR();            PH_A(1, 3, STAGE_A1(0, 2, k2); STAGE_A1(0, 3, k2);) \
  }                                                                          \
  {                                                                          \
    const int k1 = (KBASE) + ((NIT) - 1) * 64 + 32;                          \
    VMW(3); BARR(); LOAD_B(0); PH_A(0, 0, STAGE_BX(1, Bhg, 16384, k1);)      \
    VMW(4); BARR();            PH_A(0, 1, STAGE_BX(1, Blg, 24576, k1);)      \
    VMW(5); BARR();            PH_A(0, 2, STAGE_A1(1, 0, k1); STAGE_A1(1, 1, k1);) \
    VMW(6); BARR();            PH_A(0, 3, STAGE_A1(1, 2, k1); STAGE_A1(1, 3, k1);) \
    VMW(3); BARR(); LOAD_B(1); PH_A(1, 0, )                                  \
    VMW(2); BARR();            PH_A(1, 1, )                                  \
    VMW(1); BARR();            PH_A(1, 2, )                                  \
    VMW(0); BARR();            PH_A(1, 3, )                                  \
  }

__global__ __launch_bounds__(512, 2)
void k_gemm1(const u16* __restrict__ xh, const u16* __restrict__ xl,
             const u16* __restrict__ w1h, const u16* __restrict__ w1l,
             const float* __restrict__ b1,
             u16* __restrict__ hh, u16* __restrict__ hl) {
  extern __shared__ u16 lds[];
  const int tid = threadIdx.x;
  const int lane = tid & 63;
  const int w = tid >> 6;
  const int wr = w >> 2, wc = w & 3;
  const int rlow = lane & 15;
  const size_t Ksz = D_;
  const int nbn = C4_ / 256;
  const int bm = blockIdx.x / nbn, bn = blockIdx.x % nbn;
  const int rowA0 = bm * 256, rowB0 = bn * 256;
  const u16* __restrict__ Bhg = w1h;
  const u16* __restrict__ Blg = w1l;
  const u16* __restrict__ Asrc = (w < 4) ? xh : xl;

  const int gslot8 = (((lane & 3) ^ ((lane >> 3) & 3)) << 3);
  const size_t sB_base = (size_t)(rowB0 + w * 16 + (lane >> 2)) * Ksz + gslot8;
  const size_t sA_base =
      (size_t)(rowA0 + ((w >> 1) & 1) * 128 + (w & 1) * 16 + (lane >> 2)) * Ksz + gslot8;
  const int aldsb = ((w < 4) ? 0 : 8192) + ((w >> 1) & 1) * 4096 + (w & 1) * 512;

  const int aslot8 = (((lane >> 4) ^ ((lane >> 1) & 3)) << 3);
  const int ardA = wr * 4096 + rlow * 32 + aslot8;
  const int ardB = 16384 + wc * 2048 + rlow * 32 + aslot8;

  f32x4 acc[8][4];
#pragma unroll
  for (int m = 0; m < 8; ++m)
#pragma unroll
    for (int n = 0; n < 4; ++n) acc[m][n] = (f32x4){0.f, 0.f, 0.f, 0.f};
  bf16x8 bhf[4], blf[4];

  G1_MAINLOOP(0, (int)(Ksz / 64))

#pragma unroll
  for (int m = 0; m < 8; ++m)
#pragma unroll
    for (int n = 0; n < 4; ++n)
#pragma unroll
      for (int j = 0; j < 4; ++j) {
        const int rg = rowA0 + wr * 128 + m * 16 + (lane >> 4) * 4 + j;
        const int cg = rowB0 + wc * 64 + n * 16 + rlow;
        const float v = acc[m][n][j] + b1[cg];
        const float s = v / (1.f + __expf(-v));
        const size_t o = (size_t)rg * C4_ + cg;
        const u16 hi = f2bf(s);
        hh[o] = hi;
        hl[o] = f2bf(s - bf2f(hi));
      }
}

// ========== GEMM2 split-K=2: verbatim gemm1-clone, 256x256, K=2048 ========
// grid = 32(bm) x 4(bn) x 2(ks) = 256 blocks = 1/CU (template-native).
// Row stride stays 4096; block ks covers columns [ks*2048, ks*2048+2048).
// Writes f32 partials (no bias); k_combine sums + bias -> zf + zh.
__global__ __launch_bounds__(512, 2)
void k_gemm2s(const u16* __restrict__ hh, const u16* __restrict__ hl,
              const u16* __restrict__ w2h, const u16* __restrict__ w2l,
              float* __restrict__ zpart) {
  extern __shared__ u16 lds[];
  const int tid = threadIdx.x;
  const int lane = tid & 63;
  const int w = tid >> 6;
  const int wr = w >> 2, wc = w & 3;
  const int rlow = lane & 15;
  const size_t Ksz = C4_;                       // row stride (full K)
  const int ks = blockIdx.x & 1;
  const int bi = blockIdx.x >> 1;
  const int bm = bi >> 2, bn = bi & 3;          // 32 x 4
  const int rowA0 = bm * 256, rowB0 = bn * 256;
  const int kbase = ks * 2048;
  const u16* __restrict__ Bhg = w2h;
  const u16* __restrict__ Blg = w2l;
  const u16* __restrict__ Asrc = (w < 4) ? hh : hl;

  const int gslot8 = (((lane & 3) ^ ((lane >> 3) & 3)) << 3);
  const size_t sB_base = (size_t)(rowB0 + w * 16 + (lane >> 2)) * Ksz + gslot8;
  const size_t sA_base =
      (size_t)(rowA0 + ((w >> 1) & 1) * 128 + (w & 1) * 16 + (lane >> 2)) * Ksz + gslot8;
  const int aldsb = ((w < 4) ? 0 : 8192) + ((w >> 1) & 1) * 4096 + (w & 1) * 512;

  const int aslot8 = (((lane >> 4) ^ ((lane >> 1) & 3)) << 3);
  const int ardA = wr * 4096 + rlow * 32 + aslot8;
  const int ardB = 16384 + wc * 2048 + rlow * 32 + aslot8;

  f32x4 acc[8][4];
#pragma unroll
  for (int m = 0; m < 8; ++m)
#pragma unroll
    for (int n = 0; n < 4; ++n) acc[m][n] = (f32x4){0.f, 0.f, 0.f, 0.f};
  bf16x8 bhf[4], blf[4];

  G1_MAINLOOP(kbase, 32)

  float* zp = zpart + (size_t)ks * ((size_t)B_ * C_);
#pragma unroll
  for (int m = 0; m < 8; ++m)
#pragma unroll
    for (int n = 0; n < 4; ++n)
#pragma unroll
      for (int j = 0; j < 4; ++j) {
        const int rg = rowA0 + wr * 128 + m * 16 + (lane >> 4) * 4 + j;
        const int cg = rowB0 + wc * 64 + n * 16 + rlow;
        zp[(size_t)rg * C_ + cg] = acc[m][n][j];
      }
}

// -------- combine: z = p0 + p1 + b2 -> zf (f32) + zh (bf16) ---------------
__global__ __launch_bounds__(256)
void k_combine(const float* __restrict__ p0, const float* __restrict__ p1,
               const float* __restrict__ b2,
               float* __restrict__ zf, u16* __restrict__ zh) {
  const size_t n4 = (size_t)B_ * C_ / 4;
  size_t i = (size_t)blockIdx.x * blockDim.x + threadIdx.x;
  const size_t stride = (size_t)gridDim.x * blockDim.x;
  for (; i < n4; i += stride) {
    const float4 a = ((const float4*)p0)[i];
    const float4 b = ((const float4*)p1)[i];
    const float4 bb = *(const float4*)(b2 + ((i * 4) & (C_ - 1)));
    float4 v;
    v.x = a.x + b.x + bb.x; v.y = a.y + b.y + bb.y;
    v.z = a.z + b.z + bb.z; v.w = a.w + b.w + bb.w;
    ((float4*)zf)[i] = v;
    u16x4 h;
    h[0] = f2bf(v.x); h[1] = f2bf(v.y); h[2] = f2bf(v.z); h[3] = f2bf(v.w);
    *(u16x4*)(zh + i * 4) = h;
  }
}

// ===== GEMM3 v4 (R10): 256x256, quadrant-phase 8-phase, writes dotm f16 ===
#define G3_SB(P, jj, k0)                                                     \
  load_lds16(eh + sB_base + (size_t)((jj) * 8) * 1024 + (size_t)(k0),        \
             lds + (P) * 32768 + 16384 + (w * 32 + (jj) * 8) * 64);
#define G3_SA(P, h, l, k0)                                                   \
  load_lds16(zh + sA_base + (size_t)((h) * 64 + (l) * 8) * 1024 + (size_t)(k0), \
             lds + (P) * 32768 + (aw0 + (h) * 64 + (l) * 8) * 64);
#define G3_RB(P, ks)                                                         \
  { const u16* bb = lds + (P) * 32768 + 16384;                               \
    const int kof = ((((ks) * 4 + (lane >> 4)) ^ (lane & 7)) << 3);          \
    _Pragma("unroll") for (int n = 0; n < 4; ++n)                            \
      bfv[n] = *(const bf16x8*)(bb + (wc * 64 + n * 16 + rlow) * 64 + kof); }
#define G3_PH(P, h, ks, ...)                                                 \
  { const u16* ab = lds + (P) * 32768;                                       \
    const int kof = ((((ks) * 4 + (lane >> 4)) ^ (lane & 7)) << 3);          \
    bf16x8 af[4];                                                            \
    _Pragma("unroll") for (int m = 0; m < 4; ++m)                            \
      af[m] = *(const bf16x8*)(ab + (wr * 128 + (h) * 64 + m * 16 + rlow) * 64 + kof); \
    __VA_ARGS__                                                              \
    __builtin_amdgcn_s_setprio(1);                                           \
    _Pragma("unroll") for (int m = 0; m < 4; ++m)                            \
      _Pragma("unroll") for (int n = 0; n < 4; ++n)                          \
        acc[(h) * 4 + m][n] = __builtin_amdgcn_mfma_f32_16x16x32_bf16(af[m], bfv[n], acc[(h) * 4 + m][n], 0, 0, 0); \
    __builtin_amdgcn_s_setprio(0); }

__global__ __launch_bounds__(512, 2)
void k_gemm3(const u16* __restrict__ zh, const u16* __restrict__ eh,
             u16* __restrict__ dotm) {
  extern __shared__ u16 lds[];
  const int tid = threadIdx.x;
  const int lane = tid & 63;
  const int w = tid >> 6;
  const int wr = w >> 2, wc = w & 3;
  const int rlow = lane & 15;
  const int nbn = K_ / 256;
  const int bm = blockIdx.x / nbn, bn = blockIdx.x % nbn;
  const int rowA0 = bm * 256, rowB0 = bn * 256;

  const int gsl = (((lane & 7) ^ (lane >> 3)) << 3);   // pre-swizzled slot
  const int aw0 = (w >> 2) * 128 + (w & 3) * 16;
  const size_t sB_base = (size_t)(rowB0 + w * 32 + (lane >> 3)) * 1024 + gsl;
  const size_t sA_base = (size_t)(rowA0 + aw0 + (lane >> 3)) * 1024 + gsl;

  f32x4 acc[8][4];
#pragma unroll
  for (int m = 0; m < 8; ++m)
#pragma unroll
    for (int n = 0; n < 4; ++n) acc[m][n] = (f32x4){0.f, 0.f, 0.f, 0.f};
  bf16x8 bfv[4];

  G3_SB(0, 0, 0); G3_SB(0, 1, 0); G3_SB(0, 2, 0); G3_SB(0, 3, 0);
  G3_SA(0, 0, 0, 0); G3_SA(0, 0, 1, 0); G3_SA(0, 1, 0, 0); G3_SA(0, 1, 1, 0);

  for (int t = 0; t < 7; ++t) {
    const int k1 = t * 128 + 64;    // tile 2t+1 -> buf1
    const int k2 = t * 128 + 128;   // tile 2t+2 -> buf0
    VMW(2); BARR(); G3_RB(0, 0); G3_PH(0, 0, 0, G3_SB(1, 0, k1); G3_SB(1, 1, k1);)
    VMW(2); BARR();              G3_PH(0, 1, 0, G3_SB(1, 2, k1); G3_SB(1, 3, k1);)
            BARR(); G3_RB(0, 1); G3_PH(0, 0, 1, G3_SA(1, 0, 0, k1); G3_SA(1, 0, 1, k1);)
            BARR();              G3_PH(0, 1, 1, G3_SA(1, 1, 0, k1); G3_SA(1, 1, 1, k1);)
    VMW(2); BARR(); G3_RB(1, 0); G3_PH(1, 0, 0, G3_SB(0, 0, k2); G3_SB(0, 1, k2);)
    VMW(2); BARR();              G3_PH(1, 1, 0, G3_SB(0, 2, k2); G3_SB(0, 3, k2);)
            BARR(); G3_RB(1, 1); G3_PH(1, 0, 1, G3_SA(0, 0, 0, k2); G3_SA(0, 0, 1, k2);)
            BARR();              G3_PH(1, 1, 1, G3_SA(0, 1, 0, k2); G3_SA(0, 1, 1, k2);)
  }
  {
    const int k1 = 7 * 128 + 64;
    VMW(2); BARR(); G3_RB(0, 0); G3_PH(0, 0, 0, G3_SB(1, 0, k1); G3_SB(1, 1, k1);)
    VMW(2); BARR();              G3_PH(0, 1, 0, G3_SB(1, 2, k1); G3_SB(1, 3, k1);)
            BARR(); G3_RB(0, 1); G3_PH(0, 0, 1, G3_SA(1, 0, 0, k1); G3_SA(1, 0, 1, k1);)
            BARR();              G3_PH(0, 1, 1, G3_SA(1, 1, 0, k1); G3_SA(1, 1, 1, k1);)
    VMW(2); BARR(); G3_RB(1, 0); G3_PH(1, 0, 0, )
    VMW(0); BARR();              G3_PH(1, 1, 0, )
            BARR(); G3_RB(1, 1); G3_PH(1, 0, 1, )
            BARR();              G3_PH(1, 1, 1, )
  }

  // epilogue: repack acc -> f16 dotm via LDS in 4 passes of 64 rows
  __syncthreads();
  u16* ldsw = lds;
#pragma unroll
  for (int p = 0; p < 4; ++p) {
    if (wr == (p >> 1)) {
      const int mb = (p & 1) * 4;
#pragma unroll
      for (int mm = 0; mm < 4; ++mm)
#pragma unroll
        for (int n = 0; n < 4; ++n)
#pragma unroll
          for (int j = 0; j < 4; ++j) {
            const int rl = mm * 16 + (lane >> 4) * 4 + j;
            const int cl = wc * 64 + n * 16 + rlow;
            ldsw[rl * 256 + cl] = f2h(acc[mb + mm][n][j]);
          }
    }
    __syncthreads();
    for (int i = tid; i < 2048; i += 512) {
      const int r = i >> 5, c = (i & 31) * 8;
      *(uint4*)(dotm + (size_t)(rowA0 + p * 64 + r) * K_ + rowB0 + c) =
          *(const uint4*)(ldsw + r * 256 + c);
    }
    __syncthreads();
  }
}

// -------- scan: per-row min + candidates within rigorous bound (R6) -------
__global__ __launch_bounds__(256)
void k_scan(const u16* __restrict__ dotm, const float* __restrict__ norms,
            const float* __restrict__ zn2, const unsigned int* __restrict__ emaxb,
            int* __restrict__ cand, int* __restrict__ candcnt) {
  __shared__ __align__(16) u16 srow[K_];
  __shared__ float rmin[4];
  __shared__ int lcnt;
  const int r = blockIdx.x, tid = threadIdx.x;
  const size_t base = (size_t)r * K_;
  for (int i = tid; i < K_ / 8; i += 256)
    ((uint4*)srow)[i] = ((const uint4*)(dotm + base))[i];
  if (tid == 0) lcnt = 0;
  __syncthreads();
  float mymin = 3.4e38f;
  for (int k = tid; k < K_; k += 256)
    mymin = fminf(mymin, norms[k] - 2.f * h2f(srow[k]));
#pragma unroll
  for (int off = 32; off >= 1; off >>= 1)
    mymin = fminf(mymin, __shfl_xor(mymin, off, 64));
  if ((tid & 63) == 0) rmin[tid >> 6] = mymin;
  __syncthreads();
  const float gmin = fminf(fminf(rmin[0], rmin[1]), fminf(rmin[2], rmin[3]));
  const float bnd = 0.010f * sqrtf(zn2[r]) * sqrtf(__uint_as_float(*emaxb)) + 0.01f;
  const float win = gmin + 2.f * bnd;
  for (int k = tid; k < K_; k += 256) {
    const float sc = norms[k] - 2.f * h2f(srow[k]);
    if (sc <= win) {
      const int p = atomicAdd(&lcnt, 1);
      if (p < CAP) cand[r * CAP + p] = k;
    }
  }
  __syncthreads();
  if (tid == 0) candcnt[r] = lcnt;
}

// ---- fused rescore (4-wave parallel, exact f64) + gather + LayerNorm -----
__global__ __launch_bounds__(256)
void k_rescore_finalize(const int* __restrict__ cand, const int* __restrict__ candcnt,
                        const float* __restrict__ zf, const float* __restrict__ embT,
                        const float* __restrict__ gamma, const float* __restrict__ beta,
                        float* __restrict__ out, double* __restrict__ dacc) {
  const int row = blockIdx.x;
  const int tid = threadIdx.x;
  const int lane = tid & 63, wv = tid >> 6;
  __shared__ int sid;
  __shared__ double wd[4];
  __shared__ int wk[4];

  const int cnt = candcnt[row];
  if (cnt <= 1) {               // block-uniform branch
    if (tid == 0) sid = cand[row * CAP];
    __syncthreads();
  } else {
    const bool full = cnt > CAP;   // rigorous fallback (never expected)
    const int n = full ? K_ : cnt;
    double bestd = 1e300; int bestk = 0x7fffffff;
    for (int c = wv; c < n; c += 4) {
      const int k = full ? c : cand[row * CAP + c];
      double s = 0.0;
      for (int i = lane; i < C_; i += 64) {
        const double d = (double)zf[(size_t)row * C_ + i] - (double)embT[(size_t)k * C_ + i];
        s += d * d;
      }
#pragma unroll
      for (int off = 32; off >= 1; off >>= 1) s += __shfl_xor(s, off, 64);
      if (s < bestd || (s == bestd && k < bestk)) { bestd = s; bestk = k; }
    }
    if (lane == 0) { wd[wv] = bestd; wk[wv] = bestk; }
    __syncthreads();
    if (tid == 0) {
      double bd = wd[0]; int bk = wk[0];
#pragma unroll
      for (int q = 1; q < 4; ++q)
        if (wd[q] < bd || (wd[q] == bd && wk[q] < bk)) { bd = wd[q]; bk = wk[q]; }
      sid = bk;
    }
    __syncthreads();
  }
  const int id = sid;

  const float4 e4 = *(const float4*)(embT + (size_t)id * C_ + tid * 4);
  float s1 = e4.x + e4.y + e4.z + e4.w;
  float s2 = e4.x * e4.x + e4.y * e4.y + e4.z * e4.z + e4.w * e4.w;
#pragma unroll
  for (int off = 32; off >= 1; off >>= 1) {
    s1 += __shfl_xor(s1, off, 64);
    s2 += __shfl_xor(s2, off, 64);
  }
  __shared__ float r1[4], r2[4], rd[4];
  if (lane == 0) { r1[wv] = s1; r2[wv] = s2; }
  __syncthreads();
  const float S1 = r1[0] + r1[1] + r1[2] + r1[3];
  const float S2 = r2[0] + r2[1] + r2[2] + r2[3];
  const float mu = S1 * (1.f / C_);
  const float var = S2 * (1.f / C_) - mu * mu;
  const float inv = 1.f / sqrtf(var + 1e-5f);

  const float4 z4 = *(const float4*)(zf + (size_t)row * C_ + tid * 4);
  const float4 g4 = *(const float4*)(gamma + tid * 4);
  const float4 b4 = *(const float4*)(beta + tid * 4);
  float4 o4;
  o4.x = (e4.x - mu) * inv * g4.x + b4.x;
  o4.y = (e4.y - mu) * inv * g4.y + b4.y;
  o4.z = (e4.z - mu) * inv * g4.z + b4.z;
  o4.w = (e4.w - mu) * inv * g4.w + b4.w;
  *(float4*)(out + (size_t)row * C_ + tid * 4) = o4;

  const float dx = e4.x - z4.x, dy = e4.y - z4.y, dz = e4.z - z4.z, dw = e4.w - z4.w;
  float d = dx * dx + dy * dy + dz * dz + dw * dw;
#pragma unroll
  for (int off = 32; off >= 1; off >>= 1) d += __shfl_xor(d, off, 64);
  __syncthreads();
  if (lane == 0) rd[wv] = d;
  __syncthreads();
  if (tid == 0) atomicAdd(dacc, (double)(rd[0] + rd[1] + rd[2] + rd[3]));
}

// -------- prep kernels ----------------------------------------------------
__global__ void k_split(const float4* __restrict__ in, size_t n4,
                        u16* __restrict__ hi, u16* __restrict__ lo,
                        double* __restrict__ dacc, unsigned int* __restrict__ emaxb) {
  size_t i = (size_t)blockIdx.x * blockDim.x + threadIdx.x;
  if (i == 0) { *dacc = 0.0; *emaxb = 0u; }   // folded init (runs first)
  const size_t stride = (size_t)gridDim.x * blockDim.x;
  for (; i < n4; i += stride) {
    const float4 v = in[i];
    const float vv[4] = {v.x, v.y, v.z, v.w};
    u16x4 h, l;
#pragma unroll
    for (int j = 0; j < 4; ++j) {
      const u16 a = f2bf(vv[j]);
      h[j] = a;
      l[j] = f2bf(vv[j] - bf2f(a));
    }
    *(u16x4*)(hi + i * 4) = h;
    *(u16x4*)(lo + i * 4) = l;
  }
}

template <bool WF32, bool WLO>
__global__ void k_tsplit(const float* __restrict__ in, int R, int Cc,
                         u16* __restrict__ hiT, u16* __restrict__ loT,
                         float* __restrict__ f32T) {
  __shared__ float t[32][33];
  const int c0 = blockIdx.x * 32, r0 = blockIdx.y * 32;
  const int tx = threadIdx.x, ty = threadIdx.y;
#pragma unroll
  for (int i = 0; i < 4; ++i)
    t[ty + i * 8][tx] = in[(size_t)(r0 + ty + i * 8) * Cc + (c0 + tx)];
  __syncthreads();
#pragma unroll
  for (int i = 0; i < 4; ++i) {
    const int orow = c0 + ty + i * 8;
    const int ocol = r0 + tx;
    const float v = t[tx][ty + i * 8];
    const size_t o = (size_t)orow * R + ocol;
    const u16 hi = f2bf(v);
    hiT[o] = hi;
    if (WLO) loT[o] = f2bf(v - bf2f(hi));
    if (WF32) f32T[o] = v;
  }
}

__global__ __launch_bounds__(256)
void k_rownorm(const float* __restrict__ in, float* __restrict__ out,
               unsigned int* __restrict__ maxb, int domax) {
  const int r = blockIdx.x, tid = threadIdx.x;
  const float4 v = *(const float4*)(in + (size_t)r * 1024 + tid * 4);
  double s = (double)v.x * v.x + (double)v.y * v.y +
             (double)v.z * v.z + (double)v.w * v.w;
#pragma unroll
  for (int off = 32; off >= 1; off >>= 1) s += __shfl_xor(s, off, 64);
  __shared__ double sw[4];
  if ((tid & 63) == 0) sw[tid >> 6] = s;
  __syncthreads();
  if (tid == 0) {
    const float t = (float)(sw[0] + sw[1] + sw[2] + sw[3]);
    out[r] = t;
    if (domax) atomicMax(maxb, __float_as_uint(t));
  }
}

__global__ void k_wdiff(const double* __restrict__ dacc, float* __restrict__ out) {
  out[(size_t)B_ * C_] = (float)(0.01 * (*dacc) / ((double)B_ * (double)C_));
}

// ---------------------------------------------------------------------------
extern "C" void kernel_launch(void* const* d_in, const int* in_sizes, int n_in,
                              void* d_out, int out_size, void* d_ws, size_t ws_size,
                              hipStream_t stream) {
  const float* x     = (const float*)d_in[0];
  const float* W1    = (const float*)d_in[1];
  const float* b1    = (const float*)d_in[2];
  const float* W2    = (const float*)d_in[3];
  const float* b2    = (const float*)d_in[4];
  const float* gamma = (const float*)d_in[5];
  const float* beta  = (const float*)d_in[6];
  const float* embed = (const float*)d_in[7];
  float* out = (float*)d_out;

  char* ws = (char*)d_ws;
  const size_t M = 1048576ull;
  // phase 1: xh 0..64M, xl 64..128M, w1h 128..160M, w1l 160..192M,
  //          hh 192..256M, hl 256..320M
  // phase 2 (over dead xh/xl): w2h 0..8M, w2l 8..16M, zf 16..48M,
  //          zh 48..64M, zpart 64..128M (2 x 32M; consumed by combine
  //          BEFORE tsplit-embed overwrites embT@64M / eh@96M),
  //          small @112M+256K..., cand 113..115M, dotm 192..320M
  u16* xh  = (u16*)(ws);
  u16* xl  = (u16*)(ws + 64 * M);
  u16* w1h = (u16*)(ws + 128 * M);
  u16* w1l = (u16*)(ws + 160 * M);
  u16* hh  = (u16*)(ws + 192 * M);
  u16* hl  = (u16*)(ws + 256 * M);
  u16* w2h = (u16*)(ws);
  u16* w2l = (u16*)(ws + 8 * M);
  float* zf = (float*)(ws + 16 * M);
  u16* zh  = (u16*)(ws + 48 * M);
  float* zpart = (float*)(ws + 64 * M);          // 64 MB (2 partials)
  float* embT = (float*)(ws + 64 * M);           // after combine
  u16* eh  = (u16*)(ws + 96 * M);                // after combine
  float* norms = (float*)(ws + 112 * M);
  float* zn2   = (float*)(ws + 112 * M + 65536ull);
  int* candcnt = (int*)(ws + 112 * M + 131072ull);
  unsigned int* emaxb = (unsigned int*)(ws + 112 * M + 262144ull);
  double* dacc = (double*)(ws + 112 * M + 262144ull + 64ull);
  int* cand    = (int*)(ws + 113 * M);
  u16* dotm    = (u16*)(ws + 192 * M);

  (void)hipFuncSetAttribute((const void*)k_gemm1,
                            hipFuncAttributeMaxDynamicSharedMemorySize, 131072);
  (void)hipFuncSetAttribute((const void*)k_gemm2s,
                            hipFuncAttributeMaxDynamicSharedMemorySize, 131072);
  (void)hipFuncSetAttribute((const void*)k_gemm3,
                            hipFuncAttributeMaxDynamicSharedMemorySize, 131072);

  // 1. split x -> xh/xl (+ init dacc/emaxb)
  k_split<<<2048, 256, 0, stream>>>((const float4*)x, (size_t)B_ * D_ / 4, xh, xl, dacc, emaxb);
  // 2. W1 [D][4C] -> W1T hi/lo [4C][D]
  k_tsplit<false, true><<<dim3(C4_ / 32, D_ / 32), dim3(32, 8), 0, stream>>>(W1, D_, C4_, w1h, w1l, nullptr);
  // 3. GEMM1 (256^2 8-phase; +bias+SiLU+split)
  k_gemm1<<<(B_ / 256) * (C4_ / 256), 512, 131072, stream>>>(xh, xl, w1h, w1l, b1, hh, hl);
  // 4. W2 [4C][C] -> W2T hi/lo [C][4C]
  k_tsplit<false, true><<<dim3(C_ / 32, C4_ / 32), dim3(32, 8), 0, stream>>>(W2, C4_, C_, w2h, w2l, nullptr);
  // 5. GEMM2 split-K=2 (256^2 8-phase clone, 256 blocks) -> f32 partials
  k_gemm2s<<<(B_ / 256) * (C_ / 256) * 2, 512, 131072, stream>>>(hh, hl, w2h, w2l, zpart);
  // 6. combine partials + bias -> zf + zh
  k_combine<<<2048, 256, 0, stream>>>(zpart, zpart + (size_t)B_ * C_, b2, zf, zh);
  // 7. embed [C][K] -> embT f32 + bf16 hi [K][C]  (overwrites zpart)
  k_tsplit<true, false><<<dim3(K_ / 32, C_ / 32), dim3(32, 8), 0, stream>>>(embed, C_, K_, eh, nullptr, embT);
  // 8. norms (coalesced, f64) + max; z row norms
  k_rownorm<<<K_, 256, 0, stream>>>(embT, norms, emaxb, 1);
  k_rownorm<<<B_, 256, 0, stream>>>(zf, zn2, emaxb, 0);
  // 9. GEMM3 v4 (256^2 quadrant-phase 8-phase) -> dotm f16
  k_gemm3<<<(B_ / 256) * (K_ / 256), 512, 131072, stream>>>(zh, eh, dotm);
  // 10. per-row min + global-window candidates (R6-proven)
  k_scan<<<B_, 256, 0, stream>>>(dotm, norms, zn2, emaxb, cand, candcnt);
  // 11. fused exact-f64 rescore + gather + LayerNorm + commitment
  k_rescore_finalize<<<B_, 256, 0, stream>>>(cand, candcnt, zf, embT, gamma, beta, out, dacc);
  // 12. scalar diff output
  k_wdiff<<<1, 1, 0, stream>>>(dacc, out);
}

// Round 13
// 1240.500 us; speedup vs baseline: 1.2631x; 1.0008x over previous
//
#include <hip/hip_runtime.h>
#include <stdint.h>

typedef unsigned short u16;
typedef __attribute__((ext_vector_type(4))) float f32x4;
typedef __attribute__((ext_vector_type(8))) __bf16 bf16x8;
typedef __attribute__((ext_vector_type(4))) u16 u16x4;

#define B_  8192
#define D_  4096
#define C4_ 4096
#define C_  1024
#define K_  8192
#define CAP 64

__device__ __forceinline__ void load_lds16(const void* g, void* l) {
  __builtin_amdgcn_global_load_lds(
      (const __attribute__((address_space(1))) unsigned int*)g,
      (__attribute__((address_space(3))) unsigned int*)l, 16, 0, 0);
}

__device__ __forceinline__ u16 f2bf(float v) {
  unsigned int u = __float_as_uint(v);
  return (u16)((u + 0x7FFFu + ((u >> 16) & 1u)) >> 16);   // RNE
}
__device__ __forceinline__ float bf2f(u16 u) {
  return __uint_as_float(((unsigned int)u) << 16);
}
__device__ __forceinline__ u16 f2h(float v) {
  _Float16 h = (_Float16)v; u16 b; __builtin_memcpy(&b, &h, 2); return b;
}
__device__ __forceinline__ float h2f(u16 b) {
  _Float16 h; __builtin_memcpy(&h, &b, 2); return (float)h;
}

#define VMW(N) asm volatile("s_waitcnt vmcnt(" #N ")" ::: "memory")
#define BARR() asm volatile("s_barrier" ::: "memory")

// ===================== GEMM1: 256x256 tile, 8-phase counted-vmcnt =========
// (R6-verified; unchanged.) 512 thr (8 waves 2Mx4N), BK=32, 2 K-tiles/iter,
// 3-product split-bf16. LDS 128 KB. Swizzle slot ^= (row>>1)&3 both sides.
// Waits steady [3,4,5,6]x2; final-iter drain [3,2,1,0]. 24 MFMA/phase.

#define STAGE_BX(P, GPTR, LOFF, k0)                                          \
  { load_lds16((GPTR) + sB_base + (size_t)(k0),                              \
               lds + (P) * 32768 + (LOFF) + w * 512);                        \
    load_lds16((GPTR) + sB_base + (size_t)128 * Ksz + (size_t)(k0),          \
               lds + (P) * 32768 + (LOFF) + 4096 + w * 512); }

#define STAGE_A1(P, j, k0)                                                   \
  { load_lds16(Asrc + sA_base + (size_t)((j) * 32) * Ksz + (size_t)(k0),     \
               lds + (P) * 32768 + aldsb + (j) * 1024); }

#define LOAD_B(P)                                                            \
  { const u16* bb = lds + (P) * 32768;                                       \
    _Pragma("unroll") for (int n = 0; n < 4; ++n) {                          \
      bhf[n] = *(const bf16x8*)(bb + ardB + n * 512);                        \
      blf[n] = *(const bf16x8*)(bb + 8192 + ardB + n * 512); } }

#define PH_A(P, Q, ...)                                                      \
  { const u16* bb = lds + (P) * 32768;                                       \
    const bf16x8 a0h = *(const bf16x8*)(bb + ardA + ((Q)*2 + 0) * 512);      \
    const bf16x8 a0l = *(const bf16x8*)(bb + 8192 + ardA + ((Q)*2+0) * 512); \
    const bf16x8 a1h = *(const bf16x8*)(bb + ardA + ((Q)*2 + 1) * 512);      \
    const bf16x8 a1l = *(const bf16x8*)(bb + 8192 + ardA + ((Q)*2+1) * 512); \
    __VA_ARGS__                                                              \
    __builtin_amdgcn_s_setprio(1);                                           \
    _Pragma("unroll") for (int n = 0; n < 4; ++n) {                          \
      acc[(Q)*2+0][n] = __builtin_amdgcn_mfma_f32_16x16x32_bf16(a0h, bhf[n], acc[(Q)*2+0][n], 0,0,0); \
      acc[(Q)*2+0][n] = __builtin_amdgcn_mfma_f32_16x16x32_bf16(a0l, bhf[n], acc[(Q)*2+0][n], 0,0,0); \
      acc[(Q)*2+0][n] = __builtin_amdgcn_mfma_f32_16x16x32_bf16(a0h, blf[n], acc[(Q)*2+0][n], 0,0,0); \
      acc[(Q)*2+1][n] = __builtin_amdgcn_mfma_f32_16x16x32_bf16(a1h, bhf[n], acc[(Q)*2+1][n], 0,0,0); \
      acc[(Q)*2+1][n] = __builtin_amdgcn_mfma_f32_16x16x32_bf16(a1l, bhf[n], acc[(Q)*2+1][n], 0,0,0); \
      acc[(Q)*2+1][n] = __builtin_amdgcn_mfma_f32_16x16x32_bf16(a1h, blf[n], acc[(Q)*2+1][n], 0,0,0); \
    }                                                                        \
    __builtin_amdgcn_s_setprio(0); }

// shared mainloop body for gemm1 / gemm2s (identical schedule; K-extent and
// k-offset differ). Emits into local `acc`; all locals must be in scope.
#define G1_MAINLOOP(KBASE, NIT)                                              \
  STAGE_BX(0, Bhg, 16384, (KBASE)); STAGE_BX(0, Blg, 24576, (KBASE));        \
  STAGE_A1(0, 0, (KBASE)); STAGE_A1(0, 1, (KBASE));                          \
  STAGE_A1(0, 2, (KBASE)); STAGE_A1(0, 3, (KBASE));                          \
  for (int t = 0; t < (NIT) - 1; ++t) {                                      \
    const int k1 = (KBASE) + t * 64 + 32;                                    \
    const int k2 = (KBASE) + t * 64 + 64;                                    \
    VMW(3); BARR(); LOAD_B(0); PH_A(0, 0, STAGE_BX(1, Bhg, 16384, k1);)      \
    VMW(4); BARR();            PH_A(0, 1, STAGE_BX(1, Blg, 24576, k1);)      \
    VMW(5); BARR();            PH_A(0, 2, STAGE_A1(1, 0, k1); STAGE_A1(1, 1, k1);) \
    VMW(6); BARR();            PH_A(0, 3, STAGE_A1(1, 2, k1); STAGE_A1(1, 3, k1);) \
    VMW(3); BARR(); LOAD_B(1); PH_A(1, 0, STAGE_BX(0, Bhg, 16384, k2);)      \
    VMW(4); BARR();            PH_A(1, 1, STAGE_BX(0, Blg, 24576, k2);)      \
    VMW(5); BARR();            PH_A(1, 2, STAGE_A1(0, 0, k2); STAGE_A1(0, 1, k2);) \
    VMW(6); BARR();            PH_A(1, 3, STAGE_A1(0, 2, k2); STAGE_A1(0, 3, k2);) \
  }                                                                          \
  {                                                                          \
    const int k1 = (KBASE) + ((NIT) - 1) * 64 + 32;                          \
    VMW(3); BARR(); LOAD_B(0); PH_A(0, 0, STAGE_BX(1, Bhg, 16384, k1);)      \
    VMW(4); BARR();            PH_A(0, 1, STAGE_BX(1, Blg, 24576, k1);)      \
    VMW(5); BARR();            PH_A(0, 2, STAGE_A1(1, 0, k1); STAGE_A1(1, 1, k1);) \
    VMW(6); BARR();            PH_A(0, 3, STAGE_A1(1, 2, k1); STAGE_A1(1, 3, k1);) \
    VMW(3); BARR(); LOAD_B(1); PH_A(1, 0, )                                  \
    VMW(2); BARR();            PH_A(1, 1, )                                  \
    VMW(1); BARR();            PH_A(1, 2, )                                  \
    VMW(0); BARR();            PH_A(1, 3, )                                  \
  }

__global__ __launch_bounds__(512, 2)
void k_gemm1(const u16* __restrict__ xh, const u16* __restrict__ xl,
             const u16* __restrict__ w1h, const u16* __restrict__ w1l,
             const float* __restrict__ b1,
             u16* __restrict__ hh, u16* __restrict__ hl) {
  extern __shared__ u16 lds[];
  const int tid = threadIdx.x;
  const int lane = tid & 63;
  const int w = tid >> 6;
  const int wr = w >> 2, wc = w & 3;
  const int rlow = lane & 15;
  const size_t Ksz = D_;
  const int nbn = C4_ / 256;
  const int bm = blockIdx.x / nbn, bn = blockIdx.x % nbn;
  const int rowA0 = bm * 256, rowB0 = bn * 256;
  const u16* __restrict__ Bhg = w1h;
  const u16* __restrict__ Blg = w1l;
  const u16* __restrict__ Asrc = (w < 4) ? xh : xl;

  const int gslot8 = (((lane & 3) ^ ((lane >> 3) & 3)) << 3);
  const size_t sB_base = (size_t)(rowB0 + w * 16 + (lane >> 2)) * Ksz + gslot8;
  const size_t sA_base =
      (size_t)(rowA0 + ((w >> 1) & 1) * 128 + (w & 1) * 16 + (lane >> 2)) * Ksz + gslot8;
  const int aldsb = ((w < 4) ? 0 : 8192) + ((w >> 1) & 1) * 4096 + (w & 1) * 512;

  const int aslot8 = (((lane >> 4) ^ ((lane >> 1) & 3)) << 3);
  const int ardA = wr * 4096 + rlow * 32 + aslot8;
  const int ardB = 16384 + wc * 2048 + rlow * 32 + aslot8;

  f32x4 acc[8][4];
#pragma unroll
  for (int m = 0; m < 8; ++m)
#pragma unroll
    for (int n = 0; n < 4; ++n) acc[m][n] = (f32x4){0.f, 0.f, 0.f, 0.f};
  bf16x8 bhf[4], blf[4];

  G1_MAINLOOP(0, (int)(Ksz / 64))

#pragma unroll
  for (int m = 0; m < 8; ++m)
#pragma unroll
    for (int n = 0; n < 4; ++n)
#pragma unroll
      for (int j = 0; j < 4; ++j) {
        const int rg = rowA0 + wr * 128 + m * 16 + (lane >> 4) * 4 + j;
        const int cg = rowB0 + wc * 64 + n * 16 + rlow;
        const float v = acc[m][n][j] + b1[cg];
        const float s = v / (1.f + __expf(-v));
        const size_t o = (size_t)rg * C4_ + cg;
        const u16 hi = f2bf(s);
        hh[o] = hi;
        hl[o] = f2bf(s - bf2f(hi));
      }
}

// ========== GEMM2 split-K=2: verbatim gemm1-clone, 256x256, K=2048 ========
// grid = 32(bm) x 4(bn) x 2(ks) = 256 blocks = 1/CU (template-native).
// Row stride stays 4096; block ks covers columns [ks*2048, ks*2048+2048).
// Writes f32 partials (no bias); k_combine sums + bias -> zf + zh.
__global__ __launch_bounds__(512, 2)
void k_gemm2s(const u16* __restrict__ hh, const u16* __restrict__ hl,
              const u16* __restrict__ w2h, const u16* __restrict__ w2l,
              float* __restrict__ zpart) {
  extern __shared__ u16 lds[];
  const int tid = threadIdx.x;
  const int lane = tid & 63;
  const int w = tid >> 6;
  const int wr = w >> 2, wc = w & 3;
  const int rlow = lane & 15;
  const size_t Ksz = C4_;                       // row stride (full K)
  const int ks = blockIdx.x & 1;
  const int bi = blockIdx.x >> 1;
  const int bm = bi >> 2, bn = bi & 3;          // 32 x 4
  const int rowA0 = bm * 256, rowB0 = bn * 256;
  const int kbase = ks * 2048;
  const u16* __restrict__ Bhg = w2h;
  const u16* __restrict__ Blg = w2l;
  const u16* __restrict__ Asrc = (w < 4) ? hh : hl;

  const int gslot8 = (((lane & 3) ^ ((lane >> 3) & 3)) << 3);
  const size_t sB_base = (size_t)(rowB0 + w * 16 + (lane >> 2)) * Ksz + gslot8;
  const size_t sA_base =
      (size_t)(rowA0 + ((w >> 1) & 1) * 128 + (w & 1) * 16 + (lane >> 2)) * Ksz + gslot8;
  const int aldsb = ((w < 4) ? 0 : 8192) + ((w >> 1) & 1) * 4096 + (w & 1) * 512;

  const int aslot8 = (((lane >> 4) ^ ((lane >> 1) & 3)) << 3);
  const int ardA = wr * 4096 + rlow * 32 + aslot8;
  const int ardB = 16384 + wc * 2048 + rlow * 32 + aslot8;

  f32x4 acc[8][4];
#pragma unroll
  for (int m = 0; m < 8; ++m)
#pragma unroll
    for (int n = 0; n < 4; ++n) acc[m][n] = (f32x4){0.f, 0.f, 0.f, 0.f};
  bf16x8 bhf[4], blf[4];

  G1_MAINLOOP(kbase, 32)

  float* zp = zpart + (size_t)ks * ((size_t)B_ * C_);
#pragma unroll
  for (int m = 0; m < 8; ++m)
#pragma unroll
    for (int n = 0; n < 4; ++n)
#pragma unroll
      for (int j = 0; j < 4; ++j) {
        const int rg = rowA0 + wr * 128 + m * 16 + (lane >> 4) * 4 + j;
        const int cg = rowB0 + wc * 64 + n * 16 + rlow;
        zp[(size_t)rg * C_ + cg] = acc[m][n][j];
      }
}

// -------- combine: z = p0 + p1 + b2 -> zf (f32) + zh (bf16) ---------------
__global__ __launch_bounds__(256)
void k_combine(const float* __restrict__ p0, const float* __restrict__ p1,
               const float* __restrict__ b2,
               float* __restrict__ zf, u16* __restrict__ zh) {
  const size_t n4 = (size_t)B_ * C_ / 4;
  size_t i = (size_t)blockIdx.x * blockDim.x + threadIdx.x;
  const size_t stride = (size_t)gridDim.x * blockDim.x;
  for (; i < n4; i += stride) {
    const float4 a = ((const float4*)p0)[i];
    const float4 b = ((const float4*)p1)[i];
    const float4 bb = *(const float4*)(b2 + ((i * 4) & (C_ - 1)));
    float4 v;
    v.x = a.x + b.x + bb.x; v.y = a.y + b.y + bb.y;
    v.z = a.z + b.z + bb.z; v.w = a.w + b.w + bb.w;
    ((float4*)zf)[i] = v;
    u16x4 h;
    h[0] = f2bf(v.x); h[1] = f2bf(v.y); h[2] = f2bf(v.z); h[3] = f2bf(v.w);
    *(u16x4*)(zh + i * 4) = h;
  }
}

// ===== GEMM3 v4 (R10): 256x256, quadrant-phase 8-phase, writes dotm f16 ===
#define G3_SB(P, jj, k0)                                                     \
  load_lds16(eh + sB_base + (size_t)((jj) * 8) * 1024 + (size_t)(k0),        \
             lds + (P) * 32768 + 16384 + (w * 32 + (jj) * 8) * 64);
#define G3_SA(P, h, l, k0)                                                   \
  load_lds16(zh + sA_base + (size_t)((h) * 64 + (l) * 8) * 1024 + (size_t)(k0), \
             lds + (P) * 32768 + (aw0 + (h) * 64 + (l) * 8) * 64);
#define G3_RB(P, ks)                                                         \
  { const u16* bb = lds + (P) * 32768 + 16384;                               \
    const int kof = ((((ks) * 4 + (lane >> 4)) ^ (lane & 7)) << 3);          \
    _Pragma("unroll") for (int n = 0; n < 4; ++n)                            \
      bfv[n] = *(const bf16x8*)(bb + (wc * 64 + n * 16 + rlow) * 64 + kof); }
#define G3_PH(P, h, ks, ...)                                                 \
  { const u16* ab = lds + (P) * 32768;                                       \
    const int kof = ((((ks) * 4 + (lane >> 4)) ^ (lane & 7)) << 3);          \
    bf16x8 af[4];                                                            \
    _Pragma("unroll") for (int m = 0; m < 4; ++m)                            \
      af[m] = *(const bf16x8*)(ab + (wr * 128 + (h) * 64 + m * 16 + rlow) * 64 + kof); \
    __VA_ARGS__                                                              \
    __builtin_amdgcn_s_setprio(1);                                           \
    _Pragma("unroll") for (int m = 0; m < 4; ++m)                            \
      _Pragma("unroll") for (int n = 0; n < 4; ++n)                          \
        acc[(h) * 4 + m][n] = __builtin_amdgcn_mfma_f32_16x16x32_bf16(af[m], bfv[n], acc[(h) * 4 + m][n], 0, 0, 0); \
    __builtin_amdgcn_s_setprio(0); }

__global__ __launch_bounds__(512, 2)
void k_gemm3(const u16* __restrict__ zh, const u16* __restrict__ eh,
             u16* __restrict__ dotm) {
  extern __shared__ u16 lds[];
  const int tid = threadIdx.x;
  const int lane = tid & 63;
  const int w = tid >> 6;
  const int wr = w >> 2, wc = w & 3;
  const int rlow = lane & 15;
  const int nbn = K_ / 256;
  const int bm = blockIdx.x / nbn, bn = blockIdx.x % nbn;
  const int rowA0 = bm * 256, rowB0 = bn * 256;

  const int gsl = (((lane & 7) ^ (lane >> 3)) << 3);   // pre-swizzled slot
  const int aw0 = (w >> 2) * 128 + (w & 3) * 16;
  const size_t sB_base = (size_t)(rowB0 + w * 32 + (lane >> 3)) * 1024 + gsl;
  const size_t sA_base = (size_t)(rowA0 + aw0 + (lane >> 3)) * 1024 + gsl;

  f32x4 acc[8][4];
#pragma unroll
  for (int m = 0; m < 8; ++m)
#pragma unroll
    for (int n = 0; n < 4; ++n) acc[m][n] = (f32x4){0.f, 0.f, 0.f, 0.f};
  bf16x8 bfv[4];

  G3_SB(0, 0, 0); G3_SB(0, 1, 0); G3_SB(0, 2, 0); G3_SB(0, 3, 0);
  G3_SA(0, 0, 0, 0); G3_SA(0, 0, 1, 0); G3_SA(0, 1, 0, 0); G3_SA(0, 1, 1, 0);

  for (int t = 0; t < 7; ++t) {
    const int k1 = t * 128 + 64;    // tile 2t+1 -> buf1
    const int k2 = t * 128 + 128;   // tile 2t+2 -> buf0
    VMW(2); BARR(); G3_RB(0, 0); G3_PH(0, 0, 0, G3_SB(1, 0, k1); G3_SB(1, 1, k1);)
    VMW(2); BARR();              G3_PH(0, 1, 0, G3_SB(1, 2, k1); G3_SB(1, 3, k1);)
            BARR(); G3_RB(0, 1); G3_PH(0, 0, 1, G3_SA(1, 0, 0, k1); G3_SA(1, 0, 1, k1);)
            BARR();              G3_PH(0, 1, 1, G3_SA(1, 1, 0, k1); G3_SA(1, 1, 1, k1);)
    VMW(2); BARR(); G3_RB(1, 0); G3_PH(1, 0, 0, G3_SB(0, 0, k2); G3_SB(0, 1, k2);)
    VMW(2); BARR();              G3_PH(1, 1, 0, G3_SB(0, 2, k2); G3_SB(0, 3, k2);)
            BARR(); G3_RB(1, 1); G3_PH(1, 0, 1, G3_SA(0, 0, 0, k2); G3_SA(0, 0, 1, k2);)
            BARR();              G3_PH(1, 1, 1, G3_SA(0, 1, 0, k2); G3_SA(0, 1, 1, k2);)
  }
  {
    const int k1 = 7 * 128 + 64;
    VMW(2); BARR(); G3_RB(0, 0); G3_PH(0, 0, 0, G3_SB(1, 0, k1); G3_SB(1, 1, k1);)
    VMW(2); BARR();              G3_PH(0, 1, 0, G3_SB(1, 2, k1); G3_SB(1, 3, k1);)
            BARR(); G3_RB(0, 1); G3_PH(0, 0, 1, G3_SA(1, 0, 0, k1); G3_SA(1, 0, 1, k1);)
            BARR();              G3_PH(0, 1, 1, G3_SA(1, 1, 0, k1); G3_SA(1, 1, 1, k1);)
    VMW(2); BARR(); G3_RB(1, 0); G3_PH(1, 0, 0, )
    VMW(0); BARR();              G3_PH(1, 1, 0, )
            BARR(); G3_RB(1, 1); G3_PH(1, 0, 1, )
            BARR();              G3_PH(1, 1, 1, )
  }

  // epilogue: repack acc -> f16 dotm via LDS in 4 passes of 64 rows
  __syncthreads();
  u16* ldsw = lds;
#pragma unroll
  for (int p = 0; p < 4; ++p) {
    if (wr == (p >> 1)) {
      const int mb = (p & 1) * 4;
#pragma unroll
      for (int mm = 0; mm < 4; ++mm)
#pragma unroll
        for (int n = 0; n < 4; ++n)
#pragma unroll
          for (int j = 0; j < 4; ++j) {
            const int rl = mm * 16 + (lane >> 4) * 4 + j;
            const int cl = wc * 64 + n * 16 + rlow;
            ldsw[rl * 256 + cl] = f2h(acc[mb + mm][n][j]);
          }
    }
    __syncthreads();
    for (int i = tid; i < 2048; i += 512) {
      const int r = i >> 5, c = (i & 31) * 8;
      *(uint4*)(dotm + (size_t)(rowA0 + p * 64 + r) * K_ + rowB0 + c) =
          *(const uint4*)(ldsw + r * 256 + c);
    }
    __syncthreads();
  }
}

// -------- scan: per-row min + candidates within rigorous bound (R6) -------
__global__ __launch_bounds__(256)
void k_scan(const u16* __restrict__ dotm, const float* __restrict__ norms,
            const float* __restrict__ zn2, const unsigned int* __restrict__ emaxb,
            int* __restrict__ cand, int* __restrict__ candcnt) {
  __shared__ __align__(16) u16 srow[K_];
  __shared__ float rmin[4];
  __shared__ int lcnt;
  const int r = blockIdx.x, tid = threadIdx.x;
  const size_t base = (size_t)r * K_;
  for (int i = tid; i < K_ / 8; i += 256)
    ((uint4*)srow)[i] = ((const uint4*)(dotm + base))[i];
  if (tid == 0) lcnt = 0;
  __syncthreads();
  float mymin = 3.4e38f;
  for (int k = tid; k < K_; k += 256)
    mymin = fminf(mymin, norms[k] - 2.f * h2f(srow[k]));
#pragma unroll
  for (int off = 32; off >= 1; off >>= 1)
    mymin = fminf(mymin, __shfl_xor(mymin, off, 64));
  if ((tid & 63) == 0) rmin[tid >> 6] = mymin;
  __syncthreads();
  const float gmin = fminf(fminf(rmin[0], rmin[1]), fminf(rmin[2], rmin[3]));
  const float bnd = 0.010f * sqrtf(zn2[r]) * sqrtf(__uint_as_float(*emaxb)) + 0.01f;
  const float win = gmin + 2.f * bnd;
  for (int k = tid; k < K_; k += 256) {
    const float sc = norms[k] - 2.f * h2f(srow[k]);
    if (sc <= win) {
      const int p = atomicAdd(&lcnt, 1);
      if (p < CAP) cand[r * CAP + p] = k;
    }
  }
  __syncthreads();
  if (tid == 0) candcnt[r] = lcnt;
}

// ---- fused rescore (4-wave parallel, exact f64) + gather + LayerNorm -----
__global__ __launch_bounds__(256)
void k_rescore_finalize(const int* __restrict__ cand, const int* __restrict__ candcnt,
                        const float* __restrict__ zf, const float* __restrict__ embT,
                        const float* __restrict__ gamma, const float* __restrict__ beta,
                        float* __restrict__ out, double* __restrict__ dacc) {
  const int row = blockIdx.x;
  const int tid = threadIdx.x;
  const int lane = tid & 63, wv = tid >> 6;
  __shared__ int sid;
  __shared__ double wd[4];
  __shared__ int wk[4];

  const int cnt = candcnt[row];
  if (cnt <= 1) {               // block-uniform branch
    if (tid == 0) sid = cand[row * CAP];
    __syncthreads();
  } else {
    const bool full = cnt > CAP;   // rigorous fallback (never expected)
    const int n = full ? K_ : cnt;
    double bestd = 1e300; int bestk = 0x7fffffff;
    for (int c = wv; c < n; c += 4) {
      const int k = full ? c : cand[row * CAP + c];
      double s = 0.0;
      for (int i = lane; i < C_; i += 64) {
        const double d = (double)zf[(size_t)row * C_ + i] - (double)embT[(size_t)k * C_ + i];
        s += d * d;
      }
#pragma unroll
      for (int off = 32; off >= 1; off >>= 1) s += __shfl_xor(s, off, 64);
      if (s < bestd || (s == bestd && k < bestk)) { bestd = s; bestk = k; }
    }
    if (lane == 0) { wd[wv] = bestd; wk[wv] = bestk; }
    __syncthreads();
    if (tid == 0) {
      double bd = wd[0]; int bk = wk[0];
#pragma unroll
      for (int q = 1; q < 4; ++q)
        if (wd[q] < bd || (wd[q] == bd && wk[q] < bk)) { bd = wd[q]; bk = wk[q]; }
      sid = bk;
    }
    __syncthreads();
  }
  const int id = sid;

  const float4 e4 = *(const float4*)(embT + (size_t)id * C_ + tid * 4);
  float s1 = e4.x + e4.y + e4.z + e4.w;
  float s2 = e4.x * e4.x + e4.y * e4.y + e4.z * e4.z + e4.w * e4.w;
#pragma unroll
  for (int off = 32; off >= 1; off >>= 1) {
    s1 += __shfl_xor(s1, off, 64);
    s2 += __shfl_xor(s2, off, 64);
  }
  __shared__ float r1[4], r2[4], rd[4];
  if (lane == 0) { r1[wv] = s1; r2[wv] = s2; }
  __syncthreads();
  const float S1 = r1[0] + r1[1] + r1[2] + r1[3];
  const float S2 = r2[0] + r2[1] + r2[2] + r2[3];
  const float mu = S1 * (1.f / C_);
  const float var = S2 * (1.f / C_) - mu * mu;
  const float inv = 1.f / sqrtf(var + 1e-5f);

  const float4 z4 = *(const float4*)(zf + (size_t)row * C_ + tid * 4);
  const float4 g4 = *(const float4*)(gamma + tid * 4);
  const float4 b4 = *(const float4*)(beta + tid * 4);
  float4 o4;
  o4.x = (e4.x - mu) * inv * g4.x + b4.x;
  o4.y = (e4.y - mu) * inv * g4.y + b4.y;
  o4.z = (e4.z - mu) * inv * g4.z + b4.z;
  o4.w = (e4.w - mu) * inv * g4.w + b4.w;
  *(float4*)(out + (size_t)row * C_ + tid * 4) = o4;

  const float dx = e4.x - z4.x, dy = e4.y - z4.y, dz = e4.z - z4.z, dw = e4.w - z4.w;
  float d = dx * dx + dy * dy + dz * dz + dw * dw;
#pragma unroll
  for (int off = 32; off >= 1; off >>= 1) d += __shfl_xor(d, off, 64);
  __syncthreads();
  if (lane == 0) rd[wv] = d;
  __syncthreads();
  if (tid == 0) atomicAdd(dacc, (double)(rd[0] + rd[1] + rd[2] + rd[3]));
}

// -------- prep kernels ----------------------------------------------------
__global__ void k_split(const float4* __restrict__ in, size_t n4,
                        u16* __restrict__ hi, u16* __restrict__ lo,
                        double* __restrict__ dacc, unsigned int* __restrict__ emaxb) {
  size_t i = (size_t)blockIdx.x * blockDim.x + threadIdx.x;
  if (i == 0) { *dacc = 0.0; *emaxb = 0u; }   // folded init (runs first)
  const size_t stride = (size_t)gridDim.x * blockDim.x;
  for (; i < n4; i += stride) {
    const float4 v = in[i];
    const float vv[4] = {v.x, v.y, v.z, v.w};
    u16x4 h, l;
#pragma unroll
    for (int j = 0; j < 4; ++j) {
      const u16 a = f2bf(vv[j]);
      h[j] = a;
      l[j] = f2bf(vv[j] - bf2f(a));
    }
    *(u16x4*)(hi + i * 4) = h;
    *(u16x4*)(lo + i * 4) = l;
  }
}

template <bool WF32, bool WLO>
__global__ void k_tsplit(const float* __restrict__ in, int R, int Cc,
                         u16* __restrict__ hiT, u16* __restrict__ loT,
                         float* __restrict__ f32T) {
  __shared__ float t[32][33];
  const int c0 = blockIdx.x * 32, r0 = blockIdx.y * 32;
  const int tx = threadIdx.x, ty = threadIdx.y;
#pragma unroll
  for (int i = 0; i < 4; ++i)
    t[ty + i * 8][tx] = in[(size_t)(r0 + ty + i * 8) * Cc + (c0 + tx)];
  __syncthreads();
#pragma unroll
  for (int i = 0; i < 4; ++i) {
    const int orow = c0 + ty + i * 8;
    const int ocol = r0 + tx;
    const float v = t[tx][ty + i * 8];
    const size_t o = (size_t)orow * R + ocol;
    const u16 hi = f2bf(v);
    hiT[o] = hi;
    if (WLO) loT[o] = f2bf(v - bf2f(hi));
    if (WF32) f32T[o] = v;
  }
}

__global__ __launch_bounds__(256)
void k_rownorm(const float* __restrict__ in, float* __restrict__ out,
               unsigned int* __restrict__ maxb, int domax) {
  const int r = blockIdx.x, tid = threadIdx.x;
  const float4 v = *(const float4*)(in + (size_t)r * 1024 + tid * 4);
  double s = (double)v.x * v.x + (double)v.y * v.y +
             (double)v.z * v.z + (double)v.w * v.w;
#pragma unroll
  for (int off = 32; off >= 1; off >>= 1) s += __shfl_xor(s, off, 64);
  __shared__ double sw[4];
  if ((tid & 63) == 0) sw[tid >> 6] = s;
  __syncthreads();
  if (tid == 0) {
    const float t = (float)(sw[0] + sw[1] + sw[2] + sw[3]);
    out[r] = t;
    if (domax) atomicMax(maxb, __float_as_uint(t));
  }
}

__global__ void k_wdiff(const double* __restrict__ dacc, float* __restrict__ out) {
  out[(size_t)B_ * C_] = (float)(0.01 * (*dacc) / ((double)B_ * (double)C_));
}

// ---------------------------------------------------------------------------
extern "C" void kernel_launch(void* const* d_in, const int* in_sizes, int n_in,
                              void* d_out, int out_size, void* d_ws, size_t ws_size,
                              hipStream_t stream) {
  const float* x     = (const float*)d_in[0];
  const float* W1    = (const float*)d_in[1];
  const float* b1    = (const float*)d_in[2];
  const float* W2    = (const float*)d_in[3];
  const float* b2    = (const float*)d_in[4];
  const float* gamma = (const float*)d_in[5];
  const float* beta  = (const float*)d_in[6];
  const float* embed = (const float*)d_in[7];
  float* out = (float*)d_out;

  char* ws = (char*)d_ws;
  const size_t M = 1048576ull;
  // phase 1: xh 0..64M, xl 64..128M, w1h 128..160M, w1l 160..192M,
  //          hh 192..256M, hl 256..320M
  // phase 2 (over dead xh/xl): w2h 0..8M, w2l 8..16M, zf 16..48M,
  //          zh 48..64M, zpart 64..128M (2 x 32M; consumed by combine
  //          BEFORE tsplit-embed overwrites embT@64M / eh@96M),
  //          small @112M+256K..., cand 113..115M, dotm 192..320M
  u16* xh  = (u16*)(ws);
  u16* xl  = (u16*)(ws + 64 * M);
  u16* w1h = (u16*)(ws + 128 * M);
  u16* w1l = (u16*)(ws + 160 * M);
  u16* hh  = (u16*)(ws + 192 * M);
  u16* hl  = (u16*)(ws + 256 * M);
  u16* w2h = (u16*)(ws);
  u16* w2l = (u16*)(ws + 8 * M);
  float* zf = (float*)(ws + 16 * M);
  u16* zh  = (u16*)(ws + 48 * M);
  float* zpart = (float*)(ws + 64 * M);          // 64 MB (2 partials)
  float* embT = (float*)(ws + 64 * M);           // after combine
  u16* eh  = (u16*)(ws + 96 * M);                // after combine
  float* norms = (float*)(ws + 112 * M);
  float* zn2   = (float*)(ws + 112 * M + 65536ull);
  int* candcnt = (int*)(ws + 112 * M + 131072ull);
  int* idx     = (int*)(ws + 112 * M + 196608ull);
  unsigned int* emaxb = (unsigned int*)(ws + 112 * M + 262144ull);
  double* dacc = (double*)(ws + 112 * M + 262144ull + 64ull);
  int* cand    = (int*)(ws + 113 * M);
  u16* dotm    = (u16*)(ws + 192 * M);

  (void)hipFuncSetAttribute((const void*)k_gemm1,
                            hipFuncAttributeMaxDynamicSharedMemorySize, 131072);
  (void)hipFuncSetAttribute((const void*)k_gemm2s,
                            hipFuncAttributeMaxDynamicSharedMemorySize, 131072);
  (void)hipFuncSetAttribute((const void*)k_gemm3,
                            hipFuncAttributeMaxDynamicSharedMemorySize, 131072);

  // 1. split x -> xh/xl (+ init dacc/emaxb)
  k_split<<<2048, 256, 0, stream>>>((const float4*)x, (size_t)B_ * D_ / 4, xh, xl, dacc, emaxb);
  // 2. W1 [D][4C] -> W1T hi/lo [4C][D]
  k_tsplit<false, true><<<dim3(C4_ / 32, D_ / 32), dim3(32, 8), 0, stream>>>(W1, D_, C4_, w1h, w1l, nullptr);
  // 3. GEMM1 (256^2 8-phase; +bias+SiLU+split)
  k_gemm1<<<(B_ / 256) * (C4_ / 256), 512, 131072, stream>>>(xh, xl, w1h, w1l, b1, hh, hl);
  // 4. W2 [4C][C] -> W2T hi/lo [C][4C]
  k_tsplit<false, true><<<dim3(C_ / 32, C4_ / 32), dim3(32, 8), 0, stream>>>(W2, C4_, C_, w2h, w2l, nullptr);
  // 5. GEMM2 split-K=2 (256^2 8-phase clone, 256 blocks) -> f32 partials
  k_gemm2s<<<(B_ / 256) * (C_ / 256) * 2, 512, 131072, stream>>>(hh, hl, w2h, w2l, zpart);
  // 6. combine partials + bias -> zf + zh
  k_combine<<<2048, 256, 0, stream>>>(zpart, zpart + (size_t)B_ * C_, b2, zf, zh);
  // 7. embed [C][K] -> embT f32 + bf16 hi [K][C]  (overwrites zpart)
  k_tsplit<true, false><<<dim3(K_ / 32, C_ / 32), dim3(32, 8), 0, stream>>>(embed, C_, K_, eh, nullptr, embT);
  // 8. norms (coalesced, f64) + max; z row norms
  k_rownorm<<<K_, 256, 0, stream>>>(embT, norms, emaxb, 1);
  k_rownorm<<<B_, 256, 0, stream>>>(zf, zn2, emaxb, 0);
  // 9. GEMM3 v4 (256^2 quadrant-phase 8-phase) -> dotm f16
  k_gemm3<<<(B_ / 256) * (K_ / 256), 512, 131072, stream>>>(zh, eh, dotm);
  // 10. per-row min + global-window candidates (R6-proven)
  k_scan<<<B_, 256, 0, stream>>>(dotm, norms, zn2, emaxb, cand, candcnt);
  // 11. fused exact-f64 rescore + gather + LayerNorm + commitment
  k_rescore_finalize<<<B_, 256, 0, stream>>>(cand, candcnt, zf, embT, gamma, beta, out, dacc);
  // 12. scalar diff output
  k_wdiff<<<1, 1, 0, stream>>>(dacc, out);
}